// Round 11
// baseline (960.608 us; speedup 1.0000x reference)
//
#include <hip/hip_runtime.h>
#include <cstdint>
#include <cstddef>

// Problem constants (SuperGraphConstruction)
#define NN 100000      // nodes
#define NC 20000       // clusters
#define LATD 128
#define HIDD 512
#define EMBD 12
#define NES 160000     // super edges
#define NEB 800000     // bipartite edges

enum { ACT_NONE = 0, ACT_TANH = 1, ACT_RELU = 2 };

typedef __attribute__((ext_vector_type(8))) short bf16x8;
typedef __attribute__((ext_vector_type(4))) float f32x4;
typedef unsigned short ushort_t;

__device__ __forceinline__ float fast_tanh(float x) {
    return 1.f - 2.f / (__expf(2.f * x) + 1.f);
}
__device__ __forceinline__ ushort_t f2bf(float f) {
    union { float f; unsigned u; } x; x.f = f;
    unsigned r = x.u + 0x7FFFu + ((x.u >> 16) & 1u);  // RNE
    return (ushort_t)(r >> 16);
}
__device__ __forceinline__ float bf2f(ushort_t h) {
    union { unsigned u; float f; } x; x.u = ((unsigned)h) << 16;
    return x.f;
}

typedef __attribute__((address_space(1))) void gvoid_t;
typedef __attribute__((address_space(3))) void svoid_t;
__device__ __forceinline__ void gload_lds16(const void* g, void* l) {
    __builtin_amdgcn_global_load_lds((gvoid_t*)g, (svoid_t*)l, 16, 0, 0);
}

// ---------------------------------------------------------------------------
__global__ __launch_bounds__(256) void conv_f2b_kernel(
    const float* __restrict__ in, ushort_t* __restrict__ out, long n)
{
    long i = ((long)blockIdx.x * 256 + threadIdx.x) * 8;
    long stride = (long)gridDim.x * 256 * 8;
    for (; i + 7 < n; i += stride) {
        float4 a = *(const float4*)(in + i);
        float4 b = *(const float4*)(in + i + 4);
        ushort_t o[8] = { f2bf(a.x), f2bf(a.y), f2bf(a.z), f2bf(a.w),
                          f2bf(b.x), f2bf(b.y), f2bf(b.z), f2bf(b.w) };
        *(int4*)(out + i) = *(int4*)o;
    }
}

// W [K][N] fp32 -> Wt [N][K] bf16
__global__ __launch_bounds__(256) void transpose_conv_kernel(
    const float* __restrict__ W, ushort_t* __restrict__ Wt, int K, int N)
{
    int i = blockIdx.x * 256 + threadIdx.x;
    if (i >= K * N) return;
    int n = i / K, k = i % K;
    Wt[i] = f2bf(W[(size_t)k * N + n]);
}

// ---------------------------------------------------------------------------
// bf16 MFMA GEMM (m97 + T2 swizzle)
// ---------------------------------------------------------------------------
template<int ACT, bool OUT_BF16>
__global__ __launch_bounds__(256) void gemm_mfma(
    const ushort_t* __restrict__ A, const ushort_t* __restrict__ Bt,
    const float* __restrict__ bias, void* __restrict__ Cv,
    int M, int N, int K)
{
    __shared__ ushort_t As[128 * 64];
    __shared__ ushort_t Bs[128 * 64];

    const int tid = threadIdx.x;
    const int m0 = blockIdx.y * 128, n0 = blockIdx.x * 128;
    const int w = tid >> 6, lane = tid & 63;
    const int wm = w >> 1, wn = w & 1;
    const int lr = lane & 15, lg = lane >> 4;
    const int srow = lane >> 3;
    const int sseg = (lane & 7) ^ srow;

    f32x4 acc[4][4];
#pragma unroll
    for (int i = 0; i < 4; ++i)
#pragma unroll
        for (int j = 0; j < 4; ++j) acc[i][j] = (f32x4){0.f, 0.f, 0.f, 0.f};

    for (int k0 = 0; k0 < K; k0 += 64) {
#pragma unroll
        for (int i = 0; i < 4; ++i) {
            int c = w * 4 + i;
            int row = c * 8 + srow;
            int gm = m0 + row; if (gm >= M) gm = M - 1;
            gload_lds16(A + (size_t)gm * K + k0 + sseg * 8, As + c * 512);
            gload_lds16(Bt + (size_t)(n0 + row) * K + k0 + sseg * 8, Bs + c * 512);
        }
        __syncthreads();
#pragma unroll
        for (int ks = 0; ks < 2; ++ks) {
            bf16x8 af[4], bf[4];
#pragma unroll
            for (int mt = 0; mt < 4; ++mt) {
                int row = wm * 64 + mt * 16 + lr;
                int slot = (ks * 4 + lg) ^ (row & 7);
                af[mt] = *(const bf16x8*)&As[row * 64 + slot * 8];
            }
#pragma unroll
            for (int nt = 0; nt < 4; ++nt) {
                int row = wn * 64 + nt * 16 + lr;
                int slot = (ks * 4 + lg) ^ (row & 7);
                bf[nt] = *(const bf16x8*)&Bs[row * 64 + slot * 8];
            }
#pragma unroll
            for (int mt = 0; mt < 4; ++mt)
#pragma unroll
                for (int nt = 0; nt < 4; ++nt)
                    acc[mt][nt] = __builtin_amdgcn_mfma_f32_16x16x32_bf16(
                        af[mt], bf[nt], acc[mt][nt], 0, 0, 0);
        }
        __syncthreads();
    }

#pragma unroll
    for (int nt = 0; nt < 4; ++nt) {
        int col = n0 + wn * 64 + nt * 16 + lr;
        float bv = bias[col];
#pragma unroll
        for (int mt = 0; mt < 4; ++mt) {
#pragma unroll
            for (int r = 0; r < 4; ++r) {
                int row = m0 + wm * 64 + mt * 16 + lg * 4 + r;
                if (row >= M) continue;
                float v = acc[mt][nt][r] + bv;
                if (ACT == ACT_TANH) v = fast_tanh(v);
                else if (ACT == ACT_RELU) v = fmaxf(v, 0.f);
                if (OUT_BF16) ((ushort_t*)Cv)[(size_t)row * N + col] = f2bf(v);
                else ((float*)Cv)[(size_t)row * N + col] = v;
            }
        }
    }
}

// ---------------------------------------------------------------------------
// FUSED 2-layer MLP (node messages): out = relu(relu(A@W1+b1)@W2+b2)
// ---------------------------------------------------------------------------
template<bool OUT_BF16>
__global__ __launch_bounds__(256) void fused_mlp(
    const ushort_t* __restrict__ A, const ushort_t* __restrict__ W1t,
    const float* __restrict__ b1, const ushort_t* __restrict__ W2t,
    const float* __restrict__ b2, void* __restrict__ Cv, int M)
{
    __shared__ ushort_t As[128 * 128];
    __shared__ ushort_t Ws[128 * 64];
    __shared__ ushort_t Hs[128 * 128];

    const int tid = threadIdx.x;
    const int m0 = blockIdx.x * 128;
    const int w = tid >> 6, lane = tid & 63;
    const int wm = w >> 1, wn = w & 1;
    const int lr = lane & 15, lg = lane >> 4;
    const int srow = lane >> 3;
    const int sseg = (lane & 7) ^ srow;

    f32x4 acc2[4][4];
#pragma unroll
    for (int i = 0; i < 4; ++i)
#pragma unroll
        for (int j = 0; j < 4; ++j) acc2[i][j] = (f32x4){0.f, 0.f, 0.f, 0.f};

    {   // stage A resident: [128][128], 16-slot swizzled rows
        const int arow4 = lane >> 4;
        const int aslot = lane & 15;
#pragma unroll
        for (int rnd = 0; rnd < 8; ++rnd) {
            int row = rnd * 16 + w * 4 + arow4;
            int gm = m0 + row; if (gm >= M) gm = M - 1;
            int seg = aslot ^ (row & 7);
            gload_lds16(A + (size_t)gm * 128 + seg * 8, As + row * 128);
        }
    }

    for (int c = 0; c < 4; ++c) {
        f32x4 acc1[4][4];
#pragma unroll
        for (int i = 0; i < 4; ++i)
#pragma unroll
            for (int j = 0; j < 4; ++j) acc1[i][j] = (f32x4){0.f, 0.f, 0.f, 0.f};

        for (int k0 = 0; k0 < 128; k0 += 64) {
#pragma unroll
            for (int i = 0; i < 4; ++i) {
                int ch = w * 4 + i;
                int row = ch * 8 + srow;
                gload_lds16(W1t + (size_t)(c * 128 + row) * 128 + k0 + sseg * 8,
                            Ws + ch * 512);
            }
            __syncthreads();
#pragma unroll
            for (int ks = 0; ks < 2; ++ks) {
                bf16x8 af[4], bf[4];
#pragma unroll
                for (int mt = 0; mt < 4; ++mt) {
                    int row = wm * 64 + mt * 16 + lr;
                    int seg = (k0 >> 3) + ks * 4 + lg;
                    int slot = seg ^ (row & 7);
                    af[mt] = *(const bf16x8*)&As[row * 128 + slot * 8];
                }
#pragma unroll
                for (int nt = 0; nt < 4; ++nt) {
                    int row = wn * 64 + nt * 16 + lr;
                    int slot = (ks * 4 + lg) ^ (row & 7);
                    bf[nt] = *(const bf16x8*)&Ws[row * 64 + slot * 8];
                }
#pragma unroll
                for (int mt = 0; mt < 4; ++mt)
#pragma unroll
                    for (int nt = 0; nt < 4; ++nt)
                        acc1[mt][nt] = __builtin_amdgcn_mfma_f32_16x16x32_bf16(
                            af[mt], bf[nt], acc1[mt][nt], 0, 0, 0);
            }
            __syncthreads();
        }

        // h = relu(acc1 + b1) -> Hs
#pragma unroll
        for (int nt = 0; nt < 4; ++nt) {
            int colL = wn * 64 + nt * 16 + lr;
            float bv = b1[c * 128 + colL];
            int cseg = colL >> 3, coff = colL & 7;
#pragma unroll
            for (int mt = 0; mt < 4; ++mt) {
#pragma unroll
                for (int r = 0; r < 4; ++r) {
                    int row = wm * 64 + mt * 16 + lg * 4 + r;
                    float v = fmaxf(acc1[mt][nt][r] + bv, 0.f);
                    int slot = cseg ^ (row & 7);
                    Hs[row * 128 + slot * 8 + coff] = f2bf(v);
                }
            }
        }

        for (int k0h = 0; k0h < 128; k0h += 64) {
#pragma unroll
            for (int i = 0; i < 4; ++i) {
                int ch = w * 4 + i;
                int row = ch * 8 + srow;
                gload_lds16(W2t + (size_t)row * HIDD + c * 128 + k0h + sseg * 8,
                            Ws + ch * 512);
            }
            __syncthreads();
#pragma unroll
            for (int ks = 0; ks < 2; ++ks) {
                bf16x8 af[4], bf[4];
#pragma unroll
                for (int mt = 0; mt < 4; ++mt) {
                    int row = wm * 64 + mt * 16 + lr;
                    int seg = (k0h >> 3) + ks * 4 + lg;
                    int slot = seg ^ (row & 7);
                    af[mt] = *(const bf16x8*)&Hs[row * 128 + slot * 8];
                }
#pragma unroll
                for (int nt = 0; nt < 4; ++nt) {
                    int row = wn * 64 + nt * 16 + lr;
                    int slot = (ks * 4 + lg) ^ (row & 7);
                    bf[nt] = *(const bf16x8*)&Ws[row * 64 + slot * 8];
                }
#pragma unroll
                for (int mt = 0; mt < 4; ++mt)
#pragma unroll
                    for (int nt = 0; nt < 4; ++nt)
                        acc2[mt][nt] = __builtin_amdgcn_mfma_f32_16x16x32_bf16(
                            af[mt], bf[nt], acc2[mt][nt], 0, 0, 0);
            }
            __syncthreads();
        }
    }

#pragma unroll
    for (int nt = 0; nt < 4; ++nt) {
        int col = wn * 64 + nt * 16 + lr;
        float bv = b2[col];
#pragma unroll
        for (int mt = 0; mt < 4; ++mt) {
#pragma unroll
            for (int r = 0; r < 4; ++r) {
                int row = m0 + wm * 64 + mt * 16 + lg * 4 + r;
                if (row >= M) continue;
                float v = fmaxf(acc2[mt][nt][r] + bv, 0.f);
                if (OUT_BF16) ((ushort_t*)Cv)[(size_t)row * 128 + col] = f2bf(v);
                else ((float*)Cv)[(size_t)row * 128 + col] = v;
            }
        }
    }
}

// ---------------------------------------------------------------------------
// FUSED superedge (SG0-SORTED): out[e] = relu(relu(P0[sg0[e]]+P1[sg1[e]]+b1)@W2+b2)
//   Edges processed in sg0-sorted order (eids2) so consecutive edges share
//   P0 rows -> L1/L2 hits instead of HBM. Output rows scattered by orig id
//   (512B contiguous per row). Hs swizzled as in the GEMM tiles.
// ---------------------------------------------------------------------------
__global__ __launch_bounds__(256) void fused_edge(
    const ushort_t* __restrict__ P0, const ushort_t* __restrict__ P1,
    const float* __restrict__ b1, const ushort_t* __restrict__ W2t,
    const float* __restrict__ b2, float* __restrict__ Cv, int M,
    const int* __restrict__ g0, const int* __restrict__ g1,
    const int* __restrict__ eids2)
{
    __shared__ ushort_t Hs[128 * 128];
    __shared__ ushort_t Ws[128 * 64];
    __shared__ int i0s[128], i1s[128], es[128];

    const int tid = threadIdx.x;
    const int m0 = blockIdx.x * 128;
    const int w = tid >> 6, lane = tid & 63;
    const int wm = w >> 1, wn = w & 1;
    const int lr = lane & 15, lg = lane >> 4;
    const int srow = lane >> 3;
    const int sseg = (lane & 7) ^ srow;
    const int er = lane >> 4;        // edge slot 0..3 within wave
    const int cg = lane & 15;        // 16B segment within 256B chunk row

    if (tid < 128) {
        int gm = m0 + tid; if (gm >= M) gm = M - 1;
        int e = eids2[gm];
        es[tid] = e;
        i0s[tid] = g0[e];
        i1s[tid] = g1[e];
    }
    __syncthreads();

    f32x4 acc2[4][4];
#pragma unroll
    for (int i = 0; i < 4; ++i)
#pragma unroll
        for (int j = 0; j < 4; ++j) acc2[i][j] = (f32x4){0.f, 0.f, 0.f, 0.f};

    for (int c = 0; c < 4; ++c) {
        float bch[8];
#pragma unroll
        for (int j = 0; j < 8; ++j) bch[j] = b1[c * 128 + cg * 8 + j];

        // gather-add-relu into Hs: 16 edges/pass (4 waves x 4 edge slots)
#pragma unroll
        for (int pass = 0; pass < 8; ++pass) {
            int row = pass * 16 + w * 4 + er;
            int i0 = i0s[row], i1 = i1s[row];
            bf16x8 p0 = *(const bf16x8*)(P0 + (size_t)i0 * HIDD + c * 128 + cg * 8);
            bf16x8 p1 = *(const bf16x8*)(P1 + (size_t)i1 * HIDD + c * 128 + cg * 8);
            ushort_t o[8];
#pragma unroll
            for (int j = 0; j < 8; ++j) {
                float v = bf2f((ushort_t)p0[j]) + bf2f((ushort_t)p1[j]) + bch[j];
                o[j] = f2bf(fmaxf(v, 0.f));
            }
            int slot = cg ^ (row & 7);
            *(int4*)&Hs[row * 128 + slot * 8] = *(int4*)o;
        }

        for (int k0h = 0; k0h < 128; k0h += 64) {
#pragma unroll
            for (int i = 0; i < 4; ++i) {
                int ch = w * 4 + i;
                int row = ch * 8 + srow;
                gload_lds16(W2t + (size_t)row * HIDD + c * 128 + k0h + sseg * 8,
                            Ws + ch * 512);
            }
            __syncthreads();   // covers Hs writes + Ws stage
#pragma unroll
            for (int ks = 0; ks < 2; ++ks) {
                bf16x8 af[4], bf[4];
#pragma unroll
                for (int mt = 0; mt < 4; ++mt) {
                    int row = wm * 64 + mt * 16 + lr;
                    int seg = (k0h >> 3) + ks * 4 + lg;
                    int slot = seg ^ (row & 7);
                    af[mt] = *(const bf16x8*)&Hs[row * 128 + slot * 8];
                }
#pragma unroll
                for (int nt = 0; nt < 4; ++nt) {
                    int row = wn * 64 + nt * 16 + lr;
                    int slot = (ks * 4 + lg) ^ (row & 7);
                    bf[nt] = *(const bf16x8*)&Ws[row * 64 + slot * 8];
                }
#pragma unroll
                for (int mt = 0; mt < 4; ++mt)
#pragma unroll
                    for (int nt = 0; nt < 4; ++nt)
                        acc2[mt][nt] = __builtin_amdgcn_mfma_f32_16x16x32_bf16(
                            af[mt], bf[nt], acc2[mt][nt], 0, 0, 0);
            }
            __syncthreads();
        }
    }

#pragma unroll
    for (int nt = 0; nt < 4; ++nt) {
        int col = wn * 64 + nt * 16 + lr;
        float bv = b2[col];
#pragma unroll
        for (int mt = 0; mt < 4; ++mt) {
#pragma unroll
            for (int r = 0; r < 4; ++r) {
                int rowL = wm * 64 + mt * 16 + lg * 4 + r;
                if (m0 + rowL >= M) continue;
                int orow = es[rowL];
                float v = fmaxf(acc2[mt][nt][r] + bv, 0.f);
                Cv[(size_t)orow * 128 + col] = v;
            }
        }
    }
}

// ---------------------------------------------------------------------------
// embeddings = l2norm(h2 @ Wc3 + bc3); THREAD-per-row; h2 bf16.
// ---------------------------------------------------------------------------
__global__ __launch_bounds__(256) void emb_kernel(
    const ushort_t* __restrict__ h2, const float* __restrict__ W,
    const float* __restrict__ bias, float* __restrict__ out, int M)
{
    __shared__ float Wl[HIDD * EMBD];
    for (int i = threadIdx.x; i < HIDD * EMBD; i += 256) Wl[i] = W[i];
    __syncthreads();

    int m = blockIdx.x * 256 + threadIdx.x;
    if (m >= M) return;
    const ushort_t* row = h2 + (size_t)m * HIDD;

    float acc[EMBD] = {};
#pragma unroll 2
    for (int k0 = 0; k0 < HIDD; k0 += 8) {
        bf16x8 v = *(const bf16x8*)(row + k0);
        float f[8];
#pragma unroll
        for (int u = 0; u < 8; ++u) f[u] = bf2f((ushort_t)v[u]);
#pragma unroll
        for (int u = 0; u < 8; ++u) {
            const float* wr = &Wl[(k0 + u) * EMBD];
#pragma unroll
            for (int j = 0; j < EMBD; ++j) acc[j] += f[u] * wr[j];
        }
    }
    float vv[EMBD];
    float ss = 0.f;
#pragma unroll
    for (int j = 0; j < EMBD; ++j) { vv[j] = acc[j] + bias[j]; ss += vv[j] * vv[j]; }
    float inv = 1.f / fmaxf(sqrtf(ss), 1e-12f);
#pragma unroll
    for (int j = 0; j < EMBD; ++j) out[(size_t)m * EMBD + j] = vv[j] * inv;
}

// ---------------------------------------------------------------------------
__global__ void cluster_accum(const float* __restrict__ emb,
                              const int* __restrict__ clusters,
                              float* __restrict__ csums, float* __restrict__ ccnt)
{
    int n = blockIdx.x * 256 + threadIdx.x;
    if (n >= NN) return;
    int c = clusters[n];
    const float4* row = (const float4*)(emb + (size_t)n * EMBD);
    float4 r0 = row[0], r1 = row[1], r2 = row[2];
    float* dst = &csums[(size_t)c * EMBD];
    atomicAdd(&dst[0], r0.x);  atomicAdd(&dst[1], r0.y);
    atomicAdd(&dst[2], r0.z);  atomicAdd(&dst[3], r0.w);
    atomicAdd(&dst[4], r1.x);  atomicAdd(&dst[5], r1.y);
    atomicAdd(&dst[6], r1.z);  atomicAdd(&dst[7], r1.w);
    atomicAdd(&dst[8], r2.x);  atomicAdd(&dst[9], r2.y);
    atomicAdd(&dst[10], r2.z); atomicAdd(&dst[11], r2.w);
    atomicAdd(&ccnt[c], 1.f);
}

__global__ void means_kernel(const float* __restrict__ csums,
                             const float* __restrict__ ccnt,
                             float* __restrict__ means)
{
    int c = blockIdx.x * 256 + threadIdx.x;
    if (c >= NC) return;
    float cv = fmaxf(ccnt[c], 1.f);
    float v[EMBD];
    float ss = 0.f;
#pragma unroll
    for (int j = 0; j < EMBD; ++j) {
        v[j] = csums[(size_t)c * EMBD + j] / cv;
        ss += v[j] * v[j];
    }
    float inv = 1.f / fmaxf(sqrtf(ss), 1e-12f);
#pragma unroll
    for (int j = 0; j < EMBD; ++j) means[(size_t)c * EMBD + j] = v[j] * inv;
}

// ---------------------------------------------------------------------------
__device__ __forceinline__ void block_stats2(float x, float x2, float* s_sum, float* s_sumsq)
{
#pragma unroll
    for (int s = 32; s >= 1; s >>= 1) {
        x += __shfl_xor(x, s, 64);
        x2 += __shfl_xor(x2, s, 64);
    }
    __shared__ float w0[4], w1[4];
    int lane = threadIdx.x & 63, w = threadIdx.x >> 6;
    if (lane == 0) { w0[w] = x; w1[w] = x2; }
    __syncthreads();
    if (threadIdx.x == 0) {
        float a = 0.f, b = 0.f;
        for (int i = 0; i < 4; ++i) { a += w0[i]; b += w1[i]; }
        atomicAdd(s_sum, a);
        atomicAdd(s_sumsq, b);
    }
}

// ---------------------------------------------------------------------------
// sg_lik, 4 edges/thread; fused histogram over sg0 (for superedge sort)
// ---------------------------------------------------------------------------
__global__ __launch_bounds__(256) void sg_lik_kernel(
    const float* __restrict__ means, const int* __restrict__ sg0,
    const int* __restrict__ sg1, float* __restrict__ sg_lik, float* __restrict__ stats,
    int* __restrict__ cnt2)
{
    int base = (blockIdx.x * 256 + threadIdx.x) * 4;
    float xs = 0.f, xs2 = 0.f;
    if (base < NES) {
        int4 a4 = *(const int4*)(sg0 + base);
        int4 b4 = *(const int4*)(sg1 + base);
        int ai[4] = {a4.x, a4.y, a4.z, a4.w};
        int bi[4] = {b4.x, b4.y, b4.z, b4.w};
        float4 av[4][3], bv[4][3];
#pragma unroll
        for (int i = 0; i < 4; ++i) {
            const float4* ap = (const float4*)(means + (size_t)ai[i] * EMBD);
            const float4* bp = (const float4*)(means + (size_t)bi[i] * EMBD);
            av[i][0] = ap[0]; av[i][1] = ap[1]; av[i][2] = ap[2];
            bv[i][0] = bp[0]; bv[i][1] = bp[1]; bv[i][2] = bp[2];
        }
#pragma unroll
        for (int i = 0; i < 4; ++i) atomicAdd(&cnt2[ai[i]], 1);
        float4 o;
        float* op = (float*)&o;
#pragma unroll
        for (int i = 0; i < 4; ++i) {
            float s = av[i][0].x * bv[i][0].x + av[i][0].y * bv[i][0].y
                    + av[i][0].z * bv[i][0].z + av[i][0].w * bv[i][0].w
                    + av[i][1].x * bv[i][1].x + av[i][1].y * bv[i][1].y
                    + av[i][1].z * bv[i][1].z + av[i][1].w * bv[i][1].w
                    + av[i][2].x * bv[i][2].x + av[i][2].y * bv[i][2].y
                    + av[i][2].z * bv[i][2].z + av[i][2].w * bv[i][2].w;
            op[i] = s;
            xs += s; xs2 += s * s;
        }
        *(float4*)(sg_lik + base) = o;
    }
    block_stats2(xs, xs2, &stats[0], &stats[1]);
}

__global__ __launch_bounds__(256) void sgw_kernel(
    const float* __restrict__ sg_lik, const float* __restrict__ stats,
    const float* __restrict__ gamma, const float* __restrict__ beta,
    float* __restrict__ out)
{
    int base = (blockIdx.x * 256 + threadIdx.x) * 4;
    if (base >= NES) return;
    float m = stats[0] / (float)NES;
    float var = stats[1] / (float)NES - m * m;
    float rs = rsqrtf(var + 1e-5f) * gamma[0];
    float4 v = *(const float4*)(sg_lik + base);
    float4 o;
    o.x = 1.f / (1.f + __expf(-((v.x - m) * rs + beta[0])));
    o.y = 1.f / (1.f + __expf(-((v.y - m) * rs + beta[0])));
    o.z = 1.f / (1.f + __expf(-((v.z - m) * rs + beta[0])));
    o.w = 1.f / (1.f + __expf(-((v.w - m) * rs + beta[0])));
    *(float4*)(out + base) = o;
}

// ---------------------------------------------------------------------------
__global__ __launch_bounds__(256) void bg_lik_kernel(
    const float* __restrict__ emb, const float* __restrict__ means,
    const int* __restrict__ bg_src, const int* __restrict__ bg_dst,
    float* __restrict__ bg_lik, float* __restrict__ stats, int* __restrict__ cnt)
{
    int base = (blockIdx.x * 256 + threadIdx.x) * 4;
    float xs = 0.f, xs2 = 0.f;
    if (base < NEB) {
        int4 s4 = *(const int4*)(bg_src + base);
        int4 d4 = *(const int4*)(bg_dst + base);
        int si[4] = {s4.x, s4.y, s4.z, s4.w};
        int di[4] = {d4.x, d4.y, d4.z, d4.w};
        float4 av[4][3], bv[4][3];
#pragma unroll
        for (int i = 0; i < 4; ++i) {
            const float4* ap = (const float4*)(emb + (size_t)si[i] * EMBD);
            const float4* bp = (const float4*)(means + (size_t)di[i] * EMBD);
            av[i][0] = ap[0]; av[i][1] = ap[1]; av[i][2] = ap[2];
            bv[i][0] = bp[0]; bv[i][1] = bp[1]; bv[i][2] = bp[2];
        }
#pragma unroll
        for (int i = 0; i < 4; ++i) atomicAdd(&cnt[di[i]], 1);
        float4 o;
        float* op = (float*)&o;
#pragma unroll
        for (int i = 0; i < 4; ++i) {
            float s = av[i][0].x * bv[i][0].x + av[i][0].y * bv[i][0].y
                    + av[i][0].z * bv[i][0].z + av[i][0].w * bv[i][0].w
                    + av[i][1].x * bv[i][1].x + av[i][1].y * bv[i][1].y
                    + av[i][1].z * bv[i][1].z + av[i][1].w * bv[i][1].w
                    + av[i][2].x * bv[i][2].x + av[i][2].y * bv[i][2].y
                    + av[i][2].z * bv[i][2].z + av[i][2].w * bv[i][2].w;
            op[i] = s;
            xs += s; xs2 += s * s;
        }
        *(float4*)(bg_lik + base) = o;
    }
    block_stats2(xs, xs2, &stats[2], &stats[3]);
}

__global__ __launch_bounds__(256) void bw_kernel(
    const float* __restrict__ bg_lik, const float* __restrict__ stats,
    const float* __restrict__ gamma, const float* __restrict__ beta,
    const int* __restrict__ bg_src, float* __restrict__ bw, float* __restrict__ denom)
{
    int base = (blockIdx.x * 256 + threadIdx.x) * 4;
    if (base >= NEB) return;
    float m = stats[2] / (float)NEB;
    float var = stats[3] / (float)NEB - m * m;
    float rs = rsqrtf(var + 1e-5f) * gamma[0];
    int4 s4 = *(const int4*)(bg_src + base);
    int si[4] = {s4.x, s4.y, s4.z, s4.w};
    float4 v = *(const float4*)(bg_lik + base);
    float vi[4] = {v.x, v.y, v.z, v.w};
    float4 o;
    float* op = (float*)&o;
#pragma unroll
    for (int i = 0; i < 4; ++i) {
        float w = __expf((vi[i] - m) * rs + beta[0]);
        op[i] = w;
        atomicAdd(&denom[si[i]], w);
    }
    *(float4*)(bw + base) = o;
}

__global__ __launch_bounds__(256) void bw_norm_kernel(
    float* __restrict__ bw, const float* __restrict__ denom,
    const int* __restrict__ bg_src, float* __restrict__ out)
{
    int base = (blockIdx.x * 256 + threadIdx.x) * 4;
    if (base >= NEB) return;
    int4 s4 = *(const int4*)(bg_src + base);
    int si[4] = {s4.x, s4.y, s4.z, s4.w};
    float dv[4];
#pragma unroll
    for (int i = 0; i < 4; ++i) dv[i] = denom[si[i]];
    float4 v = *(const float4*)(bw + base);
    float4 o;
    o.x = v.x / (1e-12f + dv[0]);
    o.y = v.y / (1e-12f + dv[1]);
    o.z = v.z / (1e-12f + dv[2]);
    o.w = v.w / (1e-12f + dv[3]);
    *(float4*)(bw + base) = o;
    *(float4*)(out + base) = o;
}

// ---------------------------------------------------------------------------
// dual scan: block 0 scans (cntA -> offsA), block 1 scans (cntB -> offsB)
// ---------------------------------------------------------------------------
__global__ __launch_bounds__(1024) void scan2_kernel(
    const int* __restrict__ cntA, int* __restrict__ offsA,
    const int* __restrict__ cntB, int* __restrict__ offsB, int C)
{
    const int* cnt = blockIdx.x ? cntB : cntA;
    int* offs = blockIdx.x ? offsB : offsA;
    __shared__ int wsum[16];
    __shared__ int carry_s, ctot_s;
    const int tid = threadIdx.x;
    const int lane = tid & 63, w = tid >> 6;
    if (tid == 0) carry_s = 0;
    __syncthreads();
    for (int base = 0; base < C; base += 1024) {
        int i = base + tid;
        int v = (i < C) ? cnt[i] : 0;
        int x = v;
#pragma unroll
        for (int s = 1; s < 64; s <<= 1) {
            int y = __shfl_up(x, s, 64);
            if (lane >= s) x += y;
        }
        if (lane == 63) wsum[w] = x;
        __syncthreads();
        if (tid == 0) {
            int s = 0;
            for (int k = 0; k < 16; ++k) { int t = wsum[k]; wsum[k] = s; s += t; }
            ctot_s = s;
        }
        __syncthreads();
        int excl = carry_s + wsum[w] + (x - v);
        if (i < C) offs[i] = excl;
        __syncthreads();
        if (tid == 0) carry_s += ctot_s;
        __syncthreads();
    }
    if (tid == 0) offs[C] = carry_s;
}

__global__ void scatter_kernel(const int* __restrict__ bg_dst,
                               const int* __restrict__ offs,
                               int* __restrict__ fill, int* __restrict__ eids)
{
    int base = (blockIdx.x * 256 + threadIdx.x) * 4;
    if (base >= NEB) return;
    int4 d4 = *(const int4*)(bg_dst + base);
    int di[4] = {d4.x, d4.y, d4.z, d4.w};
#pragma unroll
    for (int i = 0; i < 4; ++i) {
        int p = atomicAdd(&fill[di[i]], 1);
        eids[offs[di[i]] + p] = base + i;
    }
}

__global__ void scatter_sg_kernel(const int* __restrict__ sg0,
                                  const int* __restrict__ offs2,
                                  int* __restrict__ fill2, int* __restrict__ eids2)
{
    int base = (blockIdx.x * 256 + threadIdx.x) * 4;
    if (base >= NES) return;
    int4 d4 = *(const int4*)(sg0 + base);
    int di[4] = {d4.x, d4.y, d4.z, d4.w};
#pragma unroll
    for (int i = 0; i < 4; ++i) {
        int p = atomicAdd(&fill2[di[i]], 1);
        eids2[offs2[di[i]] + p] = base + i;
    }
}

// ---------------------------------------------------------------------------
// supernodes: lane-packed gather (16 lanes x 16B = one 256B row per instr)
// ---------------------------------------------------------------------------
__global__ __launch_bounds__(256) void supernodes_kernel(
    const ushort_t* __restrict__ nmsg, const float* __restrict__ bw,
    const int* __restrict__ bg_src, const int* __restrict__ eids,
    const int* __restrict__ offs, float* __restrict__ sn)
{
    __shared__ float red[4][LATD];
    const int c = blockIdx.x;
    const int tid = threadIdx.x;
    const int wv = tid >> 6, lane = tid & 63;
    const int er = lane >> 4;
    const int cg = lane & 15;
    const int beg = offs[c], end = offs[c + 1];

    float acc[8] = {};
    for (int p = beg + wv * 4 + er; p < end; p += 16) {
        int e = eids[p];
        int s = bg_src[e];
        float w = bw[e];
        bf16x8 v = *(const bf16x8*)(nmsg + (size_t)s * LATD + cg * 8);
#pragma unroll
        for (int j = 0; j < 8; ++j) acc[j] += w * bf2f((ushort_t)v[j]);
    }
#pragma unroll
    for (int j = 0; j < 8; ++j) {
        acc[j] += __shfl_xor(acc[j], 16, 64);
        acc[j] += __shfl_xor(acc[j], 32, 64);
    }
    if (lane < 16) {
        *(float4*)&red[wv][cg * 8]     = (float4){acc[0], acc[1], acc[2], acc[3]};
        *(float4*)&red[wv][cg * 8 + 4] = (float4){acc[4], acc[5], acc[6], acc[7]};
    }
    __syncthreads();
    if (tid < LATD) {
        float s = red[0][tid] + red[1][tid] + red[2][tid] + red[3][tid];
        sn[(size_t)c * LATD + tid] = s;
    }
}

// ---------------------------------------------------------------------------
extern "C" void kernel_launch(void* const* d_in, const int* in_sizes, int n_in,
                              void* d_out, int out_size, void* d_ws, size_t ws_size,
                              hipStream_t stream)
{
    const float* emb_nodes = (const float*)d_in[0];
    const float* enc_nodes = (const float*)d_in[1];
    const float* Wc1 = (const float*)d_in[2];  const float* bc1 = (const float*)d_in[3];
    const float* Wc2 = (const float*)d_in[4];  const float* bc2 = (const float*)d_in[5];
    const float* Wc3 = (const float*)d_in[6];  const float* bc3 = (const float*)d_in[7];
    const float* Wn1 = (const float*)d_in[8];  const float* cn1 = (const float*)d_in[9];
    const float* Wn2 = (const float*)d_in[10]; const float* cn2 = (const float*)d_in[11];
    const float* We1 = (const float*)d_in[12]; const float* ce1 = (const float*)d_in[13];
    const float* We2 = (const float*)d_in[14]; const float* ce2 = (const float*)d_in[15];
    const float* sg_gamma = (const float*)d_in[16]; const float* sg_beta = (const float*)d_in[17];
    const float* bg_gamma = (const float*)d_in[18]; const float* bg_beta = (const float*)d_in[19];
    const int* clusters = (const int*)d_in[20];
    const int* sg0 = (const int*)d_in[21];
    const int* sg1 = sg0 + NES;
    const int* bg_src = (const int*)d_in[22];
    const int* bg_dst = (const int*)d_in[23];

    // output layout (flat, return order)
    float* out_emb = (float*)d_out;                       // NN*EMBD
    float* out_sn  = out_emb + (size_t)NN * EMBD;         // NC*LATD
    float* out_se  = out_sn + (size_t)NC * LATD;          // NES*LATD
    float* out_bw  = out_se + (size_t)NES * LATD;         // NEB
    float* out_sew = out_bw + (size_t)NEB;                // NES

    // ---------------- workspace layout (byte cursor, 64B-aligned) ----------
    uintptr_t cur = (uintptr_t)d_ws;
    uintptr_t wend = cur + ws_size;
    auto alloc = [&](size_t bytes) -> void* {
        cur = (cur + 63) & ~(uintptr_t)63;
        void* p = (void*)cur;
        cur += bytes;
        return p;
    };

    // zeroed region: csums, ccnt, denom, stats, cnt, fill, cnt2, fill2, zbias
    size_t zfloats = (size_t)NC * EMBD + NC + NN + 8 + NC + NC + NC + NC + HIDD;
    float* zbase = (float*)alloc(zfloats * 4);
    float* csums = zbase;
    float* ccnt  = csums + (size_t)NC * EMBD;
    float* denom = ccnt + NC;
    float* stats = denom + NN;
    int*   cnt   = (int*)(stats + 8);
    int*   fill  = cnt + NC;
    int*   cnt2  = fill + NC;
    int*   fill2 = cnt2 + NC;
    float* zbias = (float*)(fill2 + NC);        // HIDD zeros
    size_t zero_bytes = zfloats * 4;

    float* means  = (float*)alloc((size_t)NC * EMBD * 4);
    float* sg_lik = (float*)alloc((size_t)NES * 4);
    float* bg_lik = (float*)alloc((size_t)NEB * 4);
    float* bwv    = (float*)alloc((size_t)NEB * 4);
    int*   offs   = (int*)alloc((size_t)(NC + 1) * 4);
    int*   eids   = (int*)alloc((size_t)NEB * 4);
    int*   offs2  = (int*)alloc((size_t)(NC + 1) * 4);
    int*   eids2  = (int*)alloc((size_t)NES * 4);

    ushort_t* xemb   = (ushort_t*)alloc((size_t)NN * LATD * 2);
    ushort_t* xenc   = (ushort_t*)alloc((size_t)NN * LATD * 2);
    ushort_t* nmsgb  = (ushort_t*)alloc((size_t)NN * LATD * 2);
    ushort_t* sn_bf  = (ushort_t*)alloc((size_t)NC * LATD * 2);
    ushort_t* P0b    = (ushort_t*)alloc((size_t)NC * HIDD * 2);
    ushort_t* P1b    = (ushort_t*)alloc((size_t)NC * HIDD * 2);
    ushort_t* Wc1t  = (ushort_t*)alloc((size_t)LATD * HIDD * 2);
    ushort_t* Wc2t  = (ushort_t*)alloc((size_t)HIDD * HIDD * 2);
    ushort_t* Wn1t  = (ushort_t*)alloc((size_t)LATD * HIDD * 2);
    ushort_t* Wn2t  = (ushort_t*)alloc((size_t)HIDD * LATD * 2);
    ushort_t* We1tA = (ushort_t*)alloc((size_t)HIDD * LATD * 2);  // [512][128]
    ushort_t* We1tB = (ushort_t*)alloc((size_t)HIDD * LATD * 2);  // [512][128]
    ushort_t* We2t  = (ushort_t*)alloc((size_t)HIDD * LATD * 2);  // [128][512]

    cur = (cur + 63) & ~(uintptr_t)63;
    size_t rem_bytes = (wend > cur) ? (size_t)(wend - cur) : 0;
    size_t chunk_sz = (rem_bytes / (2 * (size_t)HIDD * 2)) & ~(size_t)127;
    if (chunk_sz > 51200) chunk_sz = 51200;
    if (chunk_sz < 256) return;  // fail soft
    const int CH = (int)chunk_sz;
    ushort_t* bufA = (ushort_t*)cur;
    ushort_t* bufB = bufA + (size_t)CH * HIDD;

    hipMemsetAsync(zbase, 0, zero_bytes, stream);

    dim3 blk(256);

    // ---- prep: input/weight conversions ----
    conv_f2b_kernel<<<2048, blk, 0, stream>>>(emb_nodes, xemb, (long)NN * LATD);
    conv_f2b_kernel<<<2048, blk, 0, stream>>>(enc_nodes, xenc, (long)NN * LATD);
    transpose_conv_kernel<<<(LATD * HIDD + 255) / 256, blk, 0, stream>>>(Wc1, Wc1t, LATD, HIDD);
    transpose_conv_kernel<<<(HIDD * HIDD + 255) / 256, blk, 0, stream>>>(Wc2, Wc2t, HIDD, HIDD);
    transpose_conv_kernel<<<(LATD * HIDD + 255) / 256, blk, 0, stream>>>(Wn1, Wn1t, LATD, HIDD);
    transpose_conv_kernel<<<(HIDD * LATD + 255) / 256, blk, 0, stream>>>(Wn2, Wn2t, HIDD, LATD);
    transpose_conv_kernel<<<(LATD * HIDD + 255) / 256, blk, 0, stream>>>(We1, We1tA, LATD, HIDD);
    transpose_conv_kernel<<<(LATD * HIDD + 255) / 256, blk, 0, stream>>>(We1 + (size_t)LATD * HIDD, We1tB, LATD, HIDD);
    transpose_conv_kernel<<<(HIDD * LATD + 255) / 256, blk, 0, stream>>>(We2, We2t, HIDD, LATD);

    // ---- fused node chain, chunked: xemb->h1->h2->embeddings ----
    for (int m0 = 0; m0 < NN; m0 += CH) {
        int cm = (NN - m0 < CH) ? (NN - m0) : CH;
        gemm_mfma<ACT_TANH, true><<<dim3(HIDD / 128, (cm + 127) / 128), blk, 0, stream>>>(
            xemb + (size_t)m0 * LATD, Wc1t, bc1, bufA, cm, HIDD, LATD);
        gemm_mfma<ACT_TANH, true><<<dim3(HIDD / 128, (cm + 127) / 128), blk, 0, stream>>>(
            bufA, Wc2t, bc2, bufB, cm, HIDD, HIDD);
        emb_kernel<<<(cm + 255) / 256, blk, 0, stream>>>(
            bufB, Wc3, bc3, out_emb + (size_t)m0 * EMBD, cm);
    }

    // ---- cluster means ----
    cluster_accum<<<(NN + 255) / 256, blk, 0, stream>>>(out_emb, clusters, csums, ccnt);
    means_kernel<<<(NC + 255) / 256, blk, 0, stream>>>(csums, ccnt, means);

    // ---- super edge weights (4 edges/thread; sg0 histogram fused) ----
    sg_lik_kernel<<<(NES / 4 + 255) / 256, blk, 0, stream>>>(means, sg0, sg1, sg_lik, stats, cnt2);
    sgw_kernel<<<(NES / 4 + 255) / 256, blk, 0, stream>>>(sg_lik, stats, sg_gamma, sg_beta, out_sew);

    // ---- bipartite edge weights (hist fused; 4 edges/thread) ----
    bg_lik_kernel<<<(NEB / 4 + 255) / 256, blk, 0, stream>>>(out_emb, means, bg_src, bg_dst, bg_lik, stats, cnt);
    bw_kernel<<<(NEB / 4 + 255) / 256, blk, 0, stream>>>(bg_lik, stats, bg_gamma, bg_beta, bg_src, bwv, denom);
    bw_norm_kernel<<<(NEB / 4 + 255) / 256, blk, 0, stream>>>(bwv, denom, bg_src, out_bw);

    // ---- counting sorts: bipartite edges by bg_dst, superedges by sg0 ----
    scan2_kernel<<<2, 1024, 0, stream>>>(cnt, offs, cnt2, offs2, NC);
    scatter_kernel<<<(NEB / 4 + 255) / 256, blk, 0, stream>>>(bg_dst, offs, fill, eids);
    scatter_sg_kernel<<<(NES / 4 + 255) / 256, blk, 0, stream>>>(sg0, offs2, fill2, eids2);

    // ---- node messages: FUSED relu(relu(xenc@Wn1)@Wn2) -> nmsgb (bf16) ----
    fused_mlp<true><<<(NN + 127) / 128, blk, 0, stream>>>(
        xenc, Wn1t, cn1, Wn2t, cn2, nmsgb, NN);

    // ---- supernodes (sorted edge lists, no atomics; lane-packed gather) ----
    supernodes_kernel<<<NC, blk, 0, stream>>>(nmsgb, bwv, bg_src, eids, offs, out_sn);
    conv_f2b_kernel<<<512, blk, 0, stream>>>(out_sn, sn_bf, (long)NC * LATD);

    // ---- premultiply: P0 = sn@We1_top, P1 = sn@We1_bot (no bias/act) ----
    gemm_mfma<ACT_NONE, true><<<dim3(HIDD / 128, (NC + 127) / 128), blk, 0, stream>>>(
        sn_bf, We1tA, zbias, P0b, NC, HIDD, LATD);
    gemm_mfma<ACT_NONE, true><<<dim3(HIDD / 128, (NC + 127) / 128), blk, 0, stream>>>(
        sn_bf, We1tB, zbias, P1b, NC, HIDD, LATD);

    // ---- superedges: FUSED, sg0-sorted gather order ----
    fused_edge<<<(NES + 127) / 128, blk, 0, stream>>>(
        P0b, P1b, ce1, We2t, ce2, out_se, NES, sg0, sg1, eids2);
}

// Round 12
// 888.763 us; speedup vs baseline: 1.0808x; 1.0808x over previous
//
#include <hip/hip_runtime.h>
#include <cstdint>
#include <cstddef>

// Problem constants (SuperGraphConstruction)
#define NN 100000      // nodes
#define NC 20000       // clusters
#define LATD 128
#define HIDD 512
#define EMBD 12
#define NES 160000     // super edges
#define NEB 800000     // bipartite edges

enum { ACT_NONE = 0, ACT_TANH = 1, ACT_RELU = 2 };

typedef __attribute__((ext_vector_type(8))) short bf16x8;
typedef __attribute__((ext_vector_type(4))) float f32x4;
typedef unsigned short ushort_t;

__device__ __forceinline__ float fast_tanh(float x) {
    return 1.f - 2.f / (__expf(2.f * x) + 1.f);
}
__device__ __forceinline__ ushort_t f2bf(float f) {
    union { float f; unsigned u; } x; x.f = f;
    unsigned r = x.u + 0x7FFFu + ((x.u >> 16) & 1u);  // RNE
    return (ushort_t)(r >> 16);
}
__device__ __forceinline__ float bf2f(ushort_t h) {
    union { unsigned u; float f; } x; x.u = ((unsigned)h) << 16;
    return x.f;
}

typedef __attribute__((address_space(1))) void gvoid_t;
typedef __attribute__((address_space(3))) void svoid_t;
__device__ __forceinline__ void gload_lds16(const void* g, void* l) {
    __builtin_amdgcn_global_load_lds((gvoid_t*)g, (svoid_t*)l, 16, 0, 0);
}

// ---------------------------------------------------------------------------
__global__ __launch_bounds__(256) void conv_f2b_kernel(
    const float* __restrict__ in, ushort_t* __restrict__ out, long n)
{
    long i = ((long)blockIdx.x * 256 + threadIdx.x) * 8;
    long stride = (long)gridDim.x * 256 * 8;
    for (; i + 7 < n; i += stride) {
        float4 a = *(const float4*)(in + i);
        float4 b = *(const float4*)(in + i + 4);
        ushort_t o[8] = { f2bf(a.x), f2bf(a.y), f2bf(a.z), f2bf(a.w),
                          f2bf(b.x), f2bf(b.y), f2bf(b.z), f2bf(b.w) };
        *(int4*)(out + i) = *(int4*)o;
    }
}

// W [K][N] fp32 -> Wt [N][K] bf16
__global__ __launch_bounds__(256) void transpose_conv_kernel(
    const float* __restrict__ W, ushort_t* __restrict__ Wt, int K, int N)
{
    int i = blockIdx.x * 256 + threadIdx.x;
    if (i >= K * N) return;
    int n = i / K, k = i % K;
    Wt[i] = f2bf(W[(size_t)k * N + n]);
}

// ---------------------------------------------------------------------------
// bf16 MFMA GEMM (m97 + T2 swizzle)
// ---------------------------------------------------------------------------
template<int ACT, bool OUT_BF16>
__global__ __launch_bounds__(256) void gemm_mfma(
    const ushort_t* __restrict__ A, const ushort_t* __restrict__ Bt,
    const float* __restrict__ bias, void* __restrict__ Cv,
    int M, int N, int K)
{
    __shared__ ushort_t As[128 * 64];
    __shared__ ushort_t Bs[128 * 64];

    const int tid = threadIdx.x;
    const int m0 = blockIdx.y * 128, n0 = blockIdx.x * 128;
    const int w = tid >> 6, lane = tid & 63;
    const int wm = w >> 1, wn = w & 1;
    const int lr = lane & 15, lg = lane >> 4;
    const int srow = lane >> 3;
    const int sseg = (lane & 7) ^ srow;

    f32x4 acc[4][4];
#pragma unroll
    for (int i = 0; i < 4; ++i)
#pragma unroll
        for (int j = 0; j < 4; ++j) acc[i][j] = (f32x4){0.f, 0.f, 0.f, 0.f};

    for (int k0 = 0; k0 < K; k0 += 64) {
#pragma unroll
        for (int i = 0; i < 4; ++i) {
            int c = w * 4 + i;
            int row = c * 8 + srow;
            int gm = m0 + row; if (gm >= M) gm = M - 1;
            gload_lds16(A + (size_t)gm * K + k0 + sseg * 8, As + c * 512);
            gload_lds16(Bt + (size_t)(n0 + row) * K + k0 + sseg * 8, Bs + c * 512);
        }
        __syncthreads();
#pragma unroll
        for (int ks = 0; ks < 2; ++ks) {
            bf16x8 af[4], bf[4];
#pragma unroll
            for (int mt = 0; mt < 4; ++mt) {
                int row = wm * 64 + mt * 16 + lr;
                int slot = (ks * 4 + lg) ^ (row & 7);
                af[mt] = *(const bf16x8*)&As[row * 64 + slot * 8];
            }
#pragma unroll
            for (int nt = 0; nt < 4; ++nt) {
                int row = wn * 64 + nt * 16 + lr;
                int slot = (ks * 4 + lg) ^ (row & 7);
                bf[nt] = *(const bf16x8*)&Bs[row * 64 + slot * 8];
            }
#pragma unroll
            for (int mt = 0; mt < 4; ++mt)
#pragma unroll
                for (int nt = 0; nt < 4; ++nt)
                    acc[mt][nt] = __builtin_amdgcn_mfma_f32_16x16x32_bf16(
                        af[mt], bf[nt], acc[mt][nt], 0, 0, 0);
        }
        __syncthreads();
    }

#pragma unroll
    for (int nt = 0; nt < 4; ++nt) {
        int col = n0 + wn * 64 + nt * 16 + lr;
        float bv = bias[col];
#pragma unroll
        for (int mt = 0; mt < 4; ++mt) {
#pragma unroll
            for (int r = 0; r < 4; ++r) {
                int row = m0 + wm * 64 + mt * 16 + lg * 4 + r;
                if (row >= M) continue;
                float v = acc[mt][nt][r] + bv;
                if (ACT == ACT_TANH) v = fast_tanh(v);
                else if (ACT == ACT_RELU) v = fmaxf(v, 0.f);
                if (OUT_BF16) ((ushort_t*)Cv)[(size_t)row * N + col] = f2bf(v);
                else ((float*)Cv)[(size_t)row * N + col] = v;
            }
        }
    }
}

// ---------------------------------------------------------------------------
// FUSED 2-layer MLP (node messages): out = relu(relu(A@W1+b1)@W2+b2)
// ---------------------------------------------------------------------------
template<bool OUT_BF16>
__global__ __launch_bounds__(256) void fused_mlp(
    const ushort_t* __restrict__ A, const ushort_t* __restrict__ W1t,
    const float* __restrict__ b1, const ushort_t* __restrict__ W2t,
    const float* __restrict__ b2, void* __restrict__ Cv, int M)
{
    __shared__ ushort_t As[128 * 128];
    __shared__ ushort_t Ws[128 * 64];
    __shared__ ushort_t Hs[128 * 128];

    const int tid = threadIdx.x;
    const int m0 = blockIdx.x * 128;
    const int w = tid >> 6, lane = tid & 63;
    const int wm = w >> 1, wn = w & 1;
    const int lr = lane & 15, lg = lane >> 4;
    const int srow = lane >> 3;
    const int sseg = (lane & 7) ^ srow;

    f32x4 acc2[4][4];
#pragma unroll
    for (int i = 0; i < 4; ++i)
#pragma unroll
        for (int j = 0; j < 4; ++j) acc2[i][j] = (f32x4){0.f, 0.f, 0.f, 0.f};

    {   // stage A resident: [128][128], 16-slot swizzled rows
        const int arow4 = lane >> 4;
        const int aslot = lane & 15;
#pragma unroll
        for (int rnd = 0; rnd < 8; ++rnd) {
            int row = rnd * 16 + w * 4 + arow4;
            int gm = m0 + row; if (gm >= M) gm = M - 1;
            int seg = aslot ^ (row & 7);
            gload_lds16(A + (size_t)gm * 128 + seg * 8, As + row * 128);
        }
    }

    for (int c = 0; c < 4; ++c) {
        f32x4 acc1[4][4];
#pragma unroll
        for (int i = 0; i < 4; ++i)
#pragma unroll
            for (int j = 0; j < 4; ++j) acc1[i][j] = (f32x4){0.f, 0.f, 0.f, 0.f};

        for (int k0 = 0; k0 < 128; k0 += 64) {
#pragma unroll
            for (int i = 0; i < 4; ++i) {
                int ch = w * 4 + i;
                int row = ch * 8 + srow;
                gload_lds16(W1t + (size_t)(c * 128 + row) * 128 + k0 + sseg * 8,
                            Ws + ch * 512);
            }
            __syncthreads();
#pragma unroll
            for (int ks = 0; ks < 2; ++ks) {
                bf16x8 af[4], bf[4];
#pragma unroll
                for (int mt = 0; mt < 4; ++mt) {
                    int row = wm * 64 + mt * 16 + lr;
                    int seg = (k0 >> 3) + ks * 4 + lg;
                    int slot = seg ^ (row & 7);
                    af[mt] = *(const bf16x8*)&As[row * 128 + slot * 8];
                }
#pragma unroll
                for (int nt = 0; nt < 4; ++nt) {
                    int row = wn * 64 + nt * 16 + lr;
                    int slot = (ks * 4 + lg) ^ (row & 7);
                    bf[nt] = *(const bf16x8*)&Ws[row * 64 + slot * 8];
                }
#pragma unroll
                for (int mt = 0; mt < 4; ++mt)
#pragma unroll
                    for (int nt = 0; nt < 4; ++nt)
                        acc1[mt][nt] = __builtin_amdgcn_mfma_f32_16x16x32_bf16(
                            af[mt], bf[nt], acc1[mt][nt], 0, 0, 0);
            }
            __syncthreads();
        }

        // h = relu(acc1 + b1) -> Hs
#pragma unroll
        for (int nt = 0; nt < 4; ++nt) {
            int colL = wn * 64 + nt * 16 + lr;
            float bv = b1[c * 128 + colL];
            int cseg = colL >> 3, coff = colL & 7;
#pragma unroll
            for (int mt = 0; mt < 4; ++mt) {
#pragma unroll
                for (int r = 0; r < 4; ++r) {
                    int row = wm * 64 + mt * 16 + lg * 4 + r;
                    float v = fmaxf(acc1[mt][nt][r] + bv, 0.f);
                    int slot = cseg ^ (row & 7);
                    Hs[row * 128 + slot * 8 + coff] = f2bf(v);
                }
            }
        }

        for (int k0h = 0; k0h < 128; k0h += 64) {
#pragma unroll
            for (int i = 0; i < 4; ++i) {
                int ch = w * 4 + i;
                int row = ch * 8 + srow;
                gload_lds16(W2t + (size_t)row * HIDD + c * 128 + k0h + sseg * 8,
                            Ws + ch * 512);
            }
            __syncthreads();
#pragma unroll
            for (int ks = 0; ks < 2; ++ks) {
                bf16x8 af[4], bf[4];
#pragma unroll
                for (int mt = 0; mt < 4; ++mt) {
                    int row = wm * 64 + mt * 16 + lr;
                    int seg = (k0h >> 3) + ks * 4 + lg;
                    int slot = seg ^ (row & 7);
                    af[mt] = *(const bf16x8*)&Hs[row * 128 + slot * 8];
                }
#pragma unroll
                for (int nt = 0; nt < 4; ++nt) {
                    int row = wn * 64 + nt * 16 + lr;
                    int slot = (ks * 4 + lg) ^ (row & 7);
                    bf[nt] = *(const bf16x8*)&Ws[row * 64 + slot * 8];
                }
#pragma unroll
                for (int mt = 0; mt < 4; ++mt)
#pragma unroll
                    for (int nt = 0; nt < 4; ++nt)
                        acc2[mt][nt] = __builtin_amdgcn_mfma_f32_16x16x32_bf16(
                            af[mt], bf[nt], acc2[mt][nt], 0, 0, 0);
            }
            __syncthreads();
        }
    }

#pragma unroll
    for (int nt = 0; nt < 4; ++nt) {
        int col = wn * 64 + nt * 16 + lr;
        float bv = b2[col];
#pragma unroll
        for (int mt = 0; mt < 4; ++mt) {
#pragma unroll
            for (int r = 0; r < 4; ++r) {
                int row = m0 + wm * 64 + mt * 16 + lg * 4 + r;
                if (row >= M) continue;
                float v = fmaxf(acc2[mt][nt][r] + bv, 0.f);
                if (OUT_BF16) ((ushort_t*)Cv)[(size_t)row * 128 + col] = f2bf(v);
                else ((float*)Cv)[(size_t)row * 128 + col] = v;
            }
        }
    }
}

// ---------------------------------------------------------------------------
// FUSED superedge: out[e] = relu(relu(P0[sg0[e]]+P1[sg1[e]]+b1)@W2+b2)
//   Unsorted (streaming writes); P0/P1 gathers lane-packed (16x16B/row).
// ---------------------------------------------------------------------------
__global__ __launch_bounds__(256) void fused_edge(
    const ushort_t* __restrict__ P0, const ushort_t* __restrict__ P1,
    const float* __restrict__ b1, const ushort_t* __restrict__ W2t,
    const float* __restrict__ b2, float* __restrict__ Cv, int M,
    const int* __restrict__ g0, const int* __restrict__ g1)
{
    __shared__ ushort_t Hs[128 * 128];
    __shared__ ushort_t Ws[128 * 64];
    __shared__ int i0s[128], i1s[128];

    const int tid = threadIdx.x;
    const int m0 = blockIdx.x * 128;
    const int w = tid >> 6, lane = tid & 63;
    const int wm = w >> 1, wn = w & 1;
    const int lr = lane & 15, lg = lane >> 4;
    const int srow = lane >> 3;
    const int sseg = (lane & 7) ^ srow;
    const int er = lane >> 4;        // edge slot 0..3 within wave
    const int cg = lane & 15;        // 16B segment within 256B chunk row

    if (tid < 128) {
        int gm = m0 + tid; if (gm >= M) gm = M - 1;
        i0s[tid] = g0[gm];
        i1s[tid] = g1[gm];
    }
    __syncthreads();

    f32x4 acc2[4][4];
#pragma unroll
    for (int i = 0; i < 4; ++i)
#pragma unroll
        for (int j = 0; j < 4; ++j) acc2[i][j] = (f32x4){0.f, 0.f, 0.f, 0.f};

    for (int c = 0; c < 4; ++c) {
        float bch[8];
#pragma unroll
        for (int j = 0; j < 8; ++j) bch[j] = b1[c * 128 + cg * 8 + j];

        // gather-add-relu into Hs: 16 edges/pass (4 waves x 4 edge slots)
#pragma unroll
        for (int pass = 0; pass < 8; ++pass) {
            int row = pass * 16 + w * 4 + er;
            int i0 = i0s[row], i1 = i1s[row];
            bf16x8 p0 = *(const bf16x8*)(P0 + (size_t)i0 * HIDD + c * 128 + cg * 8);
            bf16x8 p1 = *(const bf16x8*)(P1 + (size_t)i1 * HIDD + c * 128 + cg * 8);
            ushort_t o[8];
#pragma unroll
            for (int j = 0; j < 8; ++j) {
                float v = bf2f((ushort_t)p0[j]) + bf2f((ushort_t)p1[j]) + bch[j];
                o[j] = f2bf(fmaxf(v, 0.f));
            }
            int slot = cg ^ (row & 7);
            *(int4*)&Hs[row * 128 + slot * 8] = *(int4*)o;
        }

        for (int k0h = 0; k0h < 128; k0h += 64) {
#pragma unroll
            for (int i = 0; i < 4; ++i) {
                int ch = w * 4 + i;
                int row = ch * 8 + srow;
                gload_lds16(W2t + (size_t)row * HIDD + c * 128 + k0h + sseg * 8,
                            Ws + ch * 512);
            }
            __syncthreads();   // covers Hs writes + Ws stage
#pragma unroll
            for (int ks = 0; ks < 2; ++ks) {
                bf16x8 af[4], bf[4];
#pragma unroll
                for (int mt = 0; mt < 4; ++mt) {
                    int row = wm * 64 + mt * 16 + lr;
                    int seg = (k0h >> 3) + ks * 4 + lg;
                    int slot = seg ^ (row & 7);
                    af[mt] = *(const bf16x8*)&Hs[row * 128 + slot * 8];
                }
#pragma unroll
                for (int nt = 0; nt < 4; ++nt) {
                    int row = wn * 64 + nt * 16 + lr;
                    int slot = (ks * 4 + lg) ^ (row & 7);
                    bf[nt] = *(const bf16x8*)&Ws[row * 64 + slot * 8];
                }
#pragma unroll
                for (int mt = 0; mt < 4; ++mt)
#pragma unroll
                    for (int nt = 0; nt < 4; ++nt)
                        acc2[mt][nt] = __builtin_amdgcn_mfma_f32_16x16x32_bf16(
                            af[mt], bf[nt], acc2[mt][nt], 0, 0, 0);
            }
            __syncthreads();
        }
    }

#pragma unroll
    for (int nt = 0; nt < 4; ++nt) {
        int col = wn * 64 + nt * 16 + lr;
        float bv = b2[col];
#pragma unroll
        for (int mt = 0; mt < 4; ++mt) {
#pragma unroll
            for (int r = 0; r < 4; ++r) {
                int row = m0 + wm * 64 + mt * 16 + lg * 4 + r;
                if (row >= M) continue;
                float v = fmaxf(acc2[mt][nt][r] + bv, 0.f);
                Cv[(size_t)row * 128 + col] = v;
            }
        }
    }
}

// ---------------------------------------------------------------------------
// embeddings = l2norm(h2 @ Wc3 + bc3); THREAD-per-row; h2 bf16.
// ---------------------------------------------------------------------------
__global__ __launch_bounds__(256) void emb_kernel(
    const ushort_t* __restrict__ h2, const float* __restrict__ W,
    const float* __restrict__ bias, float* __restrict__ out, int M)
{
    __shared__ float Wl[HIDD * EMBD];
    for (int i = threadIdx.x; i < HIDD * EMBD; i += 256) Wl[i] = W[i];
    __syncthreads();

    int m = blockIdx.x * 256 + threadIdx.x;
    if (m >= M) return;
    const ushort_t* row = h2 + (size_t)m * HIDD;

    float acc[EMBD] = {};
#pragma unroll 2
    for (int k0 = 0; k0 < HIDD; k0 += 8) {
        bf16x8 v = *(const bf16x8*)(row + k0);
        float f[8];
#pragma unroll
        for (int u = 0; u < 8; ++u) f[u] = bf2f((ushort_t)v[u]);
#pragma unroll
        for (int u = 0; u < 8; ++u) {
            const float* wr = &Wl[(k0 + u) * EMBD];
#pragma unroll
            for (int j = 0; j < EMBD; ++j) acc[j] += f[u] * wr[j];
        }
    }
    float vv[EMBD];
    float ss = 0.f;
#pragma unroll
    for (int j = 0; j < EMBD; ++j) { vv[j] = acc[j] + bias[j]; ss += vv[j] * vv[j]; }
    float inv = 1.f / fmaxf(sqrtf(ss), 1e-12f);
#pragma unroll
    for (int j = 0; j < EMBD; ++j) out[(size_t)m * EMBD + j] = vv[j] * inv;
}

// ---------------------------------------------------------------------------
__global__ void cluster_accum(const float* __restrict__ emb,
                              const int* __restrict__ clusters,
                              float* __restrict__ csums, float* __restrict__ ccnt)
{
    int n = blockIdx.x * 256 + threadIdx.x;
    if (n >= NN) return;
    int c = clusters[n];
    const float4* row = (const float4*)(emb + (size_t)n * EMBD);
    float4 r0 = row[0], r1 = row[1], r2 = row[2];
    float* dst = &csums[(size_t)c * EMBD];
    atomicAdd(&dst[0], r0.x);  atomicAdd(&dst[1], r0.y);
    atomicAdd(&dst[2], r0.z);  atomicAdd(&dst[3], r0.w);
    atomicAdd(&dst[4], r1.x);  atomicAdd(&dst[5], r1.y);
    atomicAdd(&dst[6], r1.z);  atomicAdd(&dst[7], r1.w);
    atomicAdd(&dst[8], r2.x);  atomicAdd(&dst[9], r2.y);
    atomicAdd(&dst[10], r2.z); atomicAdd(&dst[11], r2.w);
    atomicAdd(&ccnt[c], 1.f);
}

__global__ void means_kernel(const float* __restrict__ csums,
                             const float* __restrict__ ccnt,
                             float* __restrict__ means)
{
    int c = blockIdx.x * 256 + threadIdx.x;
    if (c >= NC) return;
    float cv = fmaxf(ccnt[c], 1.f);
    float v[EMBD];
    float ss = 0.f;
#pragma unroll
    for (int j = 0; j < EMBD; ++j) {
        v[j] = csums[(size_t)c * EMBD + j] / cv;
        ss += v[j] * v[j];
    }
    float inv = 1.f / fmaxf(sqrtf(ss), 1e-12f);
#pragma unroll
    for (int j = 0; j < EMBD; ++j) means[(size_t)c * EMBD + j] = v[j] * inv;
}

// ---------------------------------------------------------------------------
__device__ __forceinline__ void block_stats2(float x, float x2, float* s_sum, float* s_sumsq)
{
#pragma unroll
    for (int s = 32; s >= 1; s >>= 1) {
        x += __shfl_xor(x, s, 64);
        x2 += __shfl_xor(x2, s, 64);
    }
    __shared__ float w0[4], w1[4];
    int lane = threadIdx.x & 63, w = threadIdx.x >> 6;
    if (lane == 0) { w0[w] = x; w1[w] = x2; }
    __syncthreads();
    if (threadIdx.x == 0) {
        float a = 0.f, b = 0.f;
        for (int i = 0; i < 4; ++i) { a += w0[i]; b += w1[i]; }
        atomicAdd(s_sum, a);
        atomicAdd(s_sumsq, b);
    }
}

// ---------------------------------------------------------------------------
__global__ __launch_bounds__(256) void sg_lik_kernel(
    const float* __restrict__ means, const int* __restrict__ sg0,
    const int* __restrict__ sg1, float* __restrict__ sg_lik, float* __restrict__ stats)
{
    int base = (blockIdx.x * 256 + threadIdx.x) * 4;
    float xs = 0.f, xs2 = 0.f;
    if (base < NES) {
        int4 a4 = *(const int4*)(sg0 + base);
        int4 b4 = *(const int4*)(sg1 + base);
        int ai[4] = {a4.x, a4.y, a4.z, a4.w};
        int bi[4] = {b4.x, b4.y, b4.z, b4.w};
        float4 av[4][3], bv[4][3];
#pragma unroll
        for (int i = 0; i < 4; ++i) {
            const float4* ap = (const float4*)(means + (size_t)ai[i] * EMBD);
            const float4* bp = (const float4*)(means + (size_t)bi[i] * EMBD);
            av[i][0] = ap[0]; av[i][1] = ap[1]; av[i][2] = ap[2];
            bv[i][0] = bp[0]; bv[i][1] = bp[1]; bv[i][2] = bp[2];
        }
        float4 o;
        float* op = (float*)&o;
#pragma unroll
        for (int i = 0; i < 4; ++i) {
            float s = av[i][0].x * bv[i][0].x + av[i][0].y * bv[i][0].y
                    + av[i][0].z * bv[i][0].z + av[i][0].w * bv[i][0].w
                    + av[i][1].x * bv[i][1].x + av[i][1].y * bv[i][1].y
                    + av[i][1].z * bv[i][1].z + av[i][1].w * bv[i][1].w
                    + av[i][2].x * bv[i][2].x + av[i][2].y * bv[i][2].y
                    + av[i][2].z * bv[i][2].z + av[i][2].w * bv[i][2].w;
            op[i] = s;
            xs += s; xs2 += s * s;
        }
        *(float4*)(sg_lik + base) = o;
    }
    block_stats2(xs, xs2, &stats[0], &stats[1]);
}

__global__ __launch_bounds__(256) void sgw_kernel(
    const float* __restrict__ sg_lik, const float* __restrict__ stats,
    const float* __restrict__ gamma, const float* __restrict__ beta,
    float* __restrict__ out)
{
    int base = (blockIdx.x * 256 + threadIdx.x) * 4;
    if (base >= NES) return;
    float m = stats[0] / (float)NES;
    float var = stats[1] / (float)NES - m * m;
    float rs = rsqrtf(var + 1e-5f) * gamma[0];
    float4 v = *(const float4*)(sg_lik + base);
    float4 o;
    o.x = 1.f / (1.f + __expf(-((v.x - m) * rs + beta[0])));
    o.y = 1.f / (1.f + __expf(-((v.y - m) * rs + beta[0])));
    o.z = 1.f / (1.f + __expf(-((v.z - m) * rs + beta[0])));
    o.w = 1.f / (1.f + __expf(-((v.w - m) * rs + beta[0])));
    *(float4*)(out + base) = o;
}

// ---------------------------------------------------------------------------
__global__ __launch_bounds__(256) void bg_lik_kernel(
    const float* __restrict__ emb, const float* __restrict__ means,
    const int* __restrict__ bg_src, const int* __restrict__ bg_dst,
    float* __restrict__ bg_lik, float* __restrict__ stats, int* __restrict__ cnt)
{
    int base = (blockIdx.x * 256 + threadIdx.x) * 4;
    float xs = 0.f, xs2 = 0.f;
    if (base < NEB) {
        int4 s4 = *(const int4*)(bg_src + base);
        int4 d4 = *(const int4*)(bg_dst + base);
        int si[4] = {s4.x, s4.y, s4.z, s4.w};
        int di[4] = {d4.x, d4.y, d4.z, d4.w};
        float4 av[4][3], bv[4][3];
#pragma unroll
        for (int i = 0; i < 4; ++i) {
            const float4* ap = (const float4*)(emb + (size_t)si[i] * EMBD);
            const float4* bp = (const float4*)(means + (size_t)di[i] * EMBD);
            av[i][0] = ap[0]; av[i][1] = ap[1]; av[i][2] = ap[2];
            bv[i][0] = bp[0]; bv[i][1] = bp[1]; bv[i][2] = bp[2];
        }
#pragma unroll
        for (int i = 0; i < 4; ++i) atomicAdd(&cnt[di[i]], 1);
        float4 o;
        float* op = (float*)&o;
#pragma unroll
        for (int i = 0; i < 4; ++i) {
            float s = av[i][0].x * bv[i][0].x + av[i][0].y * bv[i][0].y
                    + av[i][0].z * bv[i][0].z + av[i][0].w * bv[i][0].w
                    + av[i][1].x * bv[i][1].x + av[i][1].y * bv[i][1].y
                    + av[i][1].z * bv[i][1].z + av[i][1].w * bv[i][1].w
                    + av[i][2].x * bv[i][2].x + av[i][2].y * bv[i][2].y
                    + av[i][2].z * bv[i][2].z + av[i][2].w * bv[i][2].w;
            op[i] = s;
            xs += s; xs2 += s * s;
        }
        *(float4*)(bg_lik + base) = o;
    }
    block_stats2(xs, xs2, &stats[2], &stats[3]);
}

__global__ __launch_bounds__(256) void bw_kernel(
    const float* __restrict__ bg_lik, const float* __restrict__ stats,
    const float* __restrict__ gamma, const float* __restrict__ beta,
    const int* __restrict__ bg_src, float* __restrict__ bw, float* __restrict__ denom)
{
    int base = (blockIdx.x * 256 + threadIdx.x) * 4;
    if (base >= NEB) return;
    float m = stats[2] / (float)NEB;
    float var = stats[3] / (float)NEB - m * m;
    float rs = rsqrtf(var + 1e-5f) * gamma[0];
    int4 s4 = *(const int4*)(bg_src + base);
    int si[4] = {s4.x, s4.y, s4.z, s4.w};
    float4 v = *(const float4*)(bg_lik + base);
    float vi[4] = {v.x, v.y, v.z, v.w};
    float4 o;
    float* op = (float*)&o;
#pragma unroll
    for (int i = 0; i < 4; ++i) {
        float w = __expf((vi[i] - m) * rs + beta[0]);
        op[i] = w;
        atomicAdd(&denom[si[i]], w);
    }
    *(float4*)(bw + base) = o;
}

__global__ __launch_bounds__(256) void bw_norm_kernel(
    float* __restrict__ bw, const float* __restrict__ denom,
    const int* __restrict__ bg_src, float* __restrict__ out)
{
    int base = (blockIdx.x * 256 + threadIdx.x) * 4;
    if (base >= NEB) return;
    int4 s4 = *(const int4*)(bg_src + base);
    int si[4] = {s4.x, s4.y, s4.z, s4.w};
    float dv[4];
#pragma unroll
    for (int i = 0; i < 4; ++i) dv[i] = denom[si[i]];
    float4 v = *(const float4*)(bw + base);
    float4 o;
    o.x = v.x / (1e-12f + dv[0]);
    o.y = v.y / (1e-12f + dv[1]);
    o.z = v.z / (1e-12f + dv[2]);
    o.w = v.w / (1e-12f + dv[3]);
    *(float4*)(bw + base) = o;
    *(float4*)(out + base) = o;
}

// ---------------------------------------------------------------------------
__global__ __launch_bounds__(1024) void scan_kernel(
    const int* __restrict__ cnt, int* __restrict__ offs, int C)
{
    __shared__ int wsum[16];
    __shared__ int carry_s, ctot_s;
    const int tid = threadIdx.x;
    const int lane = tid & 63, w = tid >> 6;
    if (tid == 0) carry_s = 0;
    __syncthreads();
    for (int base = 0; base < C; base += 1024) {
        int i = base + tid;
        int v = (i < C) ? cnt[i] : 0;
        int x = v;
#pragma unroll
        for (int s = 1; s < 64; s <<= 1) {
            int y = __shfl_up(x, s, 64);
            if (lane >= s) x += y;
        }
        if (lane == 63) wsum[w] = x;
        __syncthreads();
        if (tid == 0) {
            int s = 0;
            for (int k = 0; k < 16; ++k) { int t = wsum[k]; wsum[k] = s; s += t; }
            ctot_s = s;
        }
        __syncthreads();
        int excl = carry_s + wsum[w] + (x - v);
        if (i < C) offs[i] = excl;
        __syncthreads();
        if (tid == 0) carry_s += ctot_s;
        __syncthreads();
    }
    if (tid == 0) offs[C] = carry_s;
}

__global__ void scatter_kernel(const int* __restrict__ bg_dst,
                               const int* __restrict__ offs,
                               int* __restrict__ fill, int* __restrict__ eids)
{
    int base = (blockIdx.x * 256 + threadIdx.x) * 4;
    if (base >= NEB) return;
    int4 d4 = *(const int4*)(bg_dst + base);
    int di[4] = {d4.x, d4.y, d4.z, d4.w};
#pragma unroll
    for (int i = 0; i < 4; ++i) {
        int p = atomicAdd(&fill[di[i]], 1);
        eids[offs[di[i]] + p] = base + i;
    }
}

// ---------------------------------------------------------------------------
// supernodes: lane-packed gather; writes fp32 out AND bf16 copy (fused conv)
// ---------------------------------------------------------------------------
__global__ __launch_bounds__(256) void supernodes_kernel(
    const ushort_t* __restrict__ nmsg, const float* __restrict__ bw,
    const int* __restrict__ bg_src, const int* __restrict__ eids,
    const int* __restrict__ offs, float* __restrict__ sn,
    ushort_t* __restrict__ sn_bf)
{
    __shared__ float red[4][LATD];
    const int c = blockIdx.x;
    const int tid = threadIdx.x;
    const int wv = tid >> 6, lane = tid & 63;
    const int er = lane >> 4;
    const int cg = lane & 15;
    const int beg = offs[c], end = offs[c + 1];

    float acc[8] = {};
    for (int p = beg + wv * 4 + er; p < end; p += 16) {
        int e = eids[p];
        int s = bg_src[e];
        float w = bw[e];
        bf16x8 v = *(const bf16x8*)(nmsg + (size_t)s * LATD + cg * 8);
#pragma unroll
        for (int j = 0; j < 8; ++j) acc[j] += w * bf2f((ushort_t)v[j]);
    }
#pragma unroll
    for (int j = 0; j < 8; ++j) {
        acc[j] += __shfl_xor(acc[j], 16, 64);
        acc[j] += __shfl_xor(acc[j], 32, 64);
    }
    if (lane < 16) {
        *(float4*)&red[wv][cg * 8]     = (float4){acc[0], acc[1], acc[2], acc[3]};
        *(float4*)&red[wv][cg * 8 + 4] = (float4){acc[4], acc[5], acc[6], acc[7]};
    }
    __syncthreads();
    if (tid < LATD) {
        float s = red[0][tid] + red[1][tid] + red[2][tid] + red[3][tid];
        sn[(size_t)c * LATD + tid] = s;
        sn_bf[(size_t)c * LATD + tid] = f2bf(s);
    }
}

// ---------------------------------------------------------------------------
extern "C" void kernel_launch(void* const* d_in, const int* in_sizes, int n_in,
                              void* d_out, int out_size, void* d_ws, size_t ws_size,
                              hipStream_t stream)
{
    const float* emb_nodes = (const float*)d_in[0];
    const float* enc_nodes = (const float*)d_in[1];
    const float* Wc1 = (const float*)d_in[2];  const float* bc1 = (const float*)d_in[3];
    const float* Wc2 = (const float*)d_in[4];  const float* bc2 = (const float*)d_in[5];
    const float* Wc3 = (const float*)d_in[6];  const float* bc3 = (const float*)d_in[7];
    const float* Wn1 = (const float*)d_in[8];  const float* cn1 = (const float*)d_in[9];
    const float* Wn2 = (const float*)d_in[10]; const float* cn2 = (const float*)d_in[11];
    const float* We1 = (const float*)d_in[12]; const float* ce1 = (const float*)d_in[13];
    const float* We2 = (const float*)d_in[14]; const float* ce2 = (const float*)d_in[15];
    const float* sg_gamma = (const float*)d_in[16]; const float* sg_beta = (const float*)d_in[17];
    const float* bg_gamma = (const float*)d_in[18]; const float* bg_beta = (const float*)d_in[19];
    const int* clusters = (const int*)d_in[20];
    const int* sg0 = (const int*)d_in[21];
    const int* sg1 = sg0 + NES;
    const int* bg_src = (const int*)d_in[22];
    const int* bg_dst = (const int*)d_in[23];

    // output layout (flat, return order)
    float* out_emb = (float*)d_out;                       // NN*EMBD
    float* out_sn  = out_emb + (size_t)NN * EMBD;         // NC*LATD
    float* out_se  = out_sn + (size_t)NC * LATD;          // NES*LATD
    float* out_bw  = out_se + (size_t)NES * LATD;         // NEB
    float* out_sew = out_bw + (size_t)NEB;                // NES

    // ---------------- workspace layout (byte cursor, 64B-aligned) ----------
    uintptr_t cur = (uintptr_t)d_ws;
    uintptr_t wend = cur + ws_size;
    auto alloc = [&](size_t bytes) -> void* {
        cur = (cur + 63) & ~(uintptr_t)63;
        void* p = (void*)cur;
        cur += bytes;
        return p;
    };

    // zeroed region: csums, ccnt, denom, stats, cnt, fill, zbias
    size_t zfloats = (size_t)NC * EMBD + NC + NN + 8 + NC + NC + HIDD;
    float* zbase = (float*)alloc(zfloats * 4);
    float* csums = zbase;
    float* ccnt  = csums + (size_t)NC * EMBD;
    float* denom = ccnt + NC;
    float* stats = denom + NN;
    int*   cnt   = (int*)(stats + 8);
    int*   fill  = cnt + NC;
    float* zbias = (float*)(fill + NC);         // HIDD zeros
    size_t zero_bytes = zfloats * 4;

    float* means  = (float*)alloc((size_t)NC * EMBD * 4);
    float* sg_lik = (float*)alloc((size_t)NES * 4);
    float* bg_lik = (float*)alloc((size_t)NEB * 4);
    float* bwv    = (float*)alloc((size_t)NEB * 4);
    int*   offs   = (int*)alloc((size_t)(NC + 1) * 4);
    int*   eids   = (int*)alloc((size_t)NEB * 4);

    ushort_t* xemb   = (ushort_t*)alloc((size_t)NN * LATD * 2);
    ushort_t* xenc   = (ushort_t*)alloc((size_t)NN * LATD * 2);
    ushort_t* nmsgb  = (ushort_t*)alloc((size_t)NN * LATD * 2);
    ushort_t* sn_bf  = (ushort_t*)alloc((size_t)NC * LATD * 2);
    ushort_t* P0b    = (ushort_t*)alloc((size_t)NC * HIDD * 2);
    ushort_t* P1b    = (ushort_t*)alloc((size_t)NC * HIDD * 2);
    ushort_t* Wc1t  = (ushort_t*)alloc((size_t)LATD * HIDD * 2);
    ushort_t* Wc2t  = (ushort_t*)alloc((size_t)HIDD * HIDD * 2);
    ushort_t* Wn1t  = (ushort_t*)alloc((size_t)LATD * HIDD * 2);
    ushort_t* Wn2t  = (ushort_t*)alloc((size_t)HIDD * LATD * 2);
    ushort_t* We1tA = (ushort_t*)alloc((size_t)HIDD * LATD * 2);  // [512][128]
    ushort_t* We1tB = (ushort_t*)alloc((size_t)HIDD * LATD * 2);  // [512][128]
    ushort_t* We2t  = (ushort_t*)alloc((size_t)HIDD * LATD * 2);  // [128][512]

    cur = (cur + 63) & ~(uintptr_t)63;
    size_t rem_bytes = (wend > cur) ? (size_t)(wend - cur) : 0;
    size_t chunk_sz = (rem_bytes / (2 * (size_t)HIDD * 2)) & ~(size_t)127;
    if (chunk_sz > 100096) chunk_sz = 100096;  // one chunk if ws allows
    if (chunk_sz < 256) return;  // fail soft
    const int CH = (int)chunk_sz;
    ushort_t* bufA = (ushort_t*)cur;
    ushort_t* bufB = bufA + (size_t)CH * HIDD;

    hipMemsetAsync(zbase, 0, zero_bytes, stream);

    dim3 blk(256);

    // ---- prep: input/weight conversions ----
    conv_f2b_kernel<<<2048, blk, 0, stream>>>(emb_nodes, xemb, (long)NN * LATD);
    conv_f2b_kernel<<<2048, blk, 0, stream>>>(enc_nodes, xenc, (long)NN * LATD);
    transpose_conv_kernel<<<(LATD * HIDD + 255) / 256, blk, 0, stream>>>(Wc1, Wc1t, LATD, HIDD);
    transpose_conv_kernel<<<(HIDD * HIDD + 255) / 256, blk, 0, stream>>>(Wc2, Wc2t, HIDD, HIDD);
    transpose_conv_kernel<<<(LATD * HIDD + 255) / 256, blk, 0, stream>>>(Wn1, Wn1t, LATD, HIDD);
    transpose_conv_kernel<<<(HIDD * LATD + 255) / 256, blk, 0, stream>>>(Wn2, Wn2t, HIDD, LATD);
    transpose_conv_kernel<<<(LATD * HIDD + 255) / 256, blk, 0, stream>>>(We1, We1tA, LATD, HIDD);
    transpose_conv_kernel<<<(LATD * HIDD + 255) / 256, blk, 0, stream>>>(We1 + (size_t)LATD * HIDD, We1tB, LATD, HIDD);
    transpose_conv_kernel<<<(HIDD * LATD + 255) / 256, blk, 0, stream>>>(We2, We2t, HIDD, LATD);

    // ---- fused node chain, chunked: xemb->h1->h2->embeddings ----
    for (int m0 = 0; m0 < NN; m0 += CH) {
        int cm = (NN - m0 < CH) ? (NN - m0) : CH;
        gemm_mfma<ACT_TANH, true><<<dim3(HIDD / 128, (cm + 127) / 128), blk, 0, stream>>>(
            xemb + (size_t)m0 * LATD, Wc1t, bc1, bufA, cm, HIDD, LATD);
        gemm_mfma<ACT_TANH, true><<<dim3(HIDD / 128, (cm + 127) / 128), blk, 0, stream>>>(
            bufA, Wc2t, bc2, bufB, cm, HIDD, HIDD);
        emb_kernel<<<(cm + 255) / 256, blk, 0, stream>>>(
            bufB, Wc3, bc3, out_emb + (size_t)m0 * EMBD, cm);
    }

    // ---- cluster means ----
    cluster_accum<<<(NN + 255) / 256, blk, 0, stream>>>(out_emb, clusters, csums, ccnt);
    means_kernel<<<(NC + 255) / 256, blk, 0, stream>>>(csums, ccnt, means);

    // ---- super edge weights (4 edges/thread) ----
    sg_lik_kernel<<<(NES / 4 + 255) / 256, blk, 0, stream>>>(means, sg0, sg1, sg_lik, stats);
    sgw_kernel<<<(NES / 4 + 255) / 256, blk, 0, stream>>>(sg_lik, stats, sg_gamma, sg_beta, out_sew);

    // ---- bipartite edge weights (hist fused; 4 edges/thread) ----
    bg_lik_kernel<<<(NEB / 4 + 255) / 256, blk, 0, stream>>>(out_emb, means, bg_src, bg_dst, bg_lik, stats, cnt);
    bw_kernel<<<(NEB / 4 + 255) / 256, blk, 0, stream>>>(bg_lik, stats, bg_gamma, bg_beta, bg_src, bwv, denom);
    bw_norm_kernel<<<(NEB / 4 + 255) / 256, blk, 0, stream>>>(bwv, denom, bg_src, out_bw);

    // ---- counting sort of edges by destination cluster ----
    scan_kernel<<<1, 1024, 0, stream>>>(cnt, offs, NC);
    scatter_kernel<<<(NEB / 4 + 255) / 256, blk, 0, stream>>>(bg_dst, offs, fill, eids);

    // ---- node messages: FUSED relu(relu(xenc@Wn1)@Wn2) -> nmsgb (bf16) ----
    fused_mlp<true><<<(NN + 127) / 128, blk, 0, stream>>>(
        xenc, Wn1t, cn1, Wn2t, cn2, nmsgb, NN);

    // ---- supernodes (sorted, no atomics; writes fp32 + bf16) ----
    supernodes_kernel<<<NC, blk, 0, stream>>>(nmsgb, bwv, bg_src, eids, offs, out_sn, sn_bf);

    // ---- premultiply: P0 = sn@We1_top, P1 = sn@We1_bot (no bias/act) ----
    gemm_mfma<ACT_NONE, true><<<dim3(HIDD / 128, (NC + 127) / 128), blk, 0, stream>>>(
        sn_bf, We1tA, zbias, P0b, NC, HIDD, LATD);
    gemm_mfma<ACT_NONE, true><<<dim3(HIDD / 128, (NC + 127) / 128), blk, 0, stream>>>(
        sn_bf, We1tB, zbias, P1b, NC, HIDD, LATD);

    // ---- superedges: FUSED relu(relu(P0[sg0]+P1[sg1]+ce1)@We2+ce2) ----
    fused_edge<<<(NES + 127) / 128, blk, 0, stream>>>(
        P0b, P1b, ce1, We2t, ce2, out_se, NES, sg0, sg1);
}

// Round 13
// 884.451 us; speedup vs baseline: 1.0861x; 1.0049x over previous
//
#include <hip/hip_runtime.h>
#include <cstdint>
#include <cstddef>

// Problem constants (SuperGraphConstruction)
#define NN 100000      // nodes
#define NC 20000       // clusters
#define LATD 128
#define HIDD 512
#define EMBD 12
#define NES 160000     // super edges
#define NEB 800000     // bipartite edges

enum { ACT_NONE = 0, ACT_TANH = 1, ACT_RELU = 2 };

typedef __attribute__((ext_vector_type(8))) short bf16x8;
typedef __attribute__((ext_vector_type(4))) float f32x4;
typedef unsigned short ushort_t;

__device__ __forceinline__ float fast_tanh(float x) {
    return 1.f - 2.f / (__expf(2.f * x) + 1.f);
}
__device__ __forceinline__ ushort_t f2bf(float f) {
    union { float f; unsigned u; } x; x.f = f;
    unsigned r = x.u + 0x7FFFu + ((x.u >> 16) & 1u);  // RNE
    return (ushort_t)(r >> 16);
}
__device__ __forceinline__ float bf2f(ushort_t h) {
    union { unsigned u; float f; } x; x.u = ((unsigned)h) << 16;
    return x.f;
}

typedef __attribute__((address_space(1))) void gvoid_t;
typedef __attribute__((address_space(3))) void svoid_t;
__device__ __forceinline__ void gload_lds16(const void* g, void* l) {
    __builtin_amdgcn_global_load_lds((gvoid_t*)g, (svoid_t*)l, 16, 0, 0);
}

// bijective XCD swizzle (m204): each XCD gets a contiguous span of wg ids
__device__ __forceinline__ int xcd_swz(int bid, int nwg) {
    int q = nwg >> 3, r = nwg & 7;
    int xcd = bid & 7, idx = bid >> 3;
    int base = (xcd < r) ? xcd * (q + 1) : r * (q + 1) + (xcd - r) * q;
    return base + idx;
}

// ---------------------------------------------------------------------------
__global__ __launch_bounds__(256) void conv_f2b_kernel(
    const float* __restrict__ in, ushort_t* __restrict__ out, long n)
{
    long i = ((long)blockIdx.x * 256 + threadIdx.x) * 8;
    long stride = (long)gridDim.x * 256 * 8;
    for (; i + 7 < n; i += stride) {
        float4 a = *(const float4*)(in + i);
        float4 b = *(const float4*)(in + i + 4);
        ushort_t o[8] = { f2bf(a.x), f2bf(a.y), f2bf(a.z), f2bf(a.w),
                          f2bf(b.x), f2bf(b.y), f2bf(b.z), f2bf(b.w) };
        *(int4*)(out + i) = *(int4*)o;
    }
}

// W [K][N] fp32 -> Wt [N][K] bf16
__global__ __launch_bounds__(256) void transpose_conv_kernel(
    const float* __restrict__ W, ushort_t* __restrict__ Wt, int K, int N)
{
    int i = blockIdx.x * 256 + threadIdx.x;
    if (i >= K * N) return;
    int n = i / K, k = i % K;
    Wt[i] = f2bf(W[(size_t)k * N + n]);
}

// ---------------------------------------------------------------------------
// bf16 MFMA GEMM (m97 + T2 swizzle + T1 XCD swizzle). 1D grid, n-inner.
// ---------------------------------------------------------------------------
template<int ACT, bool OUT_BF16>
__global__ __launch_bounds__(256) void gemm_mfma(
    const ushort_t* __restrict__ A, const ushort_t* __restrict__ Bt,
    const float* __restrict__ bias, void* __restrict__ Cv,
    int M, int N, int K, int nTilesN)
{
    __shared__ ushort_t As[128 * 64];
    __shared__ ushort_t Bs[128 * 64];

    const int wg = xcd_swz(blockIdx.x, gridDim.x);
    const int m0 = (wg / nTilesN) * 128, n0 = (wg % nTilesN) * 128;

    const int tid = threadIdx.x;
    const int w = tid >> 6, lane = tid & 63;
    const int wm = w >> 1, wn = w & 1;
    const int lr = lane & 15, lg = lane >> 4;
    const int srow = lane >> 3;
    const int sseg = (lane & 7) ^ srow;

    f32x4 acc[4][4];
#pragma unroll
    for (int i = 0; i < 4; ++i)
#pragma unroll
        for (int j = 0; j < 4; ++j) acc[i][j] = (f32x4){0.f, 0.f, 0.f, 0.f};

    for (int k0 = 0; k0 < K; k0 += 64) {
#pragma unroll
        for (int i = 0; i < 4; ++i) {
            int c = w * 4 + i;
            int row = c * 8 + srow;
            int gm = m0 + row; if (gm >= M) gm = M - 1;
            gload_lds16(A + (size_t)gm * K + k0 + sseg * 8, As + c * 512);
            gload_lds16(Bt + (size_t)(n0 + row) * K + k0 + sseg * 8, Bs + c * 512);
        }
        __syncthreads();
#pragma unroll
        for (int ks = 0; ks < 2; ++ks) {
            bf16x8 af[4], bf[4];
#pragma unroll
            for (int mt = 0; mt < 4; ++mt) {
                int row = wm * 64 + mt * 16 + lr;
                int slot = (ks * 4 + lg) ^ (row & 7);
                af[mt] = *(const bf16x8*)&As[row * 64 + slot * 8];
            }
#pragma unroll
            for (int nt = 0; nt < 4; ++nt) {
                int row = wn * 64 + nt * 16 + lr;
                int slot = (ks * 4 + lg) ^ (row & 7);
                bf[nt] = *(const bf16x8*)&Bs[row * 64 + slot * 8];
            }
#pragma unroll
            for (int mt = 0; mt < 4; ++mt)
#pragma unroll
                for (int nt = 0; nt < 4; ++nt)
                    acc[mt][nt] = __builtin_amdgcn_mfma_f32_16x16x32_bf16(
                        af[mt], bf[nt], acc[mt][nt], 0, 0, 0);
        }
        __syncthreads();
    }

#pragma unroll
    for (int nt = 0; nt < 4; ++nt) {
        int col = n0 + wn * 64 + nt * 16 + lr;
        float bv = bias[col];
#pragma unroll
        for (int mt = 0; mt < 4; ++mt) {
#pragma unroll
            for (int r = 0; r < 4; ++r) {
                int row = m0 + wm * 64 + mt * 16 + lg * 4 + r;
                if (row >= M) continue;
                float v = acc[mt][nt][r] + bv;
                if (ACT == ACT_TANH) v = fast_tanh(v);
                else if (ACT == ACT_RELU) v = fmaxf(v, 0.f);
                if (OUT_BF16) ((ushort_t*)Cv)[(size_t)row * N + col] = f2bf(v);
                else ((float*)Cv)[(size_t)row * N + col] = v;
            }
        }
    }
}

// ---------------------------------------------------------------------------
// FUSED 2-layer MLP (node messages): out = relu(relu(A@W1+b1)@W2+b2)
// ---------------------------------------------------------------------------
template<bool OUT_BF16>
__global__ __launch_bounds__(256) void fused_mlp(
    const ushort_t* __restrict__ A, const ushort_t* __restrict__ W1t,
    const float* __restrict__ b1, const ushort_t* __restrict__ W2t,
    const float* __restrict__ b2, void* __restrict__ Cv, int M)
{
    __shared__ ushort_t As[128 * 128];
    __shared__ ushort_t Ws[128 * 64];
    __shared__ ushort_t Hs[128 * 128];

    const int tid = threadIdx.x;
    const int m0 = blockIdx.x * 128;
    const int w = tid >> 6, lane = tid & 63;
    const int wm = w >> 1, wn = w & 1;
    const int lr = lane & 15, lg = lane >> 4;
    const int srow = lane >> 3;
    const int sseg = (lane & 7) ^ srow;

    f32x4 acc2[4][4];
#pragma unroll
    for (int i = 0; i < 4; ++i)
#pragma unroll
        for (int j = 0; j < 4; ++j) acc2[i][j] = (f32x4){0.f, 0.f, 0.f, 0.f};

    {   // stage A resident: [128][128], 16-slot swizzled rows
        const int arow4 = lane >> 4;
        const int aslot = lane & 15;
#pragma unroll
        for (int rnd = 0; rnd < 8; ++rnd) {
            int row = rnd * 16 + w * 4 + arow4;
            int gm = m0 + row; if (gm >= M) gm = M - 1;
            int seg = aslot ^ (row & 7);
            gload_lds16(A + (size_t)gm * 128 + seg * 8, As + row * 128);
        }
    }

    for (int c = 0; c < 4; ++c) {
        f32x4 acc1[4][4];
#pragma unroll
        for (int i = 0; i < 4; ++i)
#pragma unroll
            for (int j = 0; j < 4; ++j) acc1[i][j] = (f32x4){0.f, 0.f, 0.f, 0.f};

        for (int k0 = 0; k0 < 128; k0 += 64) {
#pragma unroll
            for (int i = 0; i < 4; ++i) {
                int ch = w * 4 + i;
                int row = ch * 8 + srow;
                gload_lds16(W1t + (size_t)(c * 128 + row) * 128 + k0 + sseg * 8,
                            Ws + ch * 512);
            }
            __syncthreads();
#pragma unroll
            for (int ks = 0; ks < 2; ++ks) {
                bf16x8 af[4], bf[4];
#pragma unroll
                for (int mt = 0; mt < 4; ++mt) {
                    int row = wm * 64 + mt * 16 + lr;
                    int seg = (k0 >> 3) + ks * 4 + lg;
                    int slot = seg ^ (row & 7);
                    af[mt] = *(const bf16x8*)&As[row * 128 + slot * 8];
                }
#pragma unroll
                for (int nt = 0; nt < 4; ++nt) {
                    int row = wn * 64 + nt * 16 + lr;
                    int slot = (ks * 4 + lg) ^ (row & 7);
                    bf[nt] = *(const bf16x8*)&Ws[row * 64 + slot * 8];
                }
#pragma unroll
                for (int mt = 0; mt < 4; ++mt)
#pragma unroll
                    for (int nt = 0; nt < 4; ++nt)
                        acc1[mt][nt] = __builtin_amdgcn_mfma_f32_16x16x32_bf16(
                            af[mt], bf[nt], acc1[mt][nt], 0, 0, 0);
            }
            __syncthreads();
        }

        // h = relu(acc1 + b1) -> Hs
#pragma unroll
        for (int nt = 0; nt < 4; ++nt) {
            int colL = wn * 64 + nt * 16 + lr;
            float bv = b1[c * 128 + colL];
            int cseg = colL >> 3, coff = colL & 7;
#pragma unroll
            for (int mt = 0; mt < 4; ++mt) {
#pragma unroll
                for (int r = 0; r < 4; ++r) {
                    int row = wm * 64 + mt * 16 + lg * 4 + r;
                    float v = fmaxf(acc1[mt][nt][r] + bv, 0.f);
                    int slot = cseg ^ (row & 7);
                    Hs[row * 128 + slot * 8 + coff] = f2bf(v);
                }
            }
        }

        for (int k0h = 0; k0h < 128; k0h += 64) {
#pragma unroll
            for (int i = 0; i < 4; ++i) {
                int ch = w * 4 + i;
                int row = ch * 8 + srow;
                gload_lds16(W2t + (size_t)row * HIDD + c * 128 + k0h + sseg * 8,
                            Ws + ch * 512);
            }
            __syncthreads();
#pragma unroll
            for (int ks = 0; ks < 2; ++ks) {
                bf16x8 af[4], bf[4];
#pragma unroll
                for (int mt = 0; mt < 4; ++mt) {
                    int row = wm * 64 + mt * 16 + lr;
                    int seg = (k0h >> 3) + ks * 4 + lg;
                    int slot = seg ^ (row & 7);
                    af[mt] = *(const bf16x8*)&Hs[row * 128 + slot * 8];
                }
#pragma unroll
                for (int nt = 0; nt < 4; ++nt) {
                    int row = wn * 64 + nt * 16 + lr;
                    int slot = (ks * 4 + lg) ^ (row & 7);
                    bf[nt] = *(const bf16x8*)&Ws[row * 64 + slot * 8];
                }
#pragma unroll
                for (int mt = 0; mt < 4; ++mt)
#pragma unroll
                    for (int nt = 0; nt < 4; ++nt)
                        acc2[mt][nt] = __builtin_amdgcn_mfma_f32_16x16x32_bf16(
                            af[mt], bf[nt], acc2[mt][nt], 0, 0, 0);
            }
            __syncthreads();
        }
    }

#pragma unroll
    for (int nt = 0; nt < 4; ++nt) {
        int col = wn * 64 + nt * 16 + lr;
        float bv = b2[col];
#pragma unroll
        for (int mt = 0; mt < 4; ++mt) {
#pragma unroll
            for (int r = 0; r < 4; ++r) {
                int row = m0 + wm * 64 + mt * 16 + lg * 4 + r;
                if (row >= M) continue;
                float v = fmaxf(acc2[mt][nt][r] + bv, 0.f);
                if (OUT_BF16) ((ushort_t*)Cv)[(size_t)row * 128 + col] = f2bf(v);
                else ((float*)Cv)[(size_t)row * 128 + col] = v;
            }
        }
    }
}

// ---------------------------------------------------------------------------
// FUSED superedge: out[e] = relu(relu(P0[sg0[e]]+P1[sg1[e]]+b1)@W2+b2)
// ---------------------------------------------------------------------------
__global__ __launch_bounds__(256) void fused_edge(
    const ushort_t* __restrict__ P0, const ushort_t* __restrict__ P1,
    const float* __restrict__ b1, const ushort_t* __restrict__ W2t,
    const float* __restrict__ b2, float* __restrict__ Cv, int M,
    const int* __restrict__ g0, const int* __restrict__ g1)
{
    __shared__ ushort_t Hs[128 * 128];
    __shared__ ushort_t Ws[128 * 64];
    __shared__ int i0s[128], i1s[128];

    const int tid = threadIdx.x;
    const int m0 = blockIdx.x * 128;
    const int w = tid >> 6, lane = tid & 63;
    const int wm = w >> 1, wn = w & 1;
    const int lr = lane & 15, lg = lane >> 4;
    const int srow = lane >> 3;
    const int sseg = (lane & 7) ^ srow;
    const int er = lane >> 4;
    const int cg = lane & 15;

    if (tid < 128) {
        int gm = m0 + tid; if (gm >= M) gm = M - 1;
        i0s[tid] = g0[gm];
        i1s[tid] = g1[gm];
    }
    __syncthreads();

    f32x4 acc2[4][4];
#pragma unroll
    for (int i = 0; i < 4; ++i)
#pragma unroll
        for (int j = 0; j < 4; ++j) acc2[i][j] = (f32x4){0.f, 0.f, 0.f, 0.f};

    for (int c = 0; c < 4; ++c) {
        float bch[8];
#pragma unroll
        for (int j = 0; j < 8; ++j) bch[j] = b1[c * 128 + cg * 8 + j];

#pragma unroll
        for (int pass = 0; pass < 8; ++pass) {
            int row = pass * 16 + w * 4 + er;
            int i0 = i0s[row], i1 = i1s[row];
            bf16x8 p0 = *(const bf16x8*)(P0 + (size_t)i0 * HIDD + c * 128 + cg * 8);
            bf16x8 p1 = *(const bf16x8*)(P1 + (size_t)i1 * HIDD + c * 128 + cg * 8);
            ushort_t o[8];
#pragma unroll
            for (int j = 0; j < 8; ++j) {
                float v = bf2f((ushort_t)p0[j]) + bf2f((ushort_t)p1[j]) + bch[j];
                o[j] = f2bf(fmaxf(v, 0.f));
            }
            int slot = cg ^ (row & 7);
            *(int4*)&Hs[row * 128 + slot * 8] = *(int4*)o;
        }

        for (int k0h = 0; k0h < 128; k0h += 64) {
#pragma unroll
            for (int i = 0; i < 4; ++i) {
                int ch = w * 4 + i;
                int row = ch * 8 + srow;
                gload_lds16(W2t + (size_t)row * HIDD + c * 128 + k0h + sseg * 8,
                            Ws + ch * 512);
            }
            __syncthreads();
#pragma unroll
            for (int ks = 0; ks < 2; ++ks) {
                bf16x8 af[4], bf[4];
#pragma unroll
                for (int mt = 0; mt < 4; ++mt) {
                    int row = wm * 64 + mt * 16 + lr;
                    int seg = (k0h >> 3) + ks * 4 + lg;
                    int slot = seg ^ (row & 7);
                    af[mt] = *(const bf16x8*)&Hs[row * 128 + slot * 8];
                }
#pragma unroll
                for (int nt = 0; nt < 4; ++nt) {
                    int row = wn * 64 + nt * 16 + lr;
                    int slot = (ks * 4 + lg) ^ (row & 7);
                    bf[nt] = *(const bf16x8*)&Ws[row * 64 + slot * 8];
                }
#pragma unroll
                for (int mt = 0; mt < 4; ++mt)
#pragma unroll
                    for (int nt = 0; nt < 4; ++nt)
                        acc2[mt][nt] = __builtin_amdgcn_mfma_f32_16x16x32_bf16(
                            af[mt], bf[nt], acc2[mt][nt], 0, 0, 0);
            }
            __syncthreads();
        }
    }

#pragma unroll
    for (int nt = 0; nt < 4; ++nt) {
        int col = wn * 64 + nt * 16 + lr;
        float bv = b2[col];
#pragma unroll
        for (int mt = 0; mt < 4; ++mt) {
#pragma unroll
            for (int r = 0; r < 4; ++r) {
                int row = m0 + wm * 64 + mt * 16 + lg * 4 + r;
                if (row >= M) continue;
                float v = fmaxf(acc2[mt][nt][r] + bv, 0.f);
                Cv[(size_t)row * 128 + col] = v;
            }
        }
    }
}

// ---------------------------------------------------------------------------
// embeddings = l2norm(h2 @ Wc3 + bc3); THREAD-per-row; h2 bf16.
// ---------------------------------------------------------------------------
__global__ __launch_bounds__(256) void emb_kernel(
    const ushort_t* __restrict__ h2, const float* __restrict__ W,
    const float* __restrict__ bias, float* __restrict__ out, int M)
{
    __shared__ float Wl[HIDD * EMBD];
    for (int i = threadIdx.x; i < HIDD * EMBD; i += 256) Wl[i] = W[i];
    __syncthreads();

    int m = blockIdx.x * 256 + threadIdx.x;
    if (m >= M) return;
    const ushort_t* row = h2 + (size_t)m * HIDD;

    float acc[EMBD] = {};
#pragma unroll 2
    for (int k0 = 0; k0 < HIDD; k0 += 8) {
        bf16x8 v = *(const bf16x8*)(row + k0);
        float f[8];
#pragma unroll
        for (int u = 0; u < 8; ++u) f[u] = bf2f((ushort_t)v[u]);
#pragma unroll
        for (int u = 0; u < 8; ++u) {
            const float* wr = &Wl[(k0 + u) * EMBD];
#pragma unroll
            for (int j = 0; j < EMBD; ++j) acc[j] += f[u] * wr[j];
        }
    }
    float vv[EMBD];
    float ss = 0.f;
#pragma unroll
    for (int j = 0; j < EMBD; ++j) { vv[j] = acc[j] + bias[j]; ss += vv[j] * vv[j]; }
    float inv = 1.f / fmaxf(sqrtf(ss), 1e-12f);
#pragma unroll
    for (int j = 0; j < EMBD; ++j) out[(size_t)m * EMBD + j] = vv[j] * inv;
}

// ---------------------------------------------------------------------------
__global__ void cluster_accum(const float* __restrict__ emb,
                              const int* __restrict__ clusters,
                              float* __restrict__ csums, float* __restrict__ ccnt)
{
    int n = blockIdx.x * 256 + threadIdx.x;
    if (n >= NN) return;
    int c = clusters[n];
    const float4* row = (const float4*)(emb + (size_t)n * EMBD);
    float4 r0 = row[0], r1 = row[1], r2 = row[2];
    float* dst = &csums[(size_t)c * EMBD];
    atomicAdd(&dst[0], r0.x);  atomicAdd(&dst[1], r0.y);
    atomicAdd(&dst[2], r0.z);  atomicAdd(&dst[3], r0.w);
    atomicAdd(&dst[4], r1.x);  atomicAdd(&dst[5], r1.y);
    atomicAdd(&dst[6], r1.z);  atomicAdd(&dst[7], r1.w);
    atomicAdd(&dst[8], r2.x);  atomicAdd(&dst[9], r2.y);
    atomicAdd(&dst[10], r2.z); atomicAdd(&dst[11], r2.w);
    atomicAdd(&ccnt[c], 1.f);
}

__global__ void means_kernel(const float* __restrict__ csums,
                             const float* __restrict__ ccnt,
                             float* __restrict__ means)
{
    int c = blockIdx.x * 256 + threadIdx.x;
    if (c >= NC) return;
    float cv = fmaxf(ccnt[c], 1.f);
    float v[EMBD];
    float ss = 0.f;
#pragma unroll
    for (int j = 0; j < EMBD; ++j) {
        v[j] = csums[(size_t)c * EMBD + j] / cv;
        ss += v[j] * v[j];
    }
    float inv = 1.f / fmaxf(sqrtf(ss), 1e-12f);
#pragma unroll
    for (int j = 0; j < EMBD; ++j) means[(size_t)c * EMBD + j] = v[j] * inv;
}

// ---------------------------------------------------------------------------
__device__ __forceinline__ void block_stats2(float x, float x2, float* s_sum, float* s_sumsq)
{
#pragma unroll
    for (int s = 32; s >= 1; s >>= 1) {
        x += __shfl_xor(x, s, 64);
        x2 += __shfl_xor(x2, s, 64);
    }
    __shared__ float w0[4], w1[4];
    int lane = threadIdx.x & 63, w = threadIdx.x >> 6;
    if (lane == 0) { w0[w] = x; w1[w] = x2; }
    __syncthreads();
    if (threadIdx.x == 0) {
        float a = 0.f, b = 0.f;
        for (int i = 0; i < 4; ++i) { a += w0[i]; b += w1[i]; }
        atomicAdd(s_sum, a);
        atomicAdd(s_sumsq, b);
    }
}

// ---------------------------------------------------------------------------
__global__ __launch_bounds__(256) void sg_lik_kernel(
    const float* __restrict__ means, const int* __restrict__ sg0,
    const int* __restrict__ sg1, float* __restrict__ sg_lik, float* __restrict__ stats)
{
    int base = (blockIdx.x * 256 + threadIdx.x) * 4;
    float xs = 0.f, xs2 = 0.f;
    if (base < NES) {
        int4 a4 = *(const int4*)(sg0 + base);
        int4 b4 = *(const int4*)(sg1 + base);
        int ai[4] = {a4.x, a4.y, a4.z, a4.w};
        int bi[4] = {b4.x, b4.y, b4.z, b4.w};
        float4 av[4][3], bv[4][3];
#pragma unroll
        for (int i = 0; i < 4; ++i) {
            const float4* ap = (const float4*)(means + (size_t)ai[i] * EMBD);
            const float4* bp = (const float4*)(means + (size_t)bi[i] * EMBD);
            av[i][0] = ap[0]; av[i][1] = ap[1]; av[i][2] = ap[2];
            bv[i][0] = bp[0]; bv[i][1] = bp[1]; bv[i][2] = bp[2];
        }
        float4 o;
        float* op = (float*)&o;
#pragma unroll
        for (int i = 0; i < 4; ++i) {
            float s = av[i][0].x * bv[i][0].x + av[i][0].y * bv[i][0].y
                    + av[i][0].z * bv[i][0].z + av[i][0].w * bv[i][0].w
                    + av[i][1].x * bv[i][1].x + av[i][1].y * bv[i][1].y
                    + av[i][1].z * bv[i][1].z + av[i][1].w * bv[i][1].w
                    + av[i][2].x * bv[i][2].x + av[i][2].y * bv[i][2].y
                    + av[i][2].z * bv[i][2].z + av[i][2].w * bv[i][2].w;
            op[i] = s;
            xs += s; xs2 += s * s;
        }
        *(float4*)(sg_lik + base) = o;
    }
    block_stats2(xs, xs2, &stats[0], &stats[1]);
}

__global__ __launch_bounds__(256) void sgw_kernel(
    const float* __restrict__ sg_lik, const float* __restrict__ stats,
    const float* __restrict__ gamma, const float* __restrict__ beta,
    float* __restrict__ out)
{
    int base = (blockIdx.x * 256 + threadIdx.x) * 4;
    if (base >= NES) return;
    float m = stats[0] / (float)NES;
    float var = stats[1] / (float)NES - m * m;
    float rs = rsqrtf(var + 1e-5f) * gamma[0];
    float4 v = *(const float4*)(sg_lik + base);
    float4 o;
    o.x = 1.f / (1.f + __expf(-((v.x - m) * rs + beta[0])));
    o.y = 1.f / (1.f + __expf(-((v.y - m) * rs + beta[0])));
    o.z = 1.f / (1.f + __expf(-((v.z - m) * rs + beta[0])));
    o.w = 1.f / (1.f + __expf(-((v.w - m) * rs + beta[0])));
    *(float4*)(out + base) = o;
}

// ---------------------------------------------------------------------------
__global__ __launch_bounds__(256) void bg_lik_kernel(
    const float* __restrict__ emb, const float* __restrict__ means,
    const int* __restrict__ bg_src, const int* __restrict__ bg_dst,
    float* __restrict__ bg_lik, float* __restrict__ stats, int* __restrict__ cnt)
{
    int base = (blockIdx.x * 256 + threadIdx.x) * 4;
    float xs = 0.f, xs2 = 0.f;
    if (base < NEB) {
        int4 s4 = *(const int4*)(bg_src + base);
        int4 d4 = *(const int4*)(bg_dst + base);
        int si[4] = {s4.x, s4.y, s4.z, s4.w};
        int di[4] = {d4.x, d4.y, d4.z, d4.w};
        float4 av[4][3], bv[4][3];
#pragma unroll
        for (int i = 0; i < 4; ++i) {
            const float4* ap = (const float4*)(emb + (size_t)si[i] * EMBD);
            const float4* bp = (const float4*)(means + (size_t)di[i] * EMBD);
            av[i][0] = ap[0]; av[i][1] = ap[1]; av[i][2] = ap[2];
            bv[i][0] = bp[0]; bv[i][1] = bp[1]; bv[i][2] = bp[2];
        }
#pragma unroll
        for (int i = 0; i < 4; ++i) atomicAdd(&cnt[di[i]], 1);
        float4 o;
        float* op = (float*)&o;
#pragma unroll
        for (int i = 0; i < 4; ++i) {
            float s = av[i][0].x * bv[i][0].x + av[i][0].y * bv[i][0].y
                    + av[i][0].z * bv[i][0].z + av[i][0].w * bv[i][0].w
                    + av[i][1].x * bv[i][1].x + av[i][1].y * bv[i][1].y
                    + av[i][1].z * bv[i][1].z + av[i][1].w * bv[i][1].w
                    + av[i][2].x * bv[i][2].x + av[i][2].y * bv[i][2].y
                    + av[i][2].z * bv[i][2].z + av[i][2].w * bv[i][2].w;
            op[i] = s;
            xs += s; xs2 += s * s;
        }
        *(float4*)(bg_lik + base) = o;
    }
    block_stats2(xs, xs2, &stats[2], &stats[3]);
}

__global__ __launch_bounds__(256) void bw_kernel(
    const float* __restrict__ bg_lik, const float* __restrict__ stats,
    const float* __restrict__ gamma, const float* __restrict__ beta,
    const int* __restrict__ bg_src, float* __restrict__ bw, float* __restrict__ denom)
{
    int base = (blockIdx.x * 256 + threadIdx.x) * 4;
    if (base >= NEB) return;
    float m = stats[2] / (float)NEB;
    float var = stats[3] / (float)NEB - m * m;
    float rs = rsqrtf(var + 1e-5f) * gamma[0];
    int4 s4 = *(const int4*)(bg_src + base);
    int si[4] = {s4.x, s4.y, s4.z, s4.w};
    float4 v = *(const float4*)(bg_lik + base);
    float vi[4] = {v.x, v.y, v.z, v.w};
    float4 o;
    float* op = (float*)&o;
#pragma unroll
    for (int i = 0; i < 4; ++i) {
        float w = __expf((vi[i] - m) * rs + beta[0]);
        op[i] = w;
        atomicAdd(&denom[si[i]], w);
    }
    *(float4*)(bw + base) = o;
}

__global__ __launch_bounds__(256) void bw_norm_kernel(
    float* __restrict__ bw, const float* __restrict__ denom,
    const int* __restrict__ bg_src, float* __restrict__ out)
{
    int base = (blockIdx.x * 256 + threadIdx.x) * 4;
    if (base >= NEB) return;
    int4 s4 = *(const int4*)(bg_src + base);
    int si[4] = {s4.x, s4.y, s4.z, s4.w};
    float dv[4];
#pragma unroll
    for (int i = 0; i < 4; ++i) dv[i] = denom[si[i]];
    float4 v = *(const float4*)(bw + base);
    float4 o;
    o.x = v.x / (1e-12f + dv[0]);
    o.y = v.y / (1e-12f + dv[1]);
    o.z = v.z / (1e-12f + dv[2]);
    o.w = v.w / (1e-12f + dv[3]);
    *(float4*)(bw + base) = o;
    *(float4*)(out + base) = o;
}

// ---------------------------------------------------------------------------
__global__ __launch_bounds__(1024) void scan_kernel(
    const int* __restrict__ cnt, int* __restrict__ offs, int C)
{
    __shared__ int wsum[16];
    __shared__ int carry_s, ctot_s;
    const int tid = threadIdx.x;
    const int lane = tid & 63, w = tid >> 6;
    if (tid == 0) carry_s = 0;
    __syncthreads();
    for (int base = 0; base < C; base += 1024) {
        int i = base + tid;
        int v = (i < C) ? cnt[i] : 0;
        int x = v;
#pragma unroll
        for (int s = 1; s < 64; s <<= 1) {
            int y = __shfl_up(x, s, 64);
            if (lane >= s) x += y;
        }
        if (lane == 63) wsum[w] = x;
        __syncthreads();
        if (tid == 0) {
            int s = 0;
            for (int k = 0; k < 16; ++k) { int t = wsum[k]; wsum[k] = s; s += t; }
            ctot_s = s;
        }
        __syncthreads();
        int excl = carry_s + wsum[w] + (x - v);
        if (i < C) offs[i] = excl;
        __syncthreads();
        if (tid == 0) carry_s += ctot_s;
        __syncthreads();
    }
    if (tid == 0) offs[C] = carry_s;
}

__global__ void scatter_kernel(const int* __restrict__ bg_dst,
                               const int* __restrict__ offs,
                               int* __restrict__ fill, int* __restrict__ eids)
{
    int base = (blockIdx.x * 256 + threadIdx.x) * 4;
    if (base >= NEB) return;
    int4 d4 = *(const int4*)(bg_dst + base);
    int di[4] = {d4.x, d4.y, d4.z, d4.w};
#pragma unroll
    for (int i = 0; i < 4; ++i) {
        int p = atomicAdd(&fill[di[i]], 1);
        eids[offs[di[i]] + p] = base + i;
    }
}

// ---------------------------------------------------------------------------
// supernodes: lane-packed gather; writes fp32 out AND bf16 copy (fused conv)
// ---------------------------------------------------------------------------
__global__ __launch_bounds__(256) void supernodes_kernel(
    const ushort_t* __restrict__ nmsg, const float* __restrict__ bw,
    const int* __restrict__ bg_src, const int* __restrict__ eids,
    const int* __restrict__ offs, float* __restrict__ sn,
    ushort_t* __restrict__ sn_bf)
{
    __shared__ float red[4][LATD];
    const int c = blockIdx.x;
    const int tid = threadIdx.x;
    const int wv = tid >> 6, lane = tid & 63;
    const int er = lane >> 4;
    const int cg = lane & 15;
    const int beg = offs[c], end = offs[c + 1];

    float acc[8] = {};
    for (int p = beg + wv * 4 + er; p < end; p += 16) {
        int e = eids[p];
        int s = bg_src[e];
        float w = bw[e];
        bf16x8 v = *(const bf16x8*)(nmsg + (size_t)s * LATD + cg * 8);
#pragma unroll
        for (int j = 0; j < 8; ++j) acc[j] += w * bf2f((ushort_t)v[j]);
    }
#pragma unroll
    for (int j = 0; j < 8; ++j) {
        acc[j] += __shfl_xor(acc[j], 16, 64);
        acc[j] += __shfl_xor(acc[j], 32, 64);
    }
    if (lane < 16) {
        *(float4*)&red[wv][cg * 8]     = (float4){acc[0], acc[1], acc[2], acc[3]};
        *(float4*)&red[wv][cg * 8 + 4] = (float4){acc[4], acc[5], acc[6], acc[7]};
    }
    __syncthreads();
    if (tid < LATD) {
        float s = red[0][tid] + red[1][tid] + red[2][tid] + red[3][tid];
        sn[(size_t)c * LATD + tid] = s;
        sn_bf[(size_t)c * LATD + tid] = f2bf(s);
    }
}

// ---------------------------------------------------------------------------
extern "C" void kernel_launch(void* const* d_in, const int* in_sizes, int n_in,
                              void* d_out, int out_size, void* d_ws, size_t ws_size,
                              hipStream_t stream)
{
    const float* emb_nodes = (const float*)d_in[0];
    const float* enc_nodes = (const float*)d_in[1];
    const float* Wc1 = (const float*)d_in[2];  const float* bc1 = (const float*)d_in[3];
    const float* Wc2 = (const float*)d_in[4];  const float* bc2 = (const float*)d_in[5];
    const float* Wc3 = (const float*)d_in[6];  const float* bc3 = (const float*)d_in[7];
    const float* Wn1 = (const float*)d_in[8];  const float* cn1 = (const float*)d_in[9];
    const float* Wn2 = (const float*)d_in[10]; const float* cn2 = (const float*)d_in[11];
    const float* We1 = (const float*)d_in[12]; const float* ce1 = (const float*)d_in[13];
    const float* We2 = (const float*)d_in[14]; const float* ce2 = (const float*)d_in[15];
    const float* sg_gamma = (const float*)d_in[16]; const float* sg_beta = (const float*)d_in[17];
    const float* bg_gamma = (const float*)d_in[18]; const float* bg_beta = (const float*)d_in[19];
    const int* clusters = (const int*)d_in[20];
    const int* sg0 = (const int*)d_in[21];
    const int* sg1 = sg0 + NES;
    const int* bg_src = (const int*)d_in[22];
    const int* bg_dst = (const int*)d_in[23];

    // output layout (flat, return order)
    float* out_emb = (float*)d_out;                       // NN*EMBD
    float* out_sn  = out_emb + (size_t)NN * EMBD;         // NC*LATD
    float* out_se  = out_sn + (size_t)NC * LATD;          // NES*LATD
    float* out_bw  = out_se + (size_t)NES * LATD;         // NEB
    float* out_sew = out_bw + (size_t)NEB;                // NES

    // ---------------- workspace layout (byte cursor, 64B-aligned) ----------
    uintptr_t cur = (uintptr_t)d_ws;
    uintptr_t wend = cur + ws_size;
    auto alloc = [&](size_t bytes) -> void* {
        cur = (cur + 63) & ~(uintptr_t)63;
        void* p = (void*)cur;
        cur += bytes;
        return p;
    };

    // zeroed region: csums, ccnt, denom, stats, cnt, fill, zbias
    size_t zfloats = (size_t)NC * EMBD + NC + NN + 8 + NC + NC + HIDD;
    float* zbase = (float*)alloc(zfloats * 4);
    float* csums = zbase;
    float* ccnt  = csums + (size_t)NC * EMBD;
    float* denom = ccnt + NC;
    float* stats = denom + NN;
    int*   cnt   = (int*)(stats + 8);
    int*   fill  = cnt + NC;
    float* zbias = (float*)(fill + NC);         // HIDD zeros
    size_t zero_bytes = zfloats * 4;

    float* means  = (float*)alloc((size_t)NC * EMBD * 4);
    float* sg_lik = (float*)alloc((size_t)NES * 4);
    float* bg_lik = (float*)alloc((size_t)NEB * 4);
    float* bwv    = (float*)alloc((size_t)NEB * 4);
    int*   offs   = (int*)alloc((size_t)(NC + 1) * 4);
    int*   eids   = (int*)alloc((size_t)NEB * 4);

    ushort_t* xemb   = (ushort_t*)alloc((size_t)NN * LATD * 2);
    ushort_t* xenc   = (ushort_t*)alloc((size_t)NN * LATD * 2);
    ushort_t* nmsgb  = (ushort_t*)alloc((size_t)NN * LATD * 2);
    ushort_t* sn_bf  = (ushort_t*)alloc((size_t)NC * LATD * 2);
    ushort_t* P0b    = (ushort_t*)alloc((size_t)NC * HIDD * 2);
    ushort_t* P1b    = (ushort_t*)alloc((size_t)NC * HIDD * 2);
    ushort_t* Wc1t  = (ushort_t*)alloc((size_t)LATD * HIDD * 2);
    ushort_t* Wc2t  = (ushort_t*)alloc((size_t)HIDD * HIDD * 2);
    ushort_t* Wn1t  = (ushort_t*)alloc((size_t)LATD * HIDD * 2);
    ushort_t* Wn2t  = (ushort_t*)alloc((size_t)HIDD * LATD * 2);
    ushort_t* We1tA = (ushort_t*)alloc((size_t)HIDD * LATD * 2);  // [512][128]
    ushort_t* We1tB = (ushort_t*)alloc((size_t)HIDD * LATD * 2);  // [512][128]
    ushort_t* We2t  = (ushort_t*)alloc((size_t)HIDD * LATD * 2);  // [128][512]

    cur = (cur + 63) & ~(uintptr_t)63;
    size_t rem_bytes = (wend > cur) ? (size_t)(wend - cur) : 0;
    size_t chunk_sz = (rem_bytes / (2 * (size_t)HIDD * 2)) & ~(size_t)127;
    if (chunk_sz > 100096) chunk_sz = 100096;  // one chunk if ws allows
    if (chunk_sz < 256) return;  // fail soft
    const int CH = (int)chunk_sz;
    ushort_t* bufA = (ushort_t*)cur;
    ushort_t* bufB = bufA + (size_t)CH * HIDD;

    hipMemsetAsync(zbase, 0, zero_bytes, stream);

    dim3 blk(256);

    // ---- prep: input/weight conversions ----
    conv_f2b_kernel<<<2048, blk, 0, stream>>>(emb_nodes, xemb, (long)NN * LATD);
    conv_f2b_kernel<<<2048, blk, 0, stream>>>(enc_nodes, xenc, (long)NN * LATD);
    transpose_conv_kernel<<<(LATD * HIDD + 255) / 256, blk, 0, stream>>>(Wc1, Wc1t, LATD, HIDD);
    transpose_conv_kernel<<<(HIDD * HIDD + 255) / 256, blk, 0, stream>>>(Wc2, Wc2t, HIDD, HIDD);
    transpose_conv_kernel<<<(LATD * HIDD + 255) / 256, blk, 0, stream>>>(Wn1, Wn1t, LATD, HIDD);
    transpose_conv_kernel<<<(HIDD * LATD + 255) / 256, blk, 0, stream>>>(Wn2, Wn2t, HIDD, LATD);
    transpose_conv_kernel<<<(LATD * HIDD + 255) / 256, blk, 0, stream>>>(We1, We1tA, LATD, HIDD);
    transpose_conv_kernel<<<(LATD * HIDD + 255) / 256, blk, 0, stream>>>(We1 + (size_t)LATD * HIDD, We1tB, LATD, HIDD);
    transpose_conv_kernel<<<(HIDD * LATD + 255) / 256, blk, 0, stream>>>(We2, We2t, HIDD, LATD);

    // ---- fused node chain, chunked: xemb->h1->h2->embeddings ----
    for (int m0 = 0; m0 < NN; m0 += CH) {
        int cm = (NN - m0 < CH) ? (NN - m0) : CH;
        int mt = (cm + 127) / 128;
        gemm_mfma<ACT_TANH, true><<<mt * (HIDD / 128), blk, 0, stream>>>(
            xemb + (size_t)m0 * LATD, Wc1t, bc1, bufA, cm, HIDD, LATD, HIDD / 128);
        gemm_mfma<ACT_TANH, true><<<mt * (HIDD / 128), blk, 0, stream>>>(
            bufA, Wc2t, bc2, bufB, cm, HIDD, HIDD, HIDD / 128);
        emb_kernel<<<(cm + 255) / 256, blk, 0, stream>>>(
            bufB, Wc3, bc3, out_emb + (size_t)m0 * EMBD, cm);
    }

    // ---- cluster means ----
    cluster_accum<<<(NN + 255) / 256, blk, 0, stream>>>(out_emb, clusters, csums, ccnt);
    means_kernel<<<(NC + 255) / 256, blk, 0, stream>>>(csums, ccnt, means);

    // ---- super edge weights (4 edges/thread) ----
    sg_lik_kernel<<<(NES / 4 + 255) / 256, blk, 0, stream>>>(means, sg0, sg1, sg_lik, stats);
    sgw_kernel<<<(NES / 4 + 255) / 256, blk, 0, stream>>>(sg_lik, stats, sg_gamma, sg_beta, out_sew);

    // ---- bipartite edge weights (hist fused; 4 edges/thread) ----
    bg_lik_kernel<<<(NEB / 4 + 255) / 256, blk, 0, stream>>>(out_emb, means, bg_src, bg_dst, bg_lik, stats, cnt);
    bw_kernel<<<(NEB / 4 + 255) / 256, blk, 0, stream>>>(bg_lik, stats, bg_gamma, bg_beta, bg_src, bwv, denom);
    bw_norm_kernel<<<(NEB / 4 + 255) / 256, blk, 0, stream>>>(bwv, denom, bg_src, out_bw);

    // ---- counting sort of edges by destination cluster ----
    scan_kernel<<<1, 1024, 0, stream>>>(cnt, offs, NC);
    scatter_kernel<<<(NEB / 4 + 255) / 256, blk, 0, stream>>>(bg_dst, offs, fill, eids);

    // ---- node messages: FUSED relu(relu(xenc@Wn1)@Wn2) -> nmsgb (bf16) ----
    fused_mlp<true><<<(NN + 127) / 128, blk, 0, stream>>>(
        xenc, Wn1t, cn1, Wn2t, cn2, nmsgb, NN);

    // ---- supernodes (sorted, no atomics; writes fp32 + bf16) ----
    supernodes_kernel<<<NC, blk, 0, stream>>>(nmsgb, bwv, bg_src, eids, offs, out_sn, sn_bf);

    // ---- premultiply: P0 = sn@We1_top, P1 = sn@We1_bot (no bias/act) ----
    {
        int mt = (NC + 127) / 128;
        gemm_mfma<ACT_NONE, true><<<mt * (HIDD / 128), blk, 0, stream>>>(
            sn_bf, We1tA, zbias, P0b, NC, HIDD, LATD, HIDD / 128);
        gemm_mfma<ACT_NONE, true><<<mt * (HIDD / 128), blk, 0, stream>>>(
            sn_bf, We1tB, zbias, P1b, NC, HIDD, LATD, HIDD / 128);
    }

    // ---- superedges: FUSED relu(relu(P0[sg0]+P1[sg1]+ce1)@We2+ce2) ----
    fused_edge<<<(NES + 127) / 128, blk, 0, stream>>>(
        P0b, P1b, ce1, We2t, ce2, out_se, NES, sg0, sg1);
}

// Round 14
// 821.184 us; speedup vs baseline: 1.1698x; 1.0770x over previous
//
#include <hip/hip_runtime.h>
#include <cstdint>
#include <cstddef>

// Problem constants (SuperGraphConstruction)
#define NN 100000      // nodes
#define NC 20000       // clusters
#define LATD 128
#define HIDD 512
#define EMBD 12
#define NES 160000     // super edges
#define NEB 800000     // bipartite edges

enum { ACT_NONE = 0, ACT_TANH = 1, ACT_RELU = 2 };

typedef __attribute__((ext_vector_type(8))) short bf16x8;
typedef __attribute__((ext_vector_type(4))) float f32x4;
typedef unsigned short ushort_t;

__device__ __forceinline__ float fast_tanh(float x) {
    return 1.f - 2.f / (__expf(2.f * x) + 1.f);
}
__device__ __forceinline__ ushort_t f2bf(float f) {
    union { float f; unsigned u; } x; x.f = f;
    unsigned r = x.u + 0x7FFFu + ((x.u >> 16) & 1u);  // RNE
    return (ushort_t)(r >> 16);
}
__device__ __forceinline__ float bf2f(ushort_t h) {
    union { unsigned u; float f; } x; x.u = ((unsigned)h) << 16;
    return x.f;
}

typedef __attribute__((address_space(1))) void gvoid_t;
typedef __attribute__((address_space(3))) void svoid_t;
__device__ __forceinline__ void gload_lds16(const void* g, void* l) {
    __builtin_amdgcn_global_load_lds((gvoid_t*)g, (svoid_t*)l, 16, 0, 0);
}

// bijective XCD swizzle (m204): each XCD gets a contiguous span of wg ids
__device__ __forceinline__ int xcd_swz(int bid, int nwg) {
    int q = nwg >> 3, r = nwg & 7;
    int xcd = bid & 7, idx = bid >> 3;
    int base = (xcd < r) ? xcd * (q + 1) : r * (q + 1) + (xcd - r) * q;
    return base + idx;
}

// ---------------------------------------------------------------------------
__global__ __launch_bounds__(256) void conv_f2b_kernel(
    const float* __restrict__ in, ushort_t* __restrict__ out, long n)
{
    long i = ((long)blockIdx.x * 256 + threadIdx.x) * 8;
    long stride = (long)gridDim.x * 256 * 8;
    for (; i + 7 < n; i += stride) {
        float4 a = *(const float4*)(in + i);
        float4 b = *(const float4*)(in + i + 4);
        ushort_t o[8] = { f2bf(a.x), f2bf(a.y), f2bf(a.z), f2bf(a.w),
                          f2bf(b.x), f2bf(b.y), f2bf(b.z), f2bf(b.w) };
        *(int4*)(out + i) = *(int4*)o;
    }
}

// W [K][N] fp32 -> Wt [N][K] bf16
__global__ __launch_bounds__(256) void transpose_conv_kernel(
    const float* __restrict__ W, ushort_t* __restrict__ Wt, int K, int N)
{
    int i = blockIdx.x * 256 + threadIdx.x;
    if (i >= K * N) return;
    int n = i / K, k = i % K;
    Wt[i] = f2bf(W[(size_t)k * N + n]);
}

// ---------------------------------------------------------------------------
// bf16 MFMA GEMM (m97 + T2 swizzle + T1 XCD swizzle). 1D grid, n-inner.
// Epilogue stages the C tile through LDS (reusing As/Bs) and writes
// coalesced 16B/lane segments (fixes 2x HBM write amplification).
// ---------------------------------------------------------------------------
template<int ACT>
__global__ __launch_bounds__(256) void gemm_mfma(
    const ushort_t* __restrict__ A, const ushort_t* __restrict__ Bt,
    const float* __restrict__ bias, ushort_t* __restrict__ Cv,
    int M, int N, int K, int nTilesN)
{
    __shared__ ushort_t smem[2 * 128 * 64];
    ushort_t* As = smem;
    ushort_t* Bs = smem + 128 * 64;
    ushort_t* Cs = smem;               // epilogue: [128][128] swizzled tile

    const int wg = xcd_swz(blockIdx.x, gridDim.x);
    const int m0 = (wg / nTilesN) * 128, n0 = (wg % nTilesN) * 128;

    const int tid = threadIdx.x;
    const int w = tid >> 6, lane = tid & 63;
    const int wm = w >> 1, wn = w & 1;
    const int lr = lane & 15, lg = lane >> 4;
    const int srow = lane >> 3;
    const int sseg = (lane & 7) ^ srow;

    f32x4 acc[4][4];
#pragma unroll
    for (int i = 0; i < 4; ++i)
#pragma unroll
        for (int j = 0; j < 4; ++j) acc[i][j] = (f32x4){0.f, 0.f, 0.f, 0.f};

    for (int k0 = 0; k0 < K; k0 += 64) {
#pragma unroll
        for (int i = 0; i < 4; ++i) {
            int c = w * 4 + i;
            int row = c * 8 + srow;
            int gm = m0 + row; if (gm >= M) gm = M - 1;
            gload_lds16(A + (size_t)gm * K + k0 + sseg * 8, As + c * 512);
            gload_lds16(Bt + (size_t)(n0 + row) * K + k0 + sseg * 8, Bs + c * 512);
        }
        __syncthreads();
#pragma unroll
        for (int ks = 0; ks < 2; ++ks) {
            bf16x8 af[4], bf[4];
#pragma unroll
            for (int mt = 0; mt < 4; ++mt) {
                int row = wm * 64 + mt * 16 + lr;
                int slot = (ks * 4 + lg) ^ (row & 7);
                af[mt] = *(const bf16x8*)&As[row * 64 + slot * 8];
            }
#pragma unroll
            for (int nt = 0; nt < 4; ++nt) {
                int row = wn * 64 + nt * 16 + lr;
                int slot = (ks * 4 + lg) ^ (row & 7);
                bf[nt] = *(const bf16x8*)&Bs[row * 64 + slot * 8];
            }
#pragma unroll
            for (int mt = 0; mt < 4; ++mt)
#pragma unroll
                for (int nt = 0; nt < 4; ++nt)
                    acc[mt][nt] = __builtin_amdgcn_mfma_f32_16x16x32_bf16(
                        af[mt], bf[nt], acc[mt][nt], 0, 0, 0);
        }
        __syncthreads();
    }

    // ---- epilogue: act+bias -> Cs (swizzled) -> coalesced 16B writes ----
#pragma unroll
    for (int nt = 0; nt < 4; ++nt) {
        int colL = wn * 64 + nt * 16 + lr;
        float bv = bias[n0 + colL];
        int cseg = colL >> 3, coff = colL & 7;
#pragma unroll
        for (int mt = 0; mt < 4; ++mt) {
#pragma unroll
            for (int r = 0; r < 4; ++r) {
                int rowL = wm * 64 + mt * 16 + lg * 4 + r;
                float v = acc[mt][nt][r] + bv;
                if (ACT == ACT_TANH) v = fast_tanh(v);
                else if (ACT == ACT_RELU) v = fmaxf(v, 0.f);
                int slot = cseg ^ (rowL & 7);
                Cs[rowL * 128 + slot * 8 + coff] = f2bf(v);
            }
        }
    }
    __syncthreads();
#pragma unroll
    for (int it = 0; it < 8; ++it) {
        int idx = it * 256 + tid;          // 0..2047 = 128 rows x 16 segs
        int rowL = idx >> 4, seg = idx & 15;
        int slot = seg ^ (rowL & 7);
        int gr = m0 + rowL;
        if (gr < M) {
            int4 v = *(const int4*)&Cs[rowL * 128 + slot * 8];
            *(int4*)&Cv[(size_t)gr * N + n0 + seg * 8] = v;
        }
    }
}

// ---------------------------------------------------------------------------
// FUSED 2-layer MLP (node messages): out = relu(relu(A@W1+b1)@W2+b2)
// ---------------------------------------------------------------------------
template<bool OUT_BF16>
__global__ __launch_bounds__(256) void fused_mlp(
    const ushort_t* __restrict__ A, const ushort_t* __restrict__ W1t,
    const float* __restrict__ b1, const ushort_t* __restrict__ W2t,
    const float* __restrict__ b2, void* __restrict__ Cv, int M)
{
    __shared__ ushort_t As[128 * 128];
    __shared__ ushort_t Ws[128 * 64];
    __shared__ ushort_t Hs[128 * 128];

    const int tid = threadIdx.x;
    const int m0 = blockIdx.x * 128;
    const int w = tid >> 6, lane = tid & 63;
    const int wm = w >> 1, wn = w & 1;
    const int lr = lane & 15, lg = lane >> 4;
    const int srow = lane >> 3;
    const int sseg = (lane & 7) ^ srow;

    f32x4 acc2[4][4];
#pragma unroll
    for (int i = 0; i < 4; ++i)
#pragma unroll
        for (int j = 0; j < 4; ++j) acc2[i][j] = (f32x4){0.f, 0.f, 0.f, 0.f};

    {   // stage A resident: [128][128], 16-slot swizzled rows
        const int arow4 = lane >> 4;
        const int aslot = lane & 15;
#pragma unroll
        for (int rnd = 0; rnd < 8; ++rnd) {
            int row = rnd * 16 + w * 4 + arow4;
            int gm = m0 + row; if (gm >= M) gm = M - 1;
            int seg = aslot ^ (row & 7);
            gload_lds16(A + (size_t)gm * 128 + seg * 8, As + row * 128);
        }
    }

    for (int c = 0; c < 4; ++c) {
        f32x4 acc1[4][4];
#pragma unroll
        for (int i = 0; i < 4; ++i)
#pragma unroll
            for (int j = 0; j < 4; ++j) acc1[i][j] = (f32x4){0.f, 0.f, 0.f, 0.f};

        for (int k0 = 0; k0 < 128; k0 += 64) {
#pragma unroll
            for (int i = 0; i < 4; ++i) {
                int ch = w * 4 + i;
                int row = ch * 8 + srow;
                gload_lds16(W1t + (size_t)(c * 128 + row) * 128 + k0 + sseg * 8,
                            Ws + ch * 512);
            }
            __syncthreads();
#pragma unroll
            for (int ks = 0; ks < 2; ++ks) {
                bf16x8 af[4], bf[4];
#pragma unroll
                for (int mt = 0; mt < 4; ++mt) {
                    int row = wm * 64 + mt * 16 + lr;
                    int seg = (k0 >> 3) + ks * 4 + lg;
                    int slot = seg ^ (row & 7);
                    af[mt] = *(const bf16x8*)&As[row * 128 + slot * 8];
                }
#pragma unroll
                for (int nt = 0; nt < 4; ++nt) {
                    int row = wn * 64 + nt * 16 + lr;
                    int slot = (ks * 4 + lg) ^ (row & 7);
                    bf[nt] = *(const bf16x8*)&Ws[row * 64 + slot * 8];
                }
#pragma unroll
                for (int mt = 0; mt < 4; ++mt)
#pragma unroll
                    for (int nt = 0; nt < 4; ++nt)
                        acc1[mt][nt] = __builtin_amdgcn_mfma_f32_16x16x32_bf16(
                            af[mt], bf[nt], acc1[mt][nt], 0, 0, 0);
            }
            __syncthreads();
        }

        // h = relu(acc1 + b1) -> Hs
#pragma unroll
        for (int nt = 0; nt < 4; ++nt) {
            int colL = wn * 64 + nt * 16 + lr;
            float bv = b1[c * 128 + colL];
            int cseg = colL >> 3, coff = colL & 7;
#pragma unroll
            for (int mt = 0; mt < 4; ++mt) {
#pragma unroll
                for (int r = 0; r < 4; ++r) {
                    int row = wm * 64 + mt * 16 + lg * 4 + r;
                    float v = fmaxf(acc1[mt][nt][r] + bv, 0.f);
                    int slot = cseg ^ (row & 7);
                    Hs[row * 128 + slot * 8 + coff] = f2bf(v);
                }
            }
        }

        for (int k0h = 0; k0h < 128; k0h += 64) {
#pragma unroll
            for (int i = 0; i < 4; ++i) {
                int ch = w * 4 + i;
                int row = ch * 8 + srow;
                gload_lds16(W2t + (size_t)row * HIDD + c * 128 + k0h + sseg * 8,
                            Ws + ch * 512);
            }
            __syncthreads();
#pragma unroll
            for (int ks = 0; ks < 2; ++ks) {
                bf16x8 af[4], bf[4];
#pragma unroll
                for (int mt = 0; mt < 4; ++mt) {
                    int row = wm * 64 + mt * 16 + lr;
                    int seg = (k0h >> 3) + ks * 4 + lg;
                    int slot = seg ^ (row & 7);
                    af[mt] = *(const bf16x8*)&Hs[row * 128 + slot * 8];
                }
#pragma unroll
                for (int nt = 0; nt < 4; ++nt) {
                    int row = wn * 64 + nt * 16 + lr;
                    int slot = (ks * 4 + lg) ^ (row & 7);
                    bf[nt] = *(const bf16x8*)&Ws[row * 64 + slot * 8];
                }
#pragma unroll
                for (int mt = 0; mt < 4; ++mt)
#pragma unroll
                    for (int nt = 0; nt < 4; ++nt)
                        acc2[mt][nt] = __builtin_amdgcn_mfma_f32_16x16x32_bf16(
                            af[mt], bf[nt], acc2[mt][nt], 0, 0, 0);
            }
            __syncthreads();
        }
    }

#pragma unroll
    for (int nt = 0; nt < 4; ++nt) {
        int col = wn * 64 + nt * 16 + lr;
        float bv = b2[col];
#pragma unroll
        for (int mt = 0; mt < 4; ++mt) {
#pragma unroll
            for (int r = 0; r < 4; ++r) {
                int row = m0 + wm * 64 + mt * 16 + lg * 4 + r;
                if (row >= M) continue;
                float v = fmaxf(acc2[mt][nt][r] + bv, 0.f);
                if (OUT_BF16) ((ushort_t*)Cv)[(size_t)row * 128 + col] = f2bf(v);
                else ((float*)Cv)[(size_t)row * 128 + col] = v;
            }
        }
    }
}

// ---------------------------------------------------------------------------
// FUSED superedge: out[e] = relu(relu(P0[sg0[e]]+P1[sg1[e]]+b1)@W2+b2)
// ---------------------------------------------------------------------------
__global__ __launch_bounds__(256) void fused_edge(
    const ushort_t* __restrict__ P0, const ushort_t* __restrict__ P1,
    const float* __restrict__ b1, const ushort_t* __restrict__ W2t,
    const float* __restrict__ b2, float* __restrict__ Cv, int M,
    const int* __restrict__ g0, const int* __restrict__ g1)
{
    __shared__ ushort_t Hs[128 * 128];
    __shared__ ushort_t Ws[128 * 64];
    __shared__ int i0s[128], i1s[128];

    const int tid = threadIdx.x;
    const int m0 = blockIdx.x * 128;
    const int w = tid >> 6, lane = tid & 63;
    const int wm = w >> 1, wn = w & 1;
    const int lr = lane & 15, lg = lane >> 4;
    const int srow = lane >> 3;
    const int sseg = (lane & 7) ^ srow;
    const int er = lane >> 4;
    const int cg = lane & 15;

    if (tid < 128) {
        int gm = m0 + tid; if (gm >= M) gm = M - 1;
        i0s[tid] = g0[gm];
        i1s[tid] = g1[gm];
    }
    __syncthreads();

    f32x4 acc2[4][4];
#pragma unroll
    for (int i = 0; i < 4; ++i)
#pragma unroll
        for (int j = 0; j < 4; ++j) acc2[i][j] = (f32x4){0.f, 0.f, 0.f, 0.f};

    for (int c = 0; c < 4; ++c) {
        float bch[8];
#pragma unroll
        for (int j = 0; j < 8; ++j) bch[j] = b1[c * 128 + cg * 8 + j];

#pragma unroll
        for (int pass = 0; pass < 8; ++pass) {
            int row = pass * 16 + w * 4 + er;
            int i0 = i0s[row], i1 = i1s[row];
            bf16x8 p0 = *(const bf16x8*)(P0 + (size_t)i0 * HIDD + c * 128 + cg * 8);
            bf16x8 p1 = *(const bf16x8*)(P1 + (size_t)i1 * HIDD + c * 128 + cg * 8);
            ushort_t o[8];
#pragma unroll
            for (int j = 0; j < 8; ++j) {
                float v = bf2f((ushort_t)p0[j]) + bf2f((ushort_t)p1[j]) + bch[j];
                o[j] = f2bf(fmaxf(v, 0.f));
            }
            int slot = cg ^ (row & 7);
            *(int4*)&Hs[row * 128 + slot * 8] = *(int4*)o;
        }

        for (int k0h = 0; k0h < 128; k0h += 64) {
#pragma unroll
            for (int i = 0; i < 4; ++i) {
                int ch = w * 4 + i;
                int row = ch * 8 + srow;
                gload_lds16(W2t + (size_t)row * HIDD + c * 128 + k0h + sseg * 8,
                            Ws + ch * 512);
            }
            __syncthreads();
#pragma unroll
            for (int ks = 0; ks < 2; ++ks) {
                bf16x8 af[4], bf[4];
#pragma unroll
                for (int mt = 0; mt < 4; ++mt) {
                    int row = wm * 64 + mt * 16 + lr;
                    int seg = (k0h >> 3) + ks * 4 + lg;
                    int slot = seg ^ (row & 7);
                    af[mt] = *(const bf16x8*)&Hs[row * 128 + slot * 8];
                }
#pragma unroll
                for (int nt = 0; nt < 4; ++nt) {
                    int row = wn * 64 + nt * 16 + lr;
                    int slot = (ks * 4 + lg) ^ (row & 7);
                    bf[nt] = *(const bf16x8*)&Ws[row * 64 + slot * 8];
                }
#pragma unroll
                for (int mt = 0; mt < 4; ++mt)
#pragma unroll
                    for (int nt = 0; nt < 4; ++nt)
                        acc2[mt][nt] = __builtin_amdgcn_mfma_f32_16x16x32_bf16(
                            af[mt], bf[nt], acc2[mt][nt], 0, 0, 0);
            }
            __syncthreads();
        }
    }

#pragma unroll
    for (int nt = 0; nt < 4; ++nt) {
        int col = wn * 64 + nt * 16 + lr;
        float bv = b2[col];
#pragma unroll
        for (int mt = 0; mt < 4; ++mt) {
#pragma unroll
            for (int r = 0; r < 4; ++r) {
                int row = m0 + wm * 64 + mt * 16 + lg * 4 + r;
                if (row >= M) continue;
                float v = fmaxf(acc2[mt][nt][r] + bv, 0.f);
                Cv[(size_t)row * 128 + col] = v;
            }
        }
    }
}

// ---------------------------------------------------------------------------
// embeddings = l2norm(h2 @ Wc3 + bc3); THREAD-per-row; h2 bf16.
// ---------------------------------------------------------------------------
__global__ __launch_bounds__(256) void emb_kernel(
    const ushort_t* __restrict__ h2, const float* __restrict__ W,
    const float* __restrict__ bias, float* __restrict__ out, int M)
{
    __shared__ float Wl[HIDD * EMBD];
    for (int i = threadIdx.x; i < HIDD * EMBD; i += 256) Wl[i] = W[i];
    __syncthreads();

    int m = blockIdx.x * 256 + threadIdx.x;
    if (m >= M) return;
    const ushort_t* row = h2 + (size_t)m * HIDD;

    float acc[EMBD] = {};
#pragma unroll 2
    for (int k0 = 0; k0 < HIDD; k0 += 8) {
        bf16x8 v = *(const bf16x8*)(row + k0);
        float f[8];
#pragma unroll
        for (int u = 0; u < 8; ++u) f[u] = bf2f((ushort_t)v[u]);
#pragma unroll
        for (int u = 0; u < 8; ++u) {
            const float* wr = &Wl[(k0 + u) * EMBD];
#pragma unroll
            for (int j = 0; j < EMBD; ++j) acc[j] += f[u] * wr[j];
        }
    }
    float vv[EMBD];
    float ss = 0.f;
#pragma unroll
    for (int j = 0; j < EMBD; ++j) { vv[j] = acc[j] + bias[j]; ss += vv[j] * vv[j]; }
    float inv = 1.f / fmaxf(sqrtf(ss), 1e-12f);
#pragma unroll
    for (int j = 0; j < EMBD; ++j) out[(size_t)m * EMBD + j] = vv[j] * inv;
}

// ---------------------------------------------------------------------------
__global__ void cluster_accum(const float* __restrict__ emb,
                              const int* __restrict__ clusters,
                              float* __restrict__ csums, float* __restrict__ ccnt)
{
    int n = blockIdx.x * 256 + threadIdx.x;
    if (n >= NN) return;
    int c = clusters[n];
    const float4* row = (const float4*)(emb + (size_t)n * EMBD);
    float4 r0 = row[0], r1 = row[1], r2 = row[2];
    float* dst = &csums[(size_t)c * EMBD];
    atomicAdd(&dst[0], r0.x);  atomicAdd(&dst[1], r0.y);
    atomicAdd(&dst[2], r0.z);  atomicAdd(&dst[3], r0.w);
    atomicAdd(&dst[4], r1.x);  atomicAdd(&dst[5], r1.y);
    atomicAdd(&dst[6], r1.z);  atomicAdd(&dst[7], r1.w);
    atomicAdd(&dst[8], r2.x);  atomicAdd(&dst[9], r2.y);
    atomicAdd(&dst[10], r2.z); atomicAdd(&dst[11], r2.w);
    atomicAdd(&ccnt[c], 1.f);
}

__global__ void means_kernel(const float* __restrict__ csums,
                             const float* __restrict__ ccnt,
                             float* __restrict__ means)
{
    int c = blockIdx.x * 256 + threadIdx.x;
    if (c >= NC) return;
    float cv = fmaxf(ccnt[c], 1.f);
    float v[EMBD];
    float ss = 0.f;
#pragma unroll
    for (int j = 0; j < EMBD; ++j) {
        v[j] = csums[(size_t)c * EMBD + j] / cv;
        ss += v[j] * v[j];
    }
    float inv = 1.f / fmaxf(sqrtf(ss), 1e-12f);
#pragma unroll
    for (int j = 0; j < EMBD; ++j) means[(size_t)c * EMBD + j] = v[j] * inv;
}

// ---------------------------------------------------------------------------
__device__ __forceinline__ void block_stats2(float x, float x2, float* s_sum, float* s_sumsq)
{
#pragma unroll
    for (int s = 32; s >= 1; s >>= 1) {
        x += __shfl_xor(x, s, 64);
        x2 += __shfl_xor(x2, s, 64);
    }
    __shared__ float w0[4], w1[4];
    int lane = threadIdx.x & 63, w = threadIdx.x >> 6;
    if (lane == 0) { w0[w] = x; w1[w] = x2; }
    __syncthreads();
    if (threadIdx.x == 0) {
        float a = 0.f, b = 0.f;
        for (int i = 0; i < 4; ++i) { a += w0[i]; b += w1[i]; }
        atomicAdd(s_sum, a);
        atomicAdd(s_sumsq, b);
    }
}

// ---------------------------------------------------------------------------
__global__ __launch_bounds__(256) void sg_lik_kernel(
    const float* __restrict__ means, const int* __restrict__ sg0,
    const int* __restrict__ sg1, float* __restrict__ sg_lik, float* __restrict__ stats)
{
    int base = (blockIdx.x * 256 + threadIdx.x) * 4;
    float xs = 0.f, xs2 = 0.f;
    if (base < NES) {
        int4 a4 = *(const int4*)(sg0 + base);
        int4 b4 = *(const int4*)(sg1 + base);
        int ai[4] = {a4.x, a4.y, a4.z, a4.w};
        int bi[4] = {b4.x, b4.y, b4.z, b4.w};
        float4 av[4][3], bv[4][3];
#pragma unroll
        for (int i = 0; i < 4; ++i) {
            const float4* ap = (const float4*)(means + (size_t)ai[i] * EMBD);
            const float4* bp = (const float4*)(means + (size_t)bi[i] * EMBD);
            av[i][0] = ap[0]; av[i][1] = ap[1]; av[i][2] = ap[2];
            bv[i][0] = bp[0]; bv[i][1] = bp[1]; bv[i][2] = bp[2];
        }
        float4 o;
        float* op = (float*)&o;
#pragma unroll
        for (int i = 0; i < 4; ++i) {
            float s = av[i][0].x * bv[i][0].x + av[i][0].y * bv[i][0].y
                    + av[i][0].z * bv[i][0].z + av[i][0].w * bv[i][0].w
                    + av[i][1].x * bv[i][1].x + av[i][1].y * bv[i][1].y
                    + av[i][1].z * bv[i][1].z + av[i][1].w * bv[i][1].w
                    + av[i][2].x * bv[i][2].x + av[i][2].y * bv[i][2].y
                    + av[i][2].z * bv[i][2].z + av[i][2].w * bv[i][2].w;
            op[i] = s;
            xs += s; xs2 += s * s;
        }
        *(float4*)(sg_lik + base) = o;
    }
    block_stats2(xs, xs2, &stats[0], &stats[1]);
}

__global__ __launch_bounds__(256) void sgw_kernel(
    const float* __restrict__ sg_lik, const float* __restrict__ stats,
    const float* __restrict__ gamma, const float* __restrict__ beta,
    float* __restrict__ out)
{
    int base = (blockIdx.x * 256 + threadIdx.x) * 4;
    if (base >= NES) return;
    float m = stats[0] / (float)NES;
    float var = stats[1] / (float)NES - m * m;
    float rs = rsqrtf(var + 1e-5f) * gamma[0];
    float4 v = *(const float4*)(sg_lik + base);
    float4 o;
    o.x = 1.f / (1.f + __expf(-((v.x - m) * rs + beta[0])));
    o.y = 1.f / (1.f + __expf(-((v.y - m) * rs + beta[0])));
    o.z = 1.f / (1.f + __expf(-((v.z - m) * rs + beta[0])));
    o.w = 1.f / (1.f + __expf(-((v.w - m) * rs + beta[0])));
    *(float4*)(out + base) = o;
}

// ---------------------------------------------------------------------------
__global__ __launch_bounds__(256) void bg_lik_kernel(
    const float* __restrict__ emb, const float* __restrict__ means,
    const int* __restrict__ bg_src, const int* __restrict__ bg_dst,
    float* __restrict__ bg_lik, float* __restrict__ stats, int* __restrict__ cnt)
{
    int base = (blockIdx.x * 256 + threadIdx.x) * 4;
    float xs = 0.f, xs2 = 0.f;
    if (base < NEB) {
        int4 s4 = *(const int4*)(bg_src + base);
        int4 d4 = *(const int4*)(bg_dst + base);
        int si[4] = {s4.x, s4.y, s4.z, s4.w};
        int di[4] = {d4.x, d4.y, d4.z, d4.w};
        float4 av[4][3], bv[4][3];
#pragma unroll
        for (int i = 0; i < 4; ++i) {
            const float4* ap = (const float4*)(emb + (size_t)si[i] * EMBD);
            const float4* bp = (const float4*)(means + (size_t)di[i] * EMBD);
            av[i][0] = ap[0]; av[i][1] = ap[1]; av[i][2] = ap[2];
            bv[i][0] = bp[0]; bv[i][1] = bp[1]; bv[i][2] = bp[2];
        }
#pragma unroll
        for (int i = 0; i < 4; ++i) atomicAdd(&cnt[di[i]], 1);
        float4 o;
        float* op = (float*)&o;
#pragma unroll
        for (int i = 0; i < 4; ++i) {
            float s = av[i][0].x * bv[i][0].x + av[i][0].y * bv[i][0].y
                    + av[i][0].z * bv[i][0].z + av[i][0].w * bv[i][0].w
                    + av[i][1].x * bv[i][1].x + av[i][1].y * bv[i][1].y
                    + av[i][1].z * bv[i][1].z + av[i][1].w * bv[i][1].w
                    + av[i][2].x * bv[i][2].x + av[i][2].y * bv[i][2].y
                    + av[i][2].z * bv[i][2].z + av[i][2].w * bv[i][2].w;
            op[i] = s;
            xs += s; xs2 += s * s;
        }
        *(float4*)(bg_lik + base) = o;
    }
    block_stats2(xs, xs2, &stats[2], &stats[3]);
}

__global__ __launch_bounds__(256) void bw_kernel(
    const float* __restrict__ bg_lik, const float* __restrict__ stats,
    const float* __restrict__ gamma, const float* __restrict__ beta,
    const int* __restrict__ bg_src, float* __restrict__ bw, float* __restrict__ denom)
{
    int base = (blockIdx.x * 256 + threadIdx.x) * 4;
    if (base >= NEB) return;
    float m = stats[2] / (float)NEB;
    float var = stats[3] / (float)NEB - m * m;
    float rs = rsqrtf(var + 1e-5f) * gamma[0];
    int4 s4 = *(const int4*)(bg_src + base);
    int si[4] = {s4.x, s4.y, s4.z, s4.w};
    float4 v = *(const float4*)(bg_lik + base);
    float vi[4] = {v.x, v.y, v.z, v.w};
    float4 o;
    float* op = (float*)&o;
#pragma unroll
    for (int i = 0; i < 4; ++i) {
        float w = __expf((vi[i] - m) * rs + beta[0]);
        op[i] = w;
        atomicAdd(&denom[si[i]], w);
    }
    *(float4*)(bw + base) = o;
}

__global__ __launch_bounds__(256) void bw_norm_kernel(
    float* __restrict__ bw, const float* __restrict__ denom,
    const int* __restrict__ bg_src, float* __restrict__ out)
{
    int base = (blockIdx.x * 256 + threadIdx.x) * 4;
    if (base >= NEB) return;
    int4 s4 = *(const int4*)(bg_src + base);
    int si[4] = {s4.x, s4.y, s4.z, s4.w};
    float dv[4];
#pragma unroll
    for (int i = 0; i < 4; ++i) dv[i] = denom[si[i]];
    float4 v = *(const float4*)(bw + base);
    float4 o;
    o.x = v.x / (1e-12f + dv[0]);
    o.y = v.y / (1e-12f + dv[1]);
    o.z = v.z / (1e-12f + dv[2]);
    o.w = v.w / (1e-12f + dv[3]);
    *(float4*)(bw + base) = o;
    *(float4*)(out + base) = o;
}

// ---------------------------------------------------------------------------
__global__ __launch_bounds__(1024) void scan_kernel(
    const int* __restrict__ cnt, int* __restrict__ offs, int C)
{
    __shared__ int wsum[16];
    __shared__ int carry_s, ctot_s;
    const int tid = threadIdx.x;
    const int lane = tid & 63, w = tid >> 6;
    if (tid == 0) carry_s = 0;
    __syncthreads();
    for (int base = 0; base < C; base += 1024) {
        int i = base + tid;
        int v = (i < C) ? cnt[i] : 0;
        int x = v;
#pragma unroll
        for (int s = 1; s < 64; s <<= 1) {
            int y = __shfl_up(x, s, 64);
            if (lane >= s) x += y;
        }
        if (lane == 63) wsum[w] = x;
        __syncthreads();
        if (tid == 0) {
            int s = 0;
            for (int k = 0; k < 16; ++k) { int t = wsum[k]; wsum[k] = s; s += t; }
            ctot_s = s;
        }
        __syncthreads();
        int excl = carry_s + wsum[w] + (x - v);
        if (i < C) offs[i] = excl;
        __syncthreads();
        if (tid == 0) carry_s += ctot_s;
        __syncthreads();
    }
    if (tid == 0) offs[C] = carry_s;
}

__global__ void scatter_kernel(const int* __restrict__ bg_dst,
                               const int* __restrict__ offs,
                               int* __restrict__ fill, int* __restrict__ eids)
{
    int base = (blockIdx.x * 256 + threadIdx.x) * 4;
    if (base >= NEB) return;
    int4 d4 = *(const int4*)(bg_dst + base);
    int di[4] = {d4.x, d4.y, d4.z, d4.w};
#pragma unroll
    for (int i = 0; i < 4; ++i) {
        int p = atomicAdd(&fill[di[i]], 1);
        eids[offs[di[i]] + p] = base + i;
    }
}

// ---------------------------------------------------------------------------
// supernodes: lane-packed gather; writes fp32 out AND bf16 copy (fused conv)
// ---------------------------------------------------------------------------
__global__ __launch_bounds__(256) void supernodes_kernel(
    const ushort_t* __restrict__ nmsg, const float* __restrict__ bw,
    const int* __restrict__ bg_src, const int* __restrict__ eids,
    const int* __restrict__ offs, float* __restrict__ sn,
    ushort_t* __restrict__ sn_bf)
{
    __shared__ float red[4][LATD];
    const int c = blockIdx.x;
    const int tid = threadIdx.x;
    const int wv = tid >> 6, lane = tid & 63;
    const int er = lane >> 4;
    const int cg = lane & 15;
    const int beg = offs[c], end = offs[c + 1];

    float acc[8] = {};
    for (int p = beg + wv * 4 + er; p < end; p += 16) {
        int e = eids[p];
        int s = bg_src[e];
        float w = bw[e];
        bf16x8 v = *(const bf16x8*)(nmsg + (size_t)s * LATD + cg * 8);
#pragma unroll
        for (int j = 0; j < 8; ++j) acc[j] += w * bf2f((ushort_t)v[j]);
    }
#pragma unroll
    for (int j = 0; j < 8; ++j) {
        acc[j] += __shfl_xor(acc[j], 16, 64);
        acc[j] += __shfl_xor(acc[j], 32, 64);
    }
    if (lane < 16) {
        *(float4*)&red[wv][cg * 8]     = (float4){acc[0], acc[1], acc[2], acc[3]};
        *(float4*)&red[wv][cg * 8 + 4] = (float4){acc[4], acc[5], acc[6], acc[7]};
    }
    __syncthreads();
    if (tid < LATD) {
        float s = red[0][tid] + red[1][tid] + red[2][tid] + red[3][tid];
        sn[(size_t)c * LATD + tid] = s;
        sn_bf[(size_t)c * LATD + tid] = f2bf(s);
    }
}

// ---------------------------------------------------------------------------
extern "C" void kernel_launch(void* const* d_in, const int* in_sizes, int n_in,
                              void* d_out, int out_size, void* d_ws, size_t ws_size,
                              hipStream_t stream)
{
    const float* emb_nodes = (const float*)d_in[0];
    const float* enc_nodes = (const float*)d_in[1];
    const float* Wc1 = (const float*)d_in[2];  const float* bc1 = (const float*)d_in[3];
    const float* Wc2 = (const float*)d_in[4];  const float* bc2 = (const float*)d_in[5];
    const float* Wc3 = (const float*)d_in[6];  const float* bc3 = (const float*)d_in[7];
    const float* Wn1 = (const float*)d_in[8];  const float* cn1 = (const float*)d_in[9];
    const float* Wn2 = (const float*)d_in[10]; const float* cn2 = (const float*)d_in[11];
    const float* We1 = (const float*)d_in[12]; const float* ce1 = (const float*)d_in[13];
    const float* We2 = (const float*)d_in[14]; const float* ce2 = (const float*)d_in[15];
    const float* sg_gamma = (const float*)d_in[16]; const float* sg_beta = (const float*)d_in[17];
    const float* bg_gamma = (const float*)d_in[18]; const float* bg_beta = (const float*)d_in[19];
    const int* clusters = (const int*)d_in[20];
    const int* sg0 = (const int*)d_in[21];
    const int* sg1 = sg0 + NES;
    const int* bg_src = (const int*)d_in[22];
    const int* bg_dst = (const int*)d_in[23];

    // output layout (flat, return order)
    float* out_emb = (float*)d_out;                       // NN*EMBD
    float* out_sn  = out_emb + (size_t)NN * EMBD;         // NC*LATD
    float* out_se  = out_sn + (size_t)NC * LATD;          // NES*LATD
    float* out_bw  = out_se + (size_t)NES * LATD;         // NEB
    float* out_sew = out_bw + (size_t)NEB;                // NES

    // ---------------- workspace layout (byte cursor, 64B-aligned) ----------
    uintptr_t cur = (uintptr_t)d_ws;
    uintptr_t wend = cur + ws_size;
    auto alloc = [&](size_t bytes) -> void* {
        cur = (cur + 63) & ~(uintptr_t)63;
        void* p = (void*)cur;
        cur += bytes;
        return p;
    };

    // zeroed region: csums, ccnt, denom, stats, cnt, fill, zbias
    size_t zfloats = (size_t)NC * EMBD + NC + NN + 8 + NC + NC + HIDD;
    float* zbase = (float*)alloc(zfloats * 4);
    float* csums = zbase;
    float* ccnt  = csums + (size_t)NC * EMBD;
    float* denom = ccnt + NC;
    float* stats = denom + NN;
    int*   cnt   = (int*)(stats + 8);
    int*   fill  = cnt + NC;
    float* zbias = (float*)(fill + NC);         // HIDD zeros
    size_t zero_bytes = zfloats * 4;

    float* means  = (float*)alloc((size_t)NC * EMBD * 4);
    float* sg_lik = (float*)alloc((size_t)NES * 4);
    float* bg_lik = (float*)alloc((size_t)NEB * 4);
    float* bwv    = (float*)alloc((size_t)NEB * 4);
    int*   offs   = (int*)alloc((size_t)(NC + 1) * 4);
    int*   eids   = (int*)alloc((size_t)NEB * 4);

    ushort_t* xemb   = (ushort_t*)alloc((size_t)NN * LATD * 2);
    ushort_t* xenc   = (ushort_t*)alloc((size_t)NN * LATD * 2);
    ushort_t* nmsgb  = (ushort_t*)alloc((size_t)NN * LATD * 2);
    ushort_t* sn_bf  = (ushort_t*)alloc((size_t)NC * LATD * 2);
    ushort_t* P0b    = (ushort_t*)alloc((size_t)NC * HIDD * 2);
    ushort_t* P1b    = (ushort_t*)alloc((size_t)NC * HIDD * 2);
    ushort_t* Wc1t  = (ushort_t*)alloc((size_t)LATD * HIDD * 2);
    ushort_t* Wc2t  = (ushort_t*)alloc((size_t)HIDD * HIDD * 2);
    ushort_t* Wn1t  = (ushort_t*)alloc((size_t)LATD * HIDD * 2);
    ushort_t* Wn2t  = (ushort_t*)alloc((size_t)HIDD * LATD * 2);
    ushort_t* We1tA = (ushort_t*)alloc((size_t)HIDD * LATD * 2);  // [512][128]
    ushort_t* We1tB = (ushort_t*)alloc((size_t)HIDD * LATD * 2);  // [512][128]
    ushort_t* We2t  = (ushort_t*)alloc((size_t)HIDD * LATD * 2);  // [128][512]

    cur = (cur + 63) & ~(uintptr_t)63;
    size_t rem_bytes = (wend > cur) ? (size_t)(wend - cur) : 0;
    size_t chunk_sz = (rem_bytes / (2 * (size_t)HIDD * 2)) & ~(size_t)127;
    if (chunk_sz > 100096) chunk_sz = 100096;  // one chunk if ws allows
    if (chunk_sz < 256) return;  // fail soft
    const int CH = (int)chunk_sz;
    ushort_t* bufA = (ushort_t*)cur;
    ushort_t* bufB = bufA + (size_t)CH * HIDD;

    hipMemsetAsync(zbase, 0, zero_bytes, stream);

    dim3 blk(256);

    // ---- prep: input/weight conversions ----
    conv_f2b_kernel<<<2048, blk, 0, stream>>>(emb_nodes, xemb, (long)NN * LATD);
    conv_f2b_kernel<<<2048, blk, 0, stream>>>(enc_nodes, xenc, (long)NN * LATD);
    transpose_conv_kernel<<<(LATD * HIDD + 255) / 256, blk, 0, stream>>>(Wc1, Wc1t, LATD, HIDD);
    transpose_conv_kernel<<<(HIDD * HIDD + 255) / 256, blk, 0, stream>>>(Wc2, Wc2t, HIDD, HIDD);
    transpose_conv_kernel<<<(LATD * HIDD + 255) / 256, blk, 0, stream>>>(Wn1, Wn1t, LATD, HIDD);
    transpose_conv_kernel<<<(HIDD * LATD + 255) / 256, blk, 0, stream>>>(Wn2, Wn2t, HIDD, LATD);
    transpose_conv_kernel<<<(LATD * HIDD + 255) / 256, blk, 0, stream>>>(We1, We1tA, LATD, HIDD);
    transpose_conv_kernel<<<(LATD * HIDD + 255) / 256, blk, 0, stream>>>(We1 + (size_t)LATD * HIDD, We1tB, LATD, HIDD);
    transpose_conv_kernel<<<(HIDD * LATD + 255) / 256, blk, 0, stream>>>(We2, We2t, HIDD, LATD);

    // ---- fused node chain, chunked: xemb->h1->h2->embeddings ----
    for (int m0 = 0; m0 < NN; m0 += CH) {
        int cm = (NN - m0 < CH) ? (NN - m0) : CH;
        int mt = (cm + 127) / 128;
        gemm_mfma<ACT_TANH><<<mt * (HIDD / 128), blk, 0, stream>>>(
            xemb + (size_t)m0 * LATD, Wc1t, bc1, bufA, cm, HIDD, LATD, HIDD / 128);
        gemm_mfma<ACT_TANH><<<mt * (HIDD / 128), blk, 0, stream>>>(
            bufA, Wc2t, bc2, bufB, cm, HIDD, HIDD, HIDD / 128);
        emb_kernel<<<(cm + 255) / 256, blk, 0, stream>>>(
            bufB, Wc3, bc3, out_emb + (size_t)m0 * EMBD, cm);
    }

    // ---- cluster means ----
    cluster_accum<<<(NN + 255) / 256, blk, 0, stream>>>(out_emb, clusters, csums, ccnt);
    means_kernel<<<(NC + 255) / 256, blk, 0, stream>>>(csums, ccnt, means);

    // ---- super edge weights (4 edges/thread) ----
    sg_lik_kernel<<<(NES / 4 + 255) / 256, blk, 0, stream>>>(means, sg0, sg1, sg_lik, stats);
    sgw_kernel<<<(NES / 4 + 255) / 256, blk, 0, stream>>>(sg_lik, stats, sg_gamma, sg_beta, out_sew);

    // ---- bipartite edge weights (hist fused; 4 edges/thread) ----
    bg_lik_kernel<<<(NEB / 4 + 255) / 256, blk, 0, stream>>>(out_emb, means, bg_src, bg_dst, bg_lik, stats, cnt);
    bw_kernel<<<(NEB / 4 + 255) / 256, blk, 0, stream>>>(bg_lik, stats, bg_gamma, bg_beta, bg_src, bwv, denom);
    bw_norm_kernel<<<(NEB / 4 + 255) / 256, blk, 0, stream>>>(bwv, denom, bg_src, out_bw);

    // ---- counting sort of edges by destination cluster ----
    scan_kernel<<<1, 1024, 0, stream>>>(cnt, offs, NC);
    scatter_kernel<<<(NEB / 4 + 255) / 256, blk, 0, stream>>>(bg_dst, offs, fill, eids);

    // ---- node messages: FUSED relu(relu(xenc@Wn1)@Wn2) -> nmsgb (bf16) ----
    fused_mlp<true><<<(NN + 127) / 128, blk, 0, stream>>>(
        xenc, Wn1t, cn1, Wn2t, cn2, nmsgb, NN);

    // ---- supernodes (sorted, no atomics; writes fp32 + bf16) ----
    supernodes_kernel<<<NC, blk, 0, stream>>>(nmsgb, bwv, bg_src, eids, offs, out_sn, sn_bf);

    // ---- premultiply: P0 = sn@We1_top, P1 = sn@We1_bot (no bias/act) ----
    {
        int mt = (NC + 127) / 128;
        gemm_mfma<ACT_NONE><<<mt * (HIDD / 128), blk, 0, stream>>>(
            sn_bf, We1tA, zbias, P0b, NC, HIDD, LATD, HIDD / 128);
        gemm_mfma<ACT_NONE><<<mt * (HIDD / 128), blk, 0, stream>>>(
            sn_bf, We1tB, zbias, P1b, NC, HIDD, LATD, HIDD / 128);
    }

    // ---- superedges: FUSED relu(relu(P0[sg0]+P1[sg1]+ce1)@We2+ce2) ----
    fused_edge<<<(NES + 127) / 128, blk, 0, stream>>>(
        P0b, P1b, ce1, We2t, ce2, out_se, NES, sg0, sg1);
}

// Round 16
// 814.915 us; speedup vs baseline: 1.1788x; 1.0077x over previous
//
#include <hip/hip_runtime.h>
#include <cstdint>
#include <cstddef>

// Problem constants (SuperGraphConstruction)
#define NN 100000      // nodes
#define NC 20000       // clusters
#define LATD 128
#define HIDD 512
#define EMBD 12
#define NES 160000     // super edges
#define NEB 800000     // bipartite edges

enum { ACT_NONE = 0, ACT_TANH = 1, ACT_RELU = 2 };

typedef __attribute__((ext_vector_type(8))) short bf16x8;
typedef __attribute__((ext_vector_type(4))) float f32x4;
typedef unsigned short ushort_t;

__device__ __forceinline__ float fast_tanh(float x) {
    return 1.f - 2.f / (__expf(2.f * x) + 1.f);
}
__device__ __forceinline__ ushort_t f2bf(float f) {
    union { float f; unsigned u; } x; x.f = f;
    unsigned r = x.u + 0x7FFFu + ((x.u >> 16) & 1u);  // RNE
    return (ushort_t)(r >> 16);
}
__device__ __forceinline__ float bf2f(ushort_t h) {
    union { unsigned u; float f; } x; x.u = ((unsigned)h) << 16;
    return x.f;
}

typedef __attribute__((address_space(1))) void gvoid_t;
typedef __attribute__((address_space(3))) void svoid_t;
__device__ __forceinline__ void gload_lds16(const void* g, void* l) {
    __builtin_amdgcn_global_load_lds((gvoid_t*)g, (svoid_t*)l, 16, 0, 0);
}

// bijective XCD swizzle (m204): each XCD gets a contiguous span of wg ids
__device__ __forceinline__ int xcd_swz(int bid, int nwg) {
    int q = nwg >> 3, r = nwg & 7;
    int xcd = bid & 7, idx = bid >> 3;
    int base = (xcd < r) ? xcd * (q + 1) : r * (q + 1) + (xcd - r) * q;
    return base + idx;
}

// ---------------------------------------------------------------------------
__global__ __launch_bounds__(256) void conv_f2b_kernel(
    const float* __restrict__ in, ushort_t* __restrict__ out, long n)
{
    long i = ((long)blockIdx.x * 256 + threadIdx.x) * 8;
    long stride = (long)gridDim.x * 256 * 8;
    for (; i + 7 < n; i += stride) {
        float4 a = *(const float4*)(in + i);
        float4 b = *(const float4*)(in + i + 4);
        ushort_t o[8] = { f2bf(a.x), f2bf(a.y), f2bf(a.z), f2bf(a.w),
                          f2bf(b.x), f2bf(b.y), f2bf(b.z), f2bf(b.w) };
        *(int4*)(out + i) = *(int4*)o;
    }
}

// W [K][N] fp32 -> Wt [N][K] bf16
__global__ __launch_bounds__(256) void transpose_conv_kernel(
    const float* __restrict__ W, ushort_t* __restrict__ Wt, int K, int N)
{
    int i = blockIdx.x * 256 + threadIdx.x;
    if (i >= K * N) return;
    int n = i / K, k = i % K;
    Wt[i] = f2bf(W[(size_t)k * N + n]);
}

// ---------------------------------------------------------------------------
// bf16 MFMA GEMM (m97 + T2 swizzle + T1 XCD swizzle). 1D grid, n-inner.
// LDS-staged coalesced epilogue (16B/lane).
// ---------------------------------------------------------------------------
template<int ACT>
__global__ __launch_bounds__(256) void gemm_mfma(
    const ushort_t* __restrict__ A, const ushort_t* __restrict__ Bt,
    const float* __restrict__ bias, ushort_t* __restrict__ Cv,
    int M, int N, int K, int nTilesN)
{
    __shared__ ushort_t smem[2 * 128 * 64];
    ushort_t* As = smem;
    ushort_t* Bs = smem + 128 * 64;
    ushort_t* Cs = smem;               // epilogue: [128][128] swizzled tile

    const int wg = xcd_swz(blockIdx.x, gridDim.x);
    const int m0 = (wg / nTilesN) * 128, n0 = (wg % nTilesN) * 128;

    const int tid = threadIdx.x;
    const int w = tid >> 6, lane = tid & 63;
    const int wm = w >> 1, wn = w & 1;
    const int lr = lane & 15, lg = lane >> 4;
    const int srow = lane >> 3;
    const int sseg = (lane & 7) ^ srow;

    f32x4 acc[4][4];
#pragma unroll
    for (int i = 0; i < 4; ++i)
#pragma unroll
        for (int j = 0; j < 4; ++j) acc[i][j] = (f32x4){0.f, 0.f, 0.f, 0.f};

    for (int k0 = 0; k0 < K; k0 += 64) {
#pragma unroll
        for (int i = 0; i < 4; ++i) {
            int c = w * 4 + i;
            int row = c * 8 + srow;
            int gm = m0 + row; if (gm >= M) gm = M - 1;
            gload_lds16(A + (size_t)gm * K + k0 + sseg * 8, As + c * 512);
            gload_lds16(Bt + (size_t)(n0 + row) * K + k0 + sseg * 8, Bs + c * 512);
        }
        __syncthreads();
#pragma unroll
        for (int ks = 0; ks < 2; ++ks) {
            bf16x8 af[4], bf[4];
#pragma unroll
            for (int mt = 0; mt < 4; ++mt) {
                int row = wm * 64 + mt * 16 + lr;
                int slot = (ks * 4 + lg) ^ (row & 7);
                af[mt] = *(const bf16x8*)&As[row * 64 + slot * 8];
            }
#pragma unroll
            for (int nt = 0; nt < 4; ++nt) {
                int row = wn * 64 + nt * 16 + lr;
                int slot = (ks * 4 + lg) ^ (row & 7);
                bf[nt] = *(const bf16x8*)&Bs[row * 64 + slot * 8];
            }
#pragma unroll
            for (int mt = 0; mt < 4; ++mt)
#pragma unroll
                for (int nt = 0; nt < 4; ++nt)
                    acc[mt][nt] = __builtin_amdgcn_mfma_f32_16x16x32_bf16(
                        af[mt], bf[nt], acc[mt][nt], 0, 0, 0);
        }
        __syncthreads();
    }

    // ---- epilogue: act+bias -> Cs (swizzled) -> coalesced 16B writes ----
#pragma unroll
    for (int nt = 0; nt < 4; ++nt) {
        int colL = wn * 64 + nt * 16 + lr;
        float bv = bias[n0 + colL];
        int cseg = colL >> 3, coff = colL & 7;
#pragma unroll
        for (int mt = 0; mt < 4; ++mt) {
#pragma unroll
            for (int r = 0; r < 4; ++r) {
                int rowL = wm * 64 + mt * 16 + lg * 4 + r;
                float v = acc[mt][nt][r] + bv;
                if (ACT == ACT_TANH) v = fast_tanh(v);
                else if (ACT == ACT_RELU) v = fmaxf(v, 0.f);
                int slot = cseg ^ (rowL & 7);
                Cs[rowL * 128 + slot * 8 + coff] = f2bf(v);
            }
        }
    }
    __syncthreads();
#pragma unroll
    for (int it = 0; it < 8; ++it) {
        int idx = it * 256 + tid;          // 0..2047 = 128 rows x 16 segs
        int rowL = idx >> 4, seg = idx & 15;
        int slot = seg ^ (rowL & 7);
        int gr = m0 + rowL;
        if (gr < M) {
            int4 v = *(const int4*)&Cs[rowL * 128 + slot * 8];
            *(int4*)&Cv[(size_t)gr * N + n0 + seg * 8] = v;
        }
    }
}

// ---------------------------------------------------------------------------
// FUSED 2-layer MLP (node messages): out = relu(relu(A@W1+b1)@W2+b2)
// ---------------------------------------------------------------------------
template<bool OUT_BF16>
__global__ __launch_bounds__(256) void fused_mlp(
    const ushort_t* __restrict__ A, const ushort_t* __restrict__ W1t,
    const float* __restrict__ b1, const ushort_t* __restrict__ W2t,
    const float* __restrict__ b2, void* __restrict__ Cv, int M)
{
    __shared__ ushort_t As[128 * 128];
    __shared__ ushort_t Ws[128 * 64];
    __shared__ ushort_t Hs[128 * 128];

    const int tid = threadIdx.x;
    const int m0 = blockIdx.x * 128;
    const int w = tid >> 6, lane = tid & 63;
    const int wm = w >> 1, wn = w & 1;
    const int lr = lane & 15, lg = lane >> 4;
    const int srow = lane >> 3;
    const int sseg = (lane & 7) ^ srow;

    f32x4 acc2[4][4];
#pragma unroll
    for (int i = 0; i < 4; ++i)
#pragma unroll
        for (int j = 0; j < 4; ++j) acc2[i][j] = (f32x4){0.f, 0.f, 0.f, 0.f};

    {   // stage A resident: [128][128], 16-slot swizzled rows
        const int arow4 = lane >> 4;
        const int aslot = lane & 15;
#pragma unroll
        for (int rnd = 0; rnd < 8; ++rnd) {
            int row = rnd * 16 + w * 4 + arow4;
            int gm = m0 + row; if (gm >= M) gm = M - 1;
            int seg = aslot ^ (row & 7);
            gload_lds16(A + (size_t)gm * 128 + seg * 8, As + row * 128);
        }
    }

    for (int c = 0; c < 4; ++c) {
        f32x4 acc1[4][4];
#pragma unroll
        for (int i = 0; i < 4; ++i)
#pragma unroll
            for (int j = 0; j < 4; ++j) acc1[i][j] = (f32x4){0.f, 0.f, 0.f, 0.f};

        for (int k0 = 0; k0 < 128; k0 += 64) {
#pragma unroll
            for (int i = 0; i < 4; ++i) {
                int ch = w * 4 + i;
                int row = ch * 8 + srow;
                gload_lds16(W1t + (size_t)(c * 128 + row) * 128 + k0 + sseg * 8,
                            Ws + ch * 512);
            }
            __syncthreads();
#pragma unroll
            for (int ks = 0; ks < 2; ++ks) {
                bf16x8 af[4], bf[4];
#pragma unroll
                for (int mt = 0; mt < 4; ++mt) {
                    int row = wm * 64 + mt * 16 + lr;
                    int seg = (k0 >> 3) + ks * 4 + lg;
                    int slot = seg ^ (row & 7);
                    af[mt] = *(const bf16x8*)&As[row * 128 + slot * 8];
                }
#pragma unroll
                for (int nt = 0; nt < 4; ++nt) {
                    int row = wn * 64 + nt * 16 + lr;
                    int slot = (ks * 4 + lg) ^ (row & 7);
                    bf[nt] = *(const bf16x8*)&Ws[row * 64 + slot * 8];
                }
#pragma unroll
                for (int mt = 0; mt < 4; ++mt)
#pragma unroll
                    for (int nt = 0; nt < 4; ++nt)
                        acc1[mt][nt] = __builtin_amdgcn_mfma_f32_16x16x32_bf16(
                            af[mt], bf[nt], acc1[mt][nt], 0, 0, 0);
            }
            __syncthreads();
        }

        // h = relu(acc1 + b1) -> Hs
#pragma unroll
        for (int nt = 0; nt < 4; ++nt) {
            int colL = wn * 64 + nt * 16 + lr;
            float bv = b1[c * 128 + colL];
            int cseg = colL >> 3, coff = colL & 7;
#pragma unroll
            for (int mt = 0; mt < 4; ++mt) {
#pragma unroll
                for (int r = 0; r < 4; ++r) {
                    int row = wm * 64 + mt * 16 + lg * 4 + r;
                    float v = fmaxf(acc1[mt][nt][r] + bv, 0.f);
                    int slot = cseg ^ (row & 7);
                    Hs[row * 128 + slot * 8 + coff] = f2bf(v);
                }
            }
        }

        for (int k0h = 0; k0h < 128; k0h += 64) {
#pragma unroll
            for (int i = 0; i < 4; ++i) {
                int ch = w * 4 + i;
                int row = ch * 8 + srow;
                gload_lds16(W2t + (size_t)row * HIDD + c * 128 + k0h + sseg * 8,
                            Ws + ch * 512);
            }
            __syncthreads();
#pragma unroll
            for (int ks = 0; ks < 2; ++ks) {
                bf16x8 af[4], bf[4];
#pragma unroll
                for (int mt = 0; mt < 4; ++mt) {
                    int row = wm * 64 + mt * 16 + lr;
                    int seg = (k0h >> 3) + ks * 4 + lg;
                    int slot = seg ^ (row & 7);
                    af[mt] = *(const bf16x8*)&Hs[row * 128 + slot * 8];
                }
#pragma unroll
                for (int nt = 0; nt < 4; ++nt) {
                    int row = wn * 64 + nt * 16 + lr;
                    int slot = (ks * 4 + lg) ^ (row & 7);
                    bf[nt] = *(const bf16x8*)&Ws[row * 64 + slot * 8];
                }
#pragma unroll
                for (int mt = 0; mt < 4; ++mt)
#pragma unroll
                    for (int nt = 0; nt < 4; ++nt)
                        acc2[mt][nt] = __builtin_amdgcn_mfma_f32_16x16x32_bf16(
                            af[mt], bf[nt], acc2[mt][nt], 0, 0, 0);
            }
            __syncthreads();
        }
    }

#pragma unroll
    for (int nt = 0; nt < 4; ++nt) {
        int col = wn * 64 + nt * 16 + lr;
        float bv = b2[col];
#pragma unroll
        for (int mt = 0; mt < 4; ++mt) {
#pragma unroll
            for (int r = 0; r < 4; ++r) {
                int row = m0 + wm * 64 + mt * 16 + lg * 4 + r;
                if (row >= M) continue;
                float v = fmaxf(acc2[mt][nt][r] + bv, 0.f);
                if (OUT_BF16) ((ushort_t*)Cv)[(size_t)row * 128 + col] = f2bf(v);
                else ((float*)Cv)[(size_t)row * 128 + col] = v;
            }
        }
    }
}

// ---------------------------------------------------------------------------
// FUSED superedge: out[e] = relu(relu(P0[sg0[e]]+P1[sg1[e]]+b1)@W2+b2)
// Output written with NON-TEMPORAL stores (never re-read) so the streaming
// 82MB out_se doesn't evict the 41MB P0/P1 gather tables from L2/L3.
// ---------------------------------------------------------------------------
__global__ __launch_bounds__(256) void fused_edge(
    const ushort_t* __restrict__ P0, const ushort_t* __restrict__ P1,
    const float* __restrict__ b1, const ushort_t* __restrict__ W2t,
    const float* __restrict__ b2, float* __restrict__ Cv, int M,
    const int* __restrict__ g0, const int* __restrict__ g1)
{
    __shared__ ushort_t Hs[128 * 128];
    __shared__ ushort_t Ws[128 * 64];
    __shared__ int i0s[128], i1s[128];

    const int tid = threadIdx.x;
    const int m0 = blockIdx.x * 128;
    const int w = tid >> 6, lane = tid & 63;
    const int wm = w >> 1, wn = w & 1;
    const int lr = lane & 15, lg = lane >> 4;
    const int srow = lane >> 3;
    const int sseg = (lane & 7) ^ srow;
    const int er = lane >> 4;
    const int cg = lane & 15;

    if (tid < 128) {
        int gm = m0 + tid; if (gm >= M) gm = M - 1;
        i0s[tid] = g0[gm];
        i1s[tid] = g1[gm];
    }
    __syncthreads();

    f32x4 acc2[4][4];
#pragma unroll
    for (int i = 0; i < 4; ++i)
#pragma unroll
        for (int j = 0; j < 4; ++j) acc2[i][j] = (f32x4){0.f, 0.f, 0.f, 0.f};

    for (int c = 0; c < 4; ++c) {
        float bch[8];
#pragma unroll
        for (int j = 0; j < 8; ++j) bch[j] = b1[c * 128 + cg * 8 + j];

#pragma unroll
        for (int pass = 0; pass < 8; ++pass) {
            int row = pass * 16 + w * 4 + er;
            int i0 = i0s[row], i1 = i1s[row];
            bf16x8 p0 = *(const bf16x8*)(P0 + (size_t)i0 * HIDD + c * 128 + cg * 8);
            bf16x8 p1 = *(const bf16x8*)(P1 + (size_t)i1 * HIDD + c * 128 + cg * 8);
            ushort_t o[8];
#pragma unroll
            for (int j = 0; j < 8; ++j) {
                float v = bf2f((ushort_t)p0[j]) + bf2f((ushort_t)p1[j]) + bch[j];
                o[j] = f2bf(fmaxf(v, 0.f));
            }
            int slot = cg ^ (row & 7);
            *(int4*)&Hs[row * 128 + slot * 8] = *(int4*)o;
        }

        for (int k0h = 0; k0h < 128; k0h += 64) {
#pragma unroll
            for (int i = 0; i < 4; ++i) {
                int ch = w * 4 + i;
                int row = ch * 8 + srow;
                gload_lds16(W2t + (size_t)row * HIDD + c * 128 + k0h + sseg * 8,
                            Ws + ch * 512);
            }
            __syncthreads();   // covers Hs writes + Ws stage
#pragma unroll
            for (int ks = 0; ks < 2; ++ks) {
                bf16x8 af[4], bf[4];
#pragma unroll
                for (int mt = 0; mt < 4; ++mt) {
                    int row = wm * 64 + mt * 16 + lr;
                    int seg = (k0h >> 3) + ks * 4 + lg;
                    int slot = seg ^ (row & 7);
                    af[mt] = *(const bf16x8*)&Hs[row * 128 + slot * 8];
                }
#pragma unroll
                for (int nt = 0; nt < 4; ++nt) {
                    int row = wn * 64 + nt * 16 + lr;
                    int slot = (ks * 4 + lg) ^ (row & 7);
                    bf[nt] = *(const bf16x8*)&Ws[row * 64 + slot * 8];
                }
#pragma unroll
                for (int mt = 0; mt < 4; ++mt)
#pragma unroll
                    for (int nt = 0; nt < 4; ++nt)
                        acc2[mt][nt] = __builtin_amdgcn_mfma_f32_16x16x32_bf16(
                            af[mt], bf[nt], acc2[mt][nt], 0, 0, 0);
            }
            __syncthreads();
        }
    }

#pragma unroll
    for (int nt = 0; nt < 4; ++nt) {
        int col = wn * 64 + nt * 16 + lr;
        float bv = b2[col];
#pragma unroll
        for (int mt = 0; mt < 4; ++mt) {
#pragma unroll
            for (int r = 0; r < 4; ++r) {
                int row = m0 + wm * 64 + mt * 16 + lg * 4 + r;
                if (row >= M) continue;
                float v = fmaxf(acc2[mt][nt][r] + bv, 0.f);
                __builtin_nontemporal_store(v, &Cv[(size_t)row * 128 + col]);
            }
        }
    }
}

// ---------------------------------------------------------------------------
// embeddings = l2norm(h2 @ Wc3 + bc3); THREAD-per-row; h2 bf16.
// ---------------------------------------------------------------------------
__global__ __launch_bounds__(256) void emb_kernel(
    const ushort_t* __restrict__ h2, const float* __restrict__ W,
    const float* __restrict__ bias, float* __restrict__ out, int M)
{
    __shared__ float Wl[HIDD * EMBD];
    for (int i = threadIdx.x; i < HIDD * EMBD; i += 256) Wl[i] = W[i];
    __syncthreads();

    int m = blockIdx.x * 256 + threadIdx.x;
    if (m >= M) return;
    const ushort_t* row = h2 + (size_t)m * HIDD;

    float acc[EMBD] = {};
#pragma unroll 2
    for (int k0 = 0; k0 < HIDD; k0 += 8) {
        bf16x8 v = *(const bf16x8*)(row + k0);
        float f[8];
#pragma unroll
        for (int u = 0; u < 8; ++u) f[u] = bf2f((ushort_t)v[u]);
#pragma unroll
        for (int u = 0; u < 8; ++u) {
            const float* wr = &Wl[(k0 + u) * EMBD];
#pragma unroll
            for (int j = 0; j < EMBD; ++j) acc[j] += f[u] * wr[j];
        }
    }
    float vv[EMBD];
    float ss = 0.f;
#pragma unroll
    for (int j = 0; j < EMBD; ++j) { vv[j] = acc[j] + bias[j]; ss += vv[j] * vv[j]; }
    float inv = 1.f / fmaxf(sqrtf(ss), 1e-12f);
#pragma unroll
    for (int j = 0; j < EMBD; ++j) out[(size_t)m * EMBD + j] = vv[j] * inv;
}

// ---------------------------------------------------------------------------
__global__ void cluster_accum(const float* __restrict__ emb,
                              const int* __restrict__ clusters,
                              float* __restrict__ csums, float* __restrict__ ccnt)
{
    int n = blockIdx.x * 256 + threadIdx.x;
    if (n >= NN) return;
    int c = clusters[n];
    const float4* row = (const float4*)(emb + (size_t)n * EMBD);
    float4 r0 = row[0], r1 = row[1], r2 = row[2];
    float* dst = &csums[(size_t)c * EMBD];
    atomicAdd(&dst[0], r0.x);  atomicAdd(&dst[1], r0.y);
    atomicAdd(&dst[2], r0.z);  atomicAdd(&dst[3], r0.w);
    atomicAdd(&dst[4], r1.x);  atomicAdd(&dst[5], r1.y);
    atomicAdd(&dst[6], r1.z);  atomicAdd(&dst[7], r1.w);
    atomicAdd(&dst[8], r2.x);  atomicAdd(&dst[9], r2.y);
    atomicAdd(&dst[10], r2.z); atomicAdd(&dst[11], r2.w);
    atomicAdd(&ccnt[c], 1.f);
}

__global__ void means_kernel(const float* __restrict__ csums,
                             const float* __restrict__ ccnt,
                             float* __restrict__ means)
{
    int c = blockIdx.x * 256 + threadIdx.x;
    if (c >= NC) return;
    float cv = fmaxf(ccnt[c], 1.f);
    float v[EMBD];
    float ss = 0.f;
#pragma unroll
    for (int j = 0; j < EMBD; ++j) {
        v[j] = csums[(size_t)c * EMBD + j] / cv;
        ss += v[j] * v[j];
    }
    float inv = 1.f / fmaxf(sqrtf(ss), 1e-12f);
#pragma unroll
    for (int j = 0; j < EMBD; ++j) means[(size_t)c * EMBD + j] = v[j] * inv;
}

// ---------------------------------------------------------------------------
__device__ __forceinline__ void block_stats2(float x, float x2, float* s_sum, float* s_sumsq)
{
#pragma unroll
    for (int s = 32; s >= 1; s >>= 1) {
        x += __shfl_xor(x, s, 64);
        x2 += __shfl_xor(x2, s, 64);
    }
    __shared__ float w0[4], w1[4];
    int lane = threadIdx.x & 63, w = threadIdx.x >> 6;
    if (lane == 0) { w0[w] = x; w1[w] = x2; }
    __syncthreads();
    if (threadIdx.x == 0) {
        float a = 0.f, b = 0.f;
        for (int i = 0; i < 4; ++i) { a += w0[i]; b += w1[i]; }
        atomicAdd(s_sum, a);
        atomicAdd(s_sumsq, b);
    }
}

// ---------------------------------------------------------------------------
__global__ __launch_bounds__(256) void sg_lik_kernel(
    const float* __restrict__ means, const int* __restrict__ sg0,
    const int* __restrict__ sg1, float* __restrict__ sg_lik, float* __restrict__ stats)
{
    int base = (blockIdx.x * 256 + threadIdx.x) * 4;
    float xs = 0.f, xs2 = 0.f;
    if (base < NES) {
        int4 a4 = *(const int4*)(sg0 + base);
        int4 b4 = *(const int4*)(sg1 + base);
        int ai[4] = {a4.x, a4.y, a4.z, a4.w};
        int bi[4] = {b4.x, b4.y, b4.z, b4.w};
        float4 av[4][3], bv[4][3];
#pragma unroll
        for (int i = 0; i < 4; ++i) {
            const float4* ap = (const float4*)(means + (size_t)ai[i] * EMBD);
            const float4* bp = (const float4*)(means + (size_t)bi[i] * EMBD);
            av[i][0] = ap[0]; av[i][1] = ap[1]; av[i][2] = ap[2];
            bv[i][0] = bp[0]; bv[i][1] = bp[1]; bv[i][2] = bp[2];
        }
        float4 o;
        float* op = (float*)&o;
#pragma unroll
        for (int i = 0; i < 4; ++i) {
            float s = av[i][0].x * bv[i][0].x + av[i][0].y * bv[i][0].y
                    + av[i][0].z * bv[i][0].z + av[i][0].w * bv[i][0].w
                    + av[i][1].x * bv[i][1].x + av[i][1].y * bv[i][1].y
                    + av[i][1].z * bv[i][1].z + av[i][1].w * bv[i][1].w
                    + av[i][2].x * bv[i][2].x + av[i][2].y * bv[i][2].y
                    + av[i][2].z * bv[i][2].z + av[i][2].w * bv[i][2].w;
            op[i] = s;
            xs += s; xs2 += s * s;
        }
        *(float4*)(sg_lik + base) = o;
    }
    block_stats2(xs, xs2, &stats[0], &stats[1]);
}

__global__ __launch_bounds__(256) void sgw_kernel(
    const float* __restrict__ sg_lik, const float* __restrict__ stats,
    const float* __restrict__ gamma, const float* __restrict__ beta,
    float* __restrict__ out)
{
    int base = (blockIdx.x * 256 + threadIdx.x) * 4;
    if (base >= NES) return;
    float m = stats[0] / (float)NES;
    float var = stats[1] / (float)NES - m * m;
    float rs = rsqrtf(var + 1e-5f) * gamma[0];
    float4 v = *(const float4*)(sg_lik + base);
    float4 o;
    o.x = 1.f / (1.f + __expf(-((v.x - m) * rs + beta[0])));
    o.y = 1.f / (1.f + __expf(-((v.y - m) * rs + beta[0])));
    o.z = 1.f / (1.f + __expf(-((v.z - m) * rs + beta[0])));
    o.w = 1.f / (1.f + __expf(-((v.w - m) * rs + beta[0])));
    *(float4*)(out + base) = o;
}

// ---------------------------------------------------------------------------
__global__ __launch_bounds__(256) void bg_lik_kernel(
    const float* __restrict__ emb, const float* __restrict__ means,
    const int* __restrict__ bg_src, const int* __restrict__ bg_dst,
    float* __restrict__ bg_lik, float* __restrict__ stats, int* __restrict__ cnt)
{
    int base = (blockIdx.x * 256 + threadIdx.x) * 4;
    float xs = 0.f, xs2 = 0.f;
    if (base < NEB) {
        int4 s4 = *(const int4*)(bg_src + base);
        int4 d4 = *(const int4*)(bg_dst + base);
        int si[4] = {s4.x, s4.y, s4.z, s4.w};
        int di[4] = {d4.x, d4.y, d4.z, d4.w};
        float4 av[4][3], bv[4][3];
#pragma unroll
        for (int i = 0; i < 4; ++i) {
            const float4* ap = (const float4*)(emb + (size_t)si[i] * EMBD);
            const float4* bp = (const float4*)(means + (size_t)di[i] * EMBD);
            av[i][0] = ap[0]; av[i][1] = ap[1]; av[i][2] = ap[2];
            bv[i][0] = bp[0]; bv[i][1] = bp[1]; bv[i][2] = bp[2];
        }
#pragma unroll
        for (int i = 0; i < 4; ++i) atomicAdd(&cnt[di[i]], 1);
        float4 o;
        float* op = (float*)&o;
#pragma unroll
        for (int i = 0; i < 4; ++i) {
            float s = av[i][0].x * bv[i][0].x + av[i][0].y * bv[i][0].y
                    + av[i][0].z * bv[i][0].z + av[i][0].w * bv[i][0].w
                    + av[i][1].x * bv[i][1].x + av[i][1].y * bv[i][1].y
                    + av[i][1].z * bv[i][1].z + av[i][1].w * bv[i][1].w
                    + av[i][2].x * bv[i][2].x + av[i][2].y * bv[i][2].y
                    + av[i][2].z * bv[i][2].z + av[i][2].w * bv[i][2].w;
            op[i] = s;
            xs += s; xs2 += s * s;
        }
        *(float4*)(bg_lik + base) = o;
    }
    block_stats2(xs, xs2, &stats[2], &stats[3]);
}

__global__ __launch_bounds__(256) void bw_kernel(
    const float* __restrict__ bg_lik, const float* __restrict__ stats,
    const float* __restrict__ gamma, const float* __restrict__ beta,
    const int* __restrict__ bg_src, float* __restrict__ bw, float* __restrict__ denom)
{
    int base = (blockIdx.x * 256 + threadIdx.x) * 4;
    if (base >= NEB) return;
    float m = stats[2] / (float)NEB;
    float var = stats[3] / (float)NEB - m * m;
    float rs = rsqrtf(var + 1e-5f) * gamma[0];
    int4 s4 = *(const int4*)(bg_src + base);
    int si[4] = {s4.x, s4.y, s4.z, s4.w};
    float4 v = *(const float4*)(bg_lik + base);
    float vi[4] = {v.x, v.y, v.z, v.w};
    float4 o;
    float* op = (float*)&o;
#pragma unroll
    for (int i = 0; i < 4; ++i) {
        float w = __expf((vi[i] - m) * rs + beta[0]);
        op[i] = w;
        atomicAdd(&denom[si[i]], w);
    }
    *(float4*)(bw + base) = o;
}

__global__ __launch_bounds__(256) void bw_norm_kernel(
    float* __restrict__ bw, const float* __restrict__ denom,
    const int* __restrict__ bg_src, float* __restrict__ out)
{
    int base = (blockIdx.x * 256 + threadIdx.x) * 4;
    if (base >= NEB) return;
    int4 s4 = *(const int4*)(bg_src + base);
    int si[4] = {s4.x, s4.y, s4.z, s4.w};
    float dv[4];
#pragma unroll
    for (int i = 0; i < 4; ++i) dv[i] = denom[si[i]];
    float4 v = *(const float4*)(bw + base);
    f32x4 o;
    o[0] = v.x / (1e-12f + dv[0]);
    o[1] = v.y / (1e-12f + dv[1]);
    o[2] = v.z / (1e-12f + dv[2]);
    o[3] = v.w / (1e-12f + dv[3]);
    *(f32x4*)(bw + base) = o;
    __builtin_nontemporal_store(o, (f32x4*)(out + base));
}

// ---------------------------------------------------------------------------
__global__ __launch_bounds__(1024) void scan_kernel(
    const int* __restrict__ cnt, int* __restrict__ offs, int C)
{
    __shared__ int wsum[16];
    __shared__ int carry_s, ctot_s;
    const int tid = threadIdx.x;
    const int lane = tid & 63, w = tid >> 6;
    if (tid == 0) carry_s = 0;
    __syncthreads();
    for (int base = 0; base < C; base += 1024) {
        int i = base + tid;
        int v = (i < C) ? cnt[i] : 0;
        int x = v;
#pragma unroll
        for (int s = 1; s < 64; s <<= 1) {
            int y = __shfl_up(x, s, 64);
            if (lane >= s) x += y;
        }
        if (lane == 63) wsum[w] = x;
        __syncthreads();
        if (tid == 0) {
            int s = 0;
            for (int k = 0; k < 16; ++k) { int t = wsum[k]; wsum[k] = s; s += t; }
            ctot_s = s;
        }
        __syncthreads();
        int excl = carry_s + wsum[w] + (x - v);
        if (i < C) offs[i] = excl;
        __syncthreads();
        if (tid == 0) carry_s += ctot_s;
        __syncthreads();
    }
    if (tid == 0) offs[C] = carry_s;
}

__global__ void scatter_kernel(const int* __restrict__ bg_dst,
                               const int* __restrict__ offs,
                               int* __restrict__ fill, int* __restrict__ eids)
{
    int base = (blockIdx.x * 256 + threadIdx.x) * 4;
    if (base >= NEB) return;
    int4 d4 = *(const int4*)(bg_dst + base);
    int di[4] = {d4.x, d4.y, d4.z, d4.w};
#pragma unroll
    for (int i = 0; i < 4; ++i) {
        int p = atomicAdd(&fill[di[i]], 1);
        eids[offs[di[i]] + p] = base + i;
    }
}

// ---------------------------------------------------------------------------
// supernodes: lane-packed gather; fp32 out via NT store (never re-read);
// bf16 copy feeds downstream GEMMs.
// ---------------------------------------------------------------------------
__global__ __launch_bounds__(256) void supernodes_kernel(
    const ushort_t* __restrict__ nmsg, const float* __restrict__ bw,
    const int* __restrict__ bg_src, const int* __restrict__ eids,
    const int* __restrict__ offs, float* __restrict__ sn,
    ushort_t* __restrict__ sn_bf)
{
    __shared__ float red[4][LATD];
    const int c = blockIdx.x;
    const int tid = threadIdx.x;
    const int wv = tid >> 6, lane = tid & 63;
    const int er = lane >> 4;
    const int cg = lane & 15;
    const int beg = offs[c], end = offs[c + 1];

    float acc[8] = {};
    for (int p = beg + wv * 4 + er; p < end; p += 16) {
        int e = eids[p];
        int s = bg_src[e];
        float w = bw[e];
        bf16x8 v = *(const bf16x8*)(nmsg + (size_t)s * LATD + cg * 8);
#pragma unroll
        for (int j = 0; j < 8; ++j) acc[j] += w * bf2f((ushort_t)v[j]);
    }
#pragma unroll
    for (int j = 0; j < 8; ++j) {
        acc[j] += __shfl_xor(acc[j], 16, 64);
        acc[j] += __shfl_xor(acc[j], 32, 64);
    }
    if (lane < 16) {
        *(float4*)&red[wv][cg * 8]     = (float4){acc[0], acc[1], acc[2], acc[3]};
        *(float4*)&red[wv][cg * 8 + 4] = (float4){acc[4], acc[5], acc[6], acc[7]};
    }
    __syncthreads();
    if (tid < LATD) {
        float s = red[0][tid] + red[1][tid] + red[2][tid] + red[3][tid];
        __builtin_nontemporal_store(s, &sn[(size_t)c * LATD + tid]);
        sn_bf[(size_t)c * LATD + tid] = f2bf(s);
    }
}

// ---------------------------------------------------------------------------
extern "C" void kernel_launch(void* const* d_in, const int* in_sizes, int n_in,
                              void* d_out, int out_size, void* d_ws, size_t ws_size,
                              hipStream_t stream)
{
    const float* emb_nodes = (const float*)d_in[0];
    const float* enc_nodes = (const float*)d_in[1];
    const float* Wc1 = (const float*)d_in[2];  const float* bc1 = (const float*)d_in[3];
    const float* Wc2 = (const float*)d_in[4];  const float* bc2 = (const float*)d_in[5];
    const float* Wc3 = (const float*)d_in[6];  const float* bc3 = (const float*)d_in[7];
    const float* Wn1 = (const float*)d_in[8];  const float* cn1 = (const float*)d_in[9];
    const float* Wn2 = (const float*)d_in[10]; const float* cn2 = (const float*)d_in[11];
    const float* We1 = (const float*)d_in[12]; const float* ce1 = (const float*)d_in[13];
    const float* We2 = (const float*)d_in[14]; const float* ce2 = (const float*)d_in[15];
    const float* sg_gamma = (const float*)d_in[16]; const float* sg_beta = (const float*)d_in[17];
    const float* bg_gamma = (const float*)d_in[18]; const float* bg_beta = (const float*)d_in[19];
    const int* clusters = (const int*)d_in[20];
    const int* sg0 = (const int*)d_in[21];
    const int* sg1 = sg0 + NES;
    const int* bg_src = (const int*)d_in[22];
    const int* bg_dst = (const int*)d_in[23];

    // output layout (flat, return order)
    float* out_emb = (float*)d_out;                       // NN*EMBD
    float* out_sn  = out_emb + (size_t)NN * EMBD;         // NC*LATD
    float* out_se  = out_sn + (size_t)NC * LATD;          // NES*LATD
    float* out_bw  = out_se + (size_t)NES * LATD;         // NEB
    float* out_sew = out_bw + (size_t)NEB;                // NES

    // ---------------- workspace layout (byte cursor, 64B-aligned) ----------
    uintptr_t cur = (uintptr_t)d_ws;
    uintptr_t wend = cur + ws_size;
    auto alloc = [&](size_t bytes) -> void* {
        cur = (cur + 63) & ~(uintptr_t)63;
        void* p = (void*)cur;
        cur += bytes;
        return p;
    };

    // zeroed region: csums, ccnt, denom, stats, cnt, fill, zbias
    size_t zfloats = (size_t)NC * EMBD + NC + NN + 8 + NC + NC + HIDD;
    float* zbase = (float*)alloc(zfloats * 4);
    float* csums = zbase;
    float* ccnt  = csums + (size_t)NC * EMBD;
    float* denom = ccnt + NC;
    float* stats = denom + NN;
    int*   cnt   = (int*)(stats + 8);
    int*   fill  = cnt + NC;
    float* zbias = (float*)(fill + NC);         // HIDD zeros
    size_t zero_bytes = zfloats * 4;

    float* means  = (float*)alloc((size_t)NC * EMBD * 4);
    float* sg_lik = (float*)alloc((size_t)NES * 4);
    float* bg_lik = (float*)alloc((size_t)NEB * 4);
    float* bwv    = (float*)alloc((size_t)NEB * 4);
    int*   offs   = (int*)alloc((size_t)(NC + 1) * 4);
    int*   eids   = (int*)alloc((size_t)NEB * 4);

    ushort_t* xemb   = (ushort_t*)alloc((size_t)NN * LATD * 2);
    ushort_t* xenc   = (ushort_t*)alloc((size_t)NN * LATD * 2);
    ushort_t* nmsgb  = (ushort_t*)alloc((size_t)NN * LATD * 2);
    ushort_t* sn_bf  = (ushort_t*)alloc((size_t)NC * LATD * 2);
    ushort_t* P0b    = (ushort_t*)alloc((size_t)NC * HIDD * 2);
    ushort_t* P1b    = (ushort_t*)alloc((size_t)NC * HIDD * 2);
    ushort_t* Wc1t  = (ushort_t*)alloc((size_t)LATD * HIDD * 2);
    ushort_t* Wc2t  = (ushort_t*)alloc((size_t)HIDD * HIDD * 2);
    ushort_t* Wn1t  = (ushort_t*)alloc((size_t)LATD * HIDD * 2);
    ushort_t* Wn2t  = (ushort_t*)alloc((size_t)HIDD * LATD * 2);
    ushort_t* We1tA = (ushort_t*)alloc((size_t)HIDD * LATD * 2);  // [512][128]
    ushort_t* We1tB = (ushort_t*)alloc((size_t)HIDD * LATD * 2);  // [512][128]
    ushort_t* We2t  = (ushort_t*)alloc((size_t)HIDD * LATD * 2);  // [128][512]

    cur = (cur + 63) & ~(uintptr_t)63;
    size_t rem_bytes = (wend > cur) ? (size_t)(wend - cur) : 0;
    size_t chunk_sz = (rem_bytes / (2 * (size_t)HIDD * 2)) & ~(size_t)127;
    if (chunk_sz > 100096) chunk_sz = 100096;  // one chunk if ws allows
    if (chunk_sz < 256) return;  // fail soft
    const int CH = (int)chunk_sz;
    ushort_t* bufA = (ushort_t*)cur;
    ushort_t* bufB = bufA + (size_t)CH * HIDD;

    hipMemsetAsync(zbase, 0, zero_bytes, stream);

    dim3 blk(256);

    // ---- prep: input/weight conversions ----
    conv_f2b_kernel<<<2048, blk, 0, stream>>>(emb_nodes, xemb, (long)NN * LATD);
    conv_f2b_kernel<<<2048, blk, 0, stream>>>(enc_nodes, xenc, (long)NN * LATD);
    transpose_conv_kernel<<<(LATD * HIDD + 255) / 256, blk, 0, stream>>>(Wc1, Wc1t, LATD, HIDD);
    transpose_conv_kernel<<<(HIDD * HIDD + 255) / 256, blk, 0, stream>>>(Wc2, Wc2t, HIDD, HIDD);
    transpose_conv_kernel<<<(LATD * HIDD + 255) / 256, blk, 0, stream>>>(Wn1, Wn1t, LATD, HIDD);
    transpose_conv_kernel<<<(HIDD * LATD + 255) / 256, blk, 0, stream>>>(Wn2, Wn2t, HIDD, LATD);
    transpose_conv_kernel<<<(LATD * HIDD + 255) / 256, blk, 0, stream>>>(We1, We1tA, LATD, HIDD);
    transpose_conv_kernel<<<(LATD * HIDD + 255) / 256, blk, 0, stream>>>(We1 + (size_t)LATD * HIDD, We1tB, LATD, HIDD);
    transpose_conv_kernel<<<(HIDD * LATD + 255) / 256, blk, 0, stream>>>(We2, We2t, HIDD, LATD);

    // ---- fused node chain, chunked: xemb->h1->h2->embeddings ----
    for (int m0 = 0; m0 < NN; m0 += CH) {
        int cm = (NN - m0 < CH) ? (NN - m0) : CH;
        int mt = (cm + 127) / 128;
        gemm_mfma<ACT_TANH><<<mt * (HIDD / 128), blk, 0, stream>>>(
            xemb + (size_t)m0 * LATD, Wc1t, bc1, bufA, cm, HIDD, LATD, HIDD / 128);
        gemm_mfma<ACT_TANH><<<mt * (HIDD / 128), blk, 0, stream>>>(
            bufA, Wc2t, bc2, bufB, cm, HIDD, HIDD, HIDD / 128);
        emb_kernel<<<(cm + 255) / 256, blk, 0, stream>>>(
            bufB, Wc3, bc3, out_emb + (size_t)m0 * EMBD, cm);
    }

    // ---- cluster means ----
    cluster_accum<<<(NN + 255) / 256, blk, 0, stream>>>(out_emb, clusters, csums, ccnt);
    means_kernel<<<(NC + 255) / 256, blk, 0, stream>>>(csums, ccnt, means);

    // ---- super edge weights (4 edges/thread) ----
    sg_lik_kernel<<<(NES / 4 + 255) / 256, blk, 0, stream>>>(means, sg0, sg1, sg_lik, stats);
    sgw_kernel<<<(NES / 4 + 255) / 256, blk, 0, stream>>>(sg_lik, stats, sg_gamma, sg_beta, out_sew);

    // ---- bipartite edge weights (hist fused; 4 edges/thread) ----
    bg_lik_kernel<<<(NEB / 4 + 255) / 256, blk, 0, stream>>>(out_emb, means, bg_src, bg_dst, bg_lik, stats, cnt);
    bw_kernel<<<(NEB / 4 + 255) / 256, blk, 0, stream>>>(bg_lik, stats, bg_gamma, bg_beta, bg_src, bwv, denom);
    bw_norm_kernel<<<(NEB / 4 + 255) / 256, blk, 0, stream>>>(bwv, denom, bg_src, out_bw);

    // ---- counting sort of edges by destination cluster ----
    scan_kernel<<<1, 1024, 0, stream>>>(cnt, offs, NC);
    scatter_kernel<<<(NEB / 4 + 255) / 256, blk, 0, stream>>>(bg_dst, offs, fill, eids);

    // ---- node messages: FUSED relu(relu(xenc@Wn1)@Wn2) -> nmsgb (bf16) ----
    fused_mlp<true><<<(NN + 127) / 128, blk, 0, stream>>>(
        xenc, Wn1t, cn1, Wn2t, cn2, nmsgb, NN);

    // ---- supernodes (sorted, no atomics; NT fp32 + bf16) ----
    supernodes_kernel<<<NC, blk, 0, stream>>>(nmsgb, bwv, bg_src, eids, offs, out_sn, sn_bf);

    // ---- premultiply: P0 = sn@We1_top, P1 = sn@We1_bot (no bias/act) ----
    {
        int mt = (NC + 127) / 128;
        gemm_mfma<ACT_NONE><<<mt * (HIDD / 128), blk, 0, stream>>>(
            sn_bf, We1tA, zbias, P0b, NC, HIDD, LATD, HIDD / 128);
        gemm_mfma<ACT_NONE><<<mt * (HIDD / 128), blk, 0, stream>>>(
            sn_bf, We1tB, zbias, P1b, NC, HIDD, LATD, HIDD / 128);
    }

    // ---- superedges: FUSED relu(relu(P0[sg0]+P1[sg1]+ce1)@We2+ce2) ----
    fused_edge<<<(NES + 127) / 128, blk, 0, stream>>>(
        P0b, P1b, ce1, We2t, ce2, out_se, NES, sg0, sg1);
}